// Round 1
// baseline (1358.748 us; speedup 1.0000x reference)
//
#include <hip/hip_runtime.h>
#include <math.h>

#define NN 50000      // nodes (both src and dst)
#define DIN 128
#define FDIM 256      // H*C
#define EE 200000
#define TT 6
#define DE 8
#define KC 48         // clusters

// ---------------- utility kernels ----------------
__global__ void zero_i32(int* __restrict__ p, int n){
  int i = blockIdx.x*256 + threadIdx.x;
  if (i < n) p[i] = 0;
}

__global__ void count_deg(const int* __restrict__ dst, int* __restrict__ deg){
  int i = blockIdx.x*256 + threadIdx.x;
  if (i < EE) atomicAdd(&deg[dst[i]], 1);
}

__global__ __launch_bounds__(1024) void excl_scan(const int* __restrict__ deg, int* __restrict__ rp, int n){
  __shared__ int sm[1024];
  int carry = 0;
  for (int base = 0; base < n; base += 1024){
    int i = base + (int)threadIdx.x;
    int v = (i < n) ? deg[i] : 0;
    __syncthreads();
    sm[threadIdx.x] = v;
    __syncthreads();
    for (int off = 1; off < 1024; off <<= 1){
      int t = (threadIdx.x >= (unsigned)off) ? sm[threadIdx.x - off] : 0;
      __syncthreads();
      sm[threadIdx.x] += t;
      __syncthreads();
    }
    if (i < n) rp[i] = carry + sm[threadIdx.x] - v;
    carry += sm[1023];
  }
  if (threadIdx.x == 0) rp[n] = carry;
}

__global__ void copy_i32(const int* __restrict__ a, int* __restrict__ b, int n){
  int i = blockIdx.x*256 + threadIdx.x;
  if (i < n) b[i] = a[i];
}

__global__ void scatter_edges(const int* __restrict__ dst, int* __restrict__ cursor, int* __restrict__ eids){
  int i = blockIdx.x*256 + threadIdx.x;
  if (i < EE){ int pos = atomicAdd(&cursor[dst[i]], 1); eids[pos] = i; }
}

// ---------------- GEMM: C[nrows,256] = (A * rowmask) @ W[K,256] ----------------
__global__ __launch_bounds__(256) void gemm_f32(const float* __restrict__ A, const float* __restrict__ W,
                                                const float* __restrict__ mask, float* __restrict__ Cm,
                                                int nrows, int K){
  __shared__ float As[16][68];  // [k][row], pad 4 -> 16B-aligned rows, conflict-light
  __shared__ float Ws[16][64];  // [k][col]
  int tid = threadIdx.x;
  int row0 = blockIdx.x * 64;
  int col0 = blockIdx.y * 64;
  int tx = tid & 15;
  int ty = tid >> 4;
  float acc[4][4] = {};
  for (int k0 = 0; k0 < K; k0 += 16){
    #pragma unroll
    for (int p = 0; p < 4; p++){
      int idx = tid + p*256;          // 0..1023
      int r  = idx >> 4;
      int kk = idx & 15;
      int gr = row0 + r;
      float v = 0.f;
      if (gr < nrows){
        v = A[(size_t)gr*K + k0 + kk];
        if (mask) v *= mask[gr];
      }
      As[kk][r] = v;
    }
    #pragma unroll
    for (int p = 0; p < 4; p++){
      int idx = tid + p*256;
      int kk = idx >> 6;
      int c  = idx & 63;
      Ws[kk][c] = W[(size_t)(k0 + kk)*256 + col0 + c];
    }
    __syncthreads();
    #pragma unroll
    for (int kk = 0; kk < 16; kk++){
      float a[4], b[4];
      #pragma unroll
      for (int i = 0; i < 4; i++) a[i] = As[kk][ty*4 + i];
      #pragma unroll
      for (int j = 0; j < 4; j++) b[j] = Ws[kk][tx*4 + j];
      #pragma unroll
      for (int i = 0; i < 4; i++)
        #pragma unroll
        for (int j = 0; j < 4; j++)
          acc[i][j] = fmaf(a[i], b[j], acc[i][j]);
    }
    __syncthreads();
  }
  #pragma unroll
  for (int i = 0; i < 4; i++){
    int gr = row0 + ty*4 + i;
    if (gr < nrows){
      #pragma unroll
      for (int j = 0; j < 4; j++)
        Cm[(size_t)gr*256 + col0 + tx*4 + j] = acc[i][j];
    }
  }
}

// ---------------- edge logits: e[E][4] ----------------
__global__ __launch_bounds__(256) void edge_logits(const int* __restrict__ src, const int* __restrict__ dst,
                                                   const float* __restrict__ hs, const float* __restrict__ hd,
                                                   const float* __restrict__ att, float* __restrict__ eo){
  int eidx = blockIdx.x*4 + (threadIdx.x >> 6);
  int lane = threadIdx.x & 63;
  if (eidx >= EE) return;
  int s = src[eidx], d = dst[eidx];
  const float* ps = hs + (size_t)s*256;
  const float* pd = hd + (size_t)d*256;
  #pragma unroll
  for (int h = 0; h < 4; h++){
    float m = ps[h*64 + lane] + pd[h*64 + lane];
    float lr = (m > 0.f) ? m : 0.2f*m;
    float v = lr * att[h*64 + lane];
    #pragma unroll
    for (int off = 32; off > 0; off >>= 1) v += __shfl_down(v, off);
    if (lane == 0) eo[eidx*4 + h] = v;
  }
}

// ---------------- per-dst segment softmax + weighted aggregation ----------------
__global__ __launch_bounds__(256) void aggregate(const int* __restrict__ rp, const int* __restrict__ eids,
                                                 const int* __restrict__ src, const float* __restrict__ elog,
                                                 const float* __restrict__ hs, const float* __restrict__ bias,
                                                 float* __restrict__ out, int do_relu){
  int n = blockIdx.x;
  int t = threadIdx.x;
  int h = t >> 6;
  int beg = rp[n], end = rp[n+1];
  float mx = -INFINITY;
  for (int i = beg; i < end; i++) mx = fmaxf(mx, elog[eids[i]*4 + h]);
  float ssum = 0.f, acc = 0.f;
  for (int i = beg; i < end; i++){
    int eid = eids[i];
    float w = expf(elog[eid*4 + h] - mx);
    ssum += w;
    acc = fmaf(w, hs[(size_t)src[eid]*256 + t], acc);
  }
  float r = acc / (ssum + 1e-16f) + bias[t];
  if (do_relu) r = fmaxf(r, 0.f);
  out[(size_t)n*256 + t] = r;
}

// ---------------- pool: logits + row softmax -> s_assign[N][48] ----------------
__global__ __launch_bounds__(256) void pool_softmax(const float* __restrict__ h2, const float* __restrict__ Wp,
                                                    const float* __restrict__ bp, float* __restrict__ s_out){
  int node = blockIdx.x*4 + (threadIdx.x >> 6);
  int lane = threadIdx.x & 63;
  float acc = -INFINITY;
  if (lane < KC){
    acc = bp[lane];
    const float* hr = h2 + (size_t)node*256;
    for (int k = 0; k < 256; k++) acc = fmaf(hr[k], Wp[k*KC + lane], acc);
  }
  float mx = acc;
  #pragma unroll
  for (int off = 32; off > 0; off >>= 1) mx = fmaxf(mx, __shfl_xor(mx, off));
  float w = (lane < KC) ? expf(acc - mx) : 0.f;
  float sm = w;
  #pragma unroll
  for (int off = 32; off > 0; off >>= 1) sm += __shfl_xor(sm, off);
  if (lane < KC) s_out[(size_t)node*KC + lane] = w / sm;
}

// ---------------- x_pooled[48][256] += s.T @ h2 (split over node chunks) ----------------
__global__ __launch_bounds__(256) void pooled_accum(const float* __restrict__ s, const float* __restrict__ h2,
                                                    float* __restrict__ xp){
  __shared__ float sld[64][KC];
  int t = threadIdx.x;  // column 0..255
  float acc[KC];
  #pragma unroll
  for (int k = 0; k < KC; k++) acc[k] = 0.f;
  int chunk = (NN + gridDim.x - 1) / gridDim.x;
  int nb = blockIdx.x * chunk;
  int ne = min(nb + chunk, NN);
  for (int base = nb; base < ne; base += 64){
    int cnt = min(64, ne - base);
    __syncthreads();
    for (int idx = t; idx < cnt*KC; idx += 256)
      sld[idx/KC][idx%KC] = s[(size_t)(base + idx/KC)*KC + idx%KC];
    __syncthreads();
    for (int n = 0; n < cnt; n++){
      float v = h2[(size_t)(base + n)*256 + t];
      #pragma unroll
      for (int k = 0; k < KC; k++) acc[k] = fmaf(sld[n][k], v, acc[k]);
    }
  }
  for (int k = 0; k < KC; k++) atomicAdd(&xp[k*256 + t], acc[k]);
}

// ---------------- edge_attr mean over E -> [48] ----------------
__global__ __launch_bounds__(256) void edge_attr_mean(const float* __restrict__ ea, float* __restrict__ out){
  int t = blockIdx.x >> 3, d = blockIdx.x & 7;
  const float* p = ea + (size_t)t*EE*DE + d;
  float s = 0.f;
  for (int i = threadIdx.x; i < EE; i += 256) s += p[(size_t)i*DE];
  __shared__ float red[256];
  red[threadIdx.x] = s; __syncthreads();
  for (int off = 128; off > 0; off >>= 1){
    if (threadIdx.x < (unsigned)off) red[threadIdx.x] += red[threadIdx.x + off];
    __syncthreads();
  }
  if (threadIdx.x == 0) out[blockIdx.x] = red[0] / (float)EE;
}

// ---------------- final classifier ----------------
__global__ void final_cls(const float* __restrict__ xp, const float* __restrict__ agg,
                          const float* __restrict__ Wc, const float* __restrict__ bc,
                          float* __restrict__ out){
  int k = threadIdx.x;
  if (k < KC){
    float s = bc[0];
    for (int f = 0; f < 256; f++) s = fmaf(xp[k*256 + f], Wc[f], s);
    s = fmaf(agg[k], Wc[256], s);
    out[k] = 1.f/(1.f + expf(-s));
  }
}

extern "C" void kernel_launch(void* const* d_in, const int* in_sizes, int n_in,
                              void* d_out, int out_size, void* d_ws, size_t ws_size,
                              hipStream_t stream) {
  const float* x_pkg     = (const float*)d_in[0];
  const float* x_dst     = (const float*)d_in[1];
  const float* edge_attr = (const float*)d_in[2];
  const float* node_mask = (const float*)d_in[3];
  const float* W1_src    = (const float*)d_in[4];
  const float* W1_dst    = (const float*)d_in[5];
  const float* att1      = (const float*)d_in[6];
  const float* b1        = (const float*)d_in[7];
  const float* W2_src    = (const float*)d_in[8];
  const float* W2_dst    = (const float*)d_in[9];
  const float* att2      = (const float*)d_in[10];
  const float* b2        = (const float*)d_in[11];
  const float* W_pool    = (const float*)d_in[12];
  const float* b_pool    = (const float*)d_in[13];
  const float* W_cls     = (const float*)d_in[14];
  const float* b_cls     = (const float*)d_in[15];
  const int*   edge_index= (const int*)d_in[16];
  float* out = (float*)d_out;

  // only t = 5 reaches the output (outs[-1]); slice all per-type params at t=5
  const int T5 = TT - 1;
  const float* W1s5 = W1_src + (size_t)T5*DIN*FDIM;
  const float* W1d5 = W1_dst + (size_t)T5*DIN*FDIM;
  const float* a1_5 = att1   + (size_t)T5*FDIM;
  const float* b1_5 = b1     + (size_t)T5*FDIM;
  const float* W2s5 = W2_src + (size_t)T5*DIN*FDIM;
  const float* W2d5 = W2_dst + (size_t)T5*FDIM*FDIM;
  const float* a2_5 = att2   + (size_t)T5*FDIM;
  const float* b2_5 = b2     + (size_t)T5*FDIM;
  const float* xd5  = x_dst  + (size_t)T5*NN*DIN;
  const int* src5   = edge_index + (size_t)T5*2*EE;
  const int* dst5   = src5 + EE;

  // workspace layout (f32 unless noted)
  float* buf0 = (float*)d_ws;            // hs1 -> hs2           [NN*256]
  float* buf1 = buf0 + (size_t)NN*FDIM;  // hd1 -> h1            [NN*256]
  float* buf2 = buf1 + (size_t)NN*FDIM;  // hd2 -> h2            [NN*256]
  float* elog = buf2 + (size_t)NN*FDIM;  // edge logits          [EE*4]
  float* sass = elog + (size_t)EE*4;     // s_assign             [NN*48]
  float* xpool= sass + (size_t)NN*KC;    // pooled               [48*256]
  float* aggE = xpool + KC*FDIM;         // edge-attr means      [48] (pad 64)
  int* deg    = (int*)(aggE + 64);       // [NN]
  int* rp     = deg + NN;                // row_ptr [NN+1]
  int* cursor = rp + NN + 1;             // [NN]
  int* eids   = cursor + NN;             // [EE]

  dim3 ggrid((NN + 63)/64, 4);

  // CSR over dst (shared by both GAT layers)
  zero_i32<<<(NN+255)/256, 256, 0, stream>>>(deg, NN);
  count_deg<<<(EE+255)/256, 256, 0, stream>>>(dst5, deg);
  excl_scan<<<1, 1024, 0, stream>>>(deg, rp, NN);
  copy_i32<<<(NN+255)/256, 256, 0, stream>>>(rp, cursor, NN);
  scatter_edges<<<(EE+255)/256, 256, 0, stream>>>(dst5, cursor, eids);

  // layer 1
  gemm_f32<<<ggrid, 256, 0, stream>>>(x_pkg, W1s5, node_mask, buf0, NN, DIN);   // hs1
  gemm_f32<<<ggrid, 256, 0, stream>>>(xd5,   W1d5, node_mask, buf1, NN, DIN);   // hd1
  edge_logits<<<EE/4, 256, 0, stream>>>(src5, dst5, buf0, buf1, a1_5, elog);
  aggregate<<<NN, 256, 0, stream>>>(rp, eids, src5, elog, buf0, b1_5, buf1, 1); // h1 (relu)

  // layer 2
  gemm_f32<<<ggrid, 256, 0, stream>>>(x_pkg, W2s5, node_mask, buf0, NN, DIN);   // hs2
  gemm_f32<<<ggrid, 256, 0, stream>>>(buf1,  W2d5, nullptr,  buf2, NN, FDIM);   // hd2 = h1 @ W2_dst
  edge_logits<<<EE/4, 256, 0, stream>>>(src5, dst5, buf0, buf2, a2_5, elog);
  aggregate<<<NN, 256, 0, stream>>>(rp, eids, src5, elog, buf0, b2_5, buf2, 0); // h2

  // pooling + classifier
  pool_softmax<<<NN/4, 256, 0, stream>>>(buf2, W_pool, b_pool, sass);
  zero_i32<<<(KC*FDIM+255)/256, 256, 0, stream>>>((int*)xpool, KC*FDIM);
  pooled_accum<<<128, 256, 0, stream>>>(sass, buf2, xpool);
  edge_attr_mean<<<TT*DE, 256, 0, stream>>>(edge_attr, aggE);
  final_cls<<<1, 64, 0, stream>>>(xpool, aggE, W_cls, b_cls, out);
}

// Round 2
// 1200.495 us; speedup vs baseline: 1.1318x; 1.1318x over previous
//
#include <hip/hip_runtime.h>
#include <math.h>

#define NN 50000      // nodes (both src and dst)
#define DIN 128
#define FDIM 256      // H*C
#define EE 200000
#define TT 6
#define DE 8
#define KC 48         // clusters

// ---------------- utility kernels ----------------
__global__ void zero_i32(int* __restrict__ p, int n){
  int i = blockIdx.x*256 + threadIdx.x;
  if (i < n) p[i] = 0;
}

__global__ void count_deg(const int* __restrict__ dst, int* __restrict__ deg){
  int i = blockIdx.x*256 + threadIdx.x;
  if (i < EE) atomicAdd(&deg[dst[i]], 1);
}

__global__ __launch_bounds__(1024) void excl_scan(const int* __restrict__ deg, int* __restrict__ rp, int n){
  __shared__ int sm[1024];
  int carry = 0;
  for (int base = 0; base < n; base += 1024){
    int i = base + (int)threadIdx.x;
    int v = (i < n) ? deg[i] : 0;
    __syncthreads();
    sm[threadIdx.x] = v;
    __syncthreads();
    for (int off = 1; off < 1024; off <<= 1){
      int t = (threadIdx.x >= (unsigned)off) ? sm[threadIdx.x - off] : 0;
      __syncthreads();
      sm[threadIdx.x] += t;
      __syncthreads();
    }
    if (i < n) rp[i] = carry + sm[threadIdx.x] - v;
    carry += sm[1023];
  }
  if (threadIdx.x == 0) rp[n] = carry;
}

__global__ void copy_i32(const int* __restrict__ a, int* __restrict__ b, int n){
  int i = blockIdx.x*256 + threadIdx.x;
  if (i < n) b[i] = a[i];
}

__global__ void scatter_edges(const int* __restrict__ dst, int* __restrict__ cursor, int* __restrict__ eids){
  int i = blockIdx.x*256 + threadIdx.x;
  if (i < EE){ int pos = atomicAdd(&cursor[dst[i]], 1); eids[pos] = i; }
}

// ---------------- GEMM: C[nrows,256] = (A * rowmask) @ W[K,256] ----------------
__global__ __launch_bounds__(256) void gemm_f32(const float* __restrict__ A, const float* __restrict__ W,
                                                const float* __restrict__ mask, float* __restrict__ Cm,
                                                int nrows, int K){
  __shared__ float As[16][68];
  __shared__ float Ws[16][64];
  int tid = threadIdx.x;
  int row0 = blockIdx.x * 64;
  int col0 = blockIdx.y * 64;
  int tx = tid & 15;
  int ty = tid >> 4;
  float acc[4][4] = {};
  for (int k0 = 0; k0 < K; k0 += 16){
    #pragma unroll
    for (int p = 0; p < 4; p++){
      int idx = tid + p*256;
      int r  = idx >> 4;
      int kk = idx & 15;
      int gr = row0 + r;
      float v = 0.f;
      if (gr < nrows){
        v = A[(size_t)gr*K + k0 + kk];
        if (mask) v *= mask[gr];
      }
      As[kk][r] = v;
    }
    #pragma unroll
    for (int p = 0; p < 4; p++){
      int idx = tid + p*256;
      int kk = idx >> 6;
      int c  = idx & 63;
      Ws[kk][c] = W[(size_t)(k0 + kk)*256 + col0 + c];
    }
    __syncthreads();
    #pragma unroll
    for (int kk = 0; kk < 16; kk++){
      float a[4], b[4];
      #pragma unroll
      for (int i = 0; i < 4; i++) a[i] = As[kk][ty*4 + i];
      #pragma unroll
      for (int j = 0; j < 4; j++) b[j] = Ws[kk][tx*4 + j];
      #pragma unroll
      for (int i = 0; i < 4; i++)
        #pragma unroll
        for (int j = 0; j < 4; j++)
          acc[i][j] = fmaf(a[i], b[j], acc[i][j]);
    }
    __syncthreads();
  }
  #pragma unroll
  for (int i = 0; i < 4; i++){
    int gr = row0 + ty*4 + i;
    if (gr < nrows){
      #pragma unroll
      for (int j = 0; j < 4; j++)
        Cm[(size_t)gr*256 + col0 + tx*4 + j] = acc[i][j];
    }
  }
}

// ---------------- edge logits: e[E][4] ----------------
__global__ __launch_bounds__(256) void edge_logits(const int* __restrict__ src, const int* __restrict__ dst,
                                                   const float* __restrict__ hs, const float* __restrict__ hd,
                                                   const float* __restrict__ att, float* __restrict__ eo){
  int eidx = blockIdx.x*4 + (threadIdx.x >> 6);
  int lane = threadIdx.x & 63;
  if (eidx >= EE) return;
  int s = src[eidx], d = dst[eidx];
  const float* ps = hs + (size_t)s*256;
  const float* pd = hd + (size_t)d*256;
  #pragma unroll
  for (int h = 0; h < 4; h++){
    float m = ps[h*64 + lane] + pd[h*64 + lane];
    float lr = (m > 0.f) ? m : 0.2f*m;
    float v = lr * att[h*64 + lane];
    #pragma unroll
    for (int off = 32; off > 0; off >>= 1) v += __shfl_down(v, off);
    if (lane == 0) eo[eidx*4 + h] = v;
  }
}

// ---------------- per-dst segment softmax + weighted aggregation ----------------
__global__ __launch_bounds__(256) void aggregate(const int* __restrict__ rp, const int* __restrict__ eids,
                                                 const int* __restrict__ src, const float* __restrict__ elog,
                                                 const float* __restrict__ hs, const float* __restrict__ bias,
                                                 float* __restrict__ out, int do_relu){
  int n = blockIdx.x;
  int t = threadIdx.x;
  int h = t >> 6;
  int beg = rp[n], end = rp[n+1];
  float mx = -INFINITY;
  for (int i = beg; i < end; i++) mx = fmaxf(mx, elog[eids[i]*4 + h]);
  float ssum = 0.f, acc = 0.f;
  for (int i = beg; i < end; i++){
    int eid = eids[i];
    float w = expf(elog[eid*4 + h] - mx);
    ssum += w;
    acc = fmaf(w, hs[(size_t)src[eid]*256 + t], acc);
  }
  float r = acc / (ssum + 1e-16f) + bias[t];
  if (do_relu) r = fmaxf(r, 0.f);
  out[(size_t)n*256 + t] = r;
}

// ---------------- pool: logits + row softmax -> s_assign[N][48] ----------------
__global__ __launch_bounds__(256) void pool_softmax(const float* __restrict__ h2, const float* __restrict__ Wp,
                                                    const float* __restrict__ bp, float* __restrict__ s_out){
  int node = blockIdx.x*4 + (threadIdx.x >> 6);
  int lane = threadIdx.x & 63;
  float acc = -INFINITY;
  if (lane < KC){
    acc = bp[lane];
    const float* hr = h2 + (size_t)node*256;
    for (int k = 0; k < 256; k++) acc = fmaf(hr[k], Wp[k*KC + lane], acc);
  }
  float mx = acc;
  #pragma unroll
  for (int off = 32; off > 0; off >>= 1) mx = fmaxf(mx, __shfl_xor(mx, off));
  float w = (lane < KC) ? expf(acc - mx) : 0.f;
  float sm = w;
  #pragma unroll
  for (int off = 32; off > 0; off >>= 1) sm += __shfl_xor(sm, off);
  if (lane < KC) s_out[(size_t)node*KC + lane] = w / sm;
}

// ---------------- x_pooled[48][256] += s.T @ h2 (split over node chunks) ----------------
__global__ __launch_bounds__(256) void pooled_accum(const float* __restrict__ s, const float* __restrict__ h2,
                                                    float* __restrict__ xp){
  __shared__ float sld[64][KC];
  int t = threadIdx.x;
  float acc[KC];
  #pragma unroll
  for (int k = 0; k < KC; k++) acc[k] = 0.f;
  int chunk = (NN + gridDim.x - 1) / gridDim.x;
  int nb = blockIdx.x * chunk;
  int ne = min(nb + chunk, NN);
  for (int base = nb; base < ne; base += 64){
    int cnt = min(64, ne - base);
    __syncthreads();
    for (int idx = t; idx < cnt*KC; idx += 256)
      sld[idx/KC][idx%KC] = s[(size_t)(base + idx/KC)*KC + idx%KC];
    __syncthreads();
    for (int n = 0; n < cnt; n++){
      float v = h2[(size_t)(base + n)*256 + t];
      #pragma unroll
      for (int k = 0; k < KC; k++) acc[k] = fmaf(sld[n][k], v, acc[k]);
    }
  }
  for (int k = 0; k < KC; k++) atomicAdd(&xp[k*256 + t], acc[k]);
}

// ---------------- edge_attr mean over E -> [48], parallel grid-stride ----------------
// grid = TT*BPT blocks; block handles a contiguous float4 chunk of one type.
// Thread's float4 index strides by 256 (even) so (i&1) is invariant -> fixed d-range,
// fully coalesced 16B/lane loads.
#define BPT 128
__global__ __launch_bounds__(256) void edge_attr_mean(const float* __restrict__ ea, float* __restrict__ out){
  int t   = blockIdx.x / BPT;
  int blk = blockIdx.x % BPT;
  const int NF4 = EE * 2;
  const int per_blk = (NF4 + BPT - 1) / BPT;
  int i0 = blk * per_blk;
  int i1 = min(i0 + per_blk, NF4);
  const float4* base = (const float4*)(ea + (size_t)t*EE*DE);
  float s[8] = {0,0,0,0,0,0,0,0};
  for (int i = i0 + (int)threadIdx.x; i < i1; i += 256){
    float4 v = base[i];
    int db = (i & 1) * 4;
    s[db+0] += v.x; s[db+1] += v.y; s[db+2] += v.z; s[db+3] += v.w;
  }
  __shared__ float red[256];
  for (int d = 0; d < 8; d++){
    red[threadIdx.x] = s[d];
    __syncthreads();
    for (int off = 128; off > 0; off >>= 1){
      if (threadIdx.x < (unsigned)off) red[threadIdx.x] += red[threadIdx.x + off];
      __syncthreads();
    }
    if (threadIdx.x == 0) atomicAdd(&out[t*DE + d], red[0] / (float)EE);
    __syncthreads();
  }
}

// ---------------- final classifier ----------------
__global__ void final_cls(const float* __restrict__ xp, const float* __restrict__ agg,
                          const float* __restrict__ Wc, const float* __restrict__ bc,
                          float* __restrict__ out){
  int k = threadIdx.x;
  if (k < KC){
    float s = bc[0];
    for (int f = 0; f < 256; f++) s = fmaf(xp[k*256 + f], Wc[f], s);
    s = fmaf(agg[k], Wc[256], s);
    out[k] = 1.f/(1.f + expf(-s));
  }
}

extern "C" void kernel_launch(void* const* d_in, const int* in_sizes, int n_in,
                              void* d_out, int out_size, void* d_ws, size_t ws_size,
                              hipStream_t stream) {
  const float* x_pkg     = (const float*)d_in[0];
  const float* x_dst     = (const float*)d_in[1];
  const float* edge_attr = (const float*)d_in[2];
  const float* node_mask = (const float*)d_in[3];
  const float* W1_src    = (const float*)d_in[4];
  const float* W1_dst    = (const float*)d_in[5];
  const float* att1      = (const float*)d_in[6];
  const float* b1        = (const float*)d_in[7];
  const float* W2_src    = (const float*)d_in[8];
  const float* W2_dst    = (const float*)d_in[9];
  const float* att2      = (const float*)d_in[10];
  const float* b2        = (const float*)d_in[11];
  const float* W_pool    = (const float*)d_in[12];
  const float* b_pool    = (const float*)d_in[13];
  const float* W_cls     = (const float*)d_in[14];
  const float* b_cls     = (const float*)d_in[15];
  const int*   edge_index= (const int*)d_in[16];
  float* out = (float*)d_out;

  const int T5 = TT - 1;
  const float* W1s5 = W1_src + (size_t)T5*DIN*FDIM;
  const float* W1d5 = W1_dst + (size_t)T5*DIN*FDIM;
  const float* a1_5 = att1   + (size_t)T5*FDIM;
  const float* b1_5 = b1     + (size_t)T5*FDIM;
  const float* W2s5 = W2_src + (size_t)T5*DIN*FDIM;
  const float* W2d5 = W2_dst + (size_t)T5*FDIM*FDIM;
  const float* a2_5 = att2   + (size_t)T5*FDIM;
  const float* b2_5 = b2     + (size_t)T5*FDIM;
  const float* xd5  = x_dst  + (size_t)T5*NN*DIN;
  const int* src5   = edge_index + (size_t)T5*2*EE;
  const int* dst5   = src5 + EE;

  float* buf0 = (float*)d_ws;
  float* buf1 = buf0 + (size_t)NN*FDIM;
  float* buf2 = buf1 + (size_t)NN*FDIM;
  float* elog = buf2 + (size_t)NN*FDIM;
  float* sass = elog + (size_t)EE*4;
  float* xpool= sass + (size_t)NN*KC;
  float* aggE = xpool + KC*FDIM;
  int* deg    = (int*)(aggE + 64);
  int* rp     = deg + NN;
  int* cursor = rp + NN + 1;
  int* eids   = cursor + NN;

  dim3 ggrid((NN + 63)/64, 4);

  // CSR over dst (shared by both GAT layers)
  zero_i32<<<(NN+255)/256, 256, 0, stream>>>(deg, NN);
  count_deg<<<(EE+255)/256, 256, 0, stream>>>(dst5, deg);
  excl_scan<<<1, 1024, 0, stream>>>(deg, rp, NN);
  copy_i32<<<(NN+255)/256, 256, 0, stream>>>(rp, cursor, NN);
  scatter_edges<<<(EE+255)/256, 256, 0, stream>>>(dst5, cursor, eids);

  // edge_attr mean (independent path)
  zero_i32<<<1, 64, 0, stream>>>((int*)aggE, 64);
  edge_attr_mean<<<TT*BPT, 256, 0, stream>>>(edge_attr, aggE);

  // layer 1
  gemm_f32<<<ggrid, 256, 0, stream>>>(x_pkg, W1s5, node_mask, buf0, NN, DIN);   // hs1
  gemm_f32<<<ggrid, 256, 0, stream>>>(xd5,   W1d5, node_mask, buf1, NN, DIN);   // hd1
  edge_logits<<<EE/4, 256, 0, stream>>>(src5, dst5, buf0, buf1, a1_5, elog);
  aggregate<<<NN, 256, 0, stream>>>(rp, eids, src5, elog, buf0, b1_5, buf1, 1); // h1 (relu)

  // layer 2
  gemm_f32<<<ggrid, 256, 0, stream>>>(x_pkg, W2s5, node_mask, buf0, NN, DIN);   // hs2
  gemm_f32<<<ggrid, 256, 0, stream>>>(buf1,  W2d5, nullptr,  buf2, NN, FDIM);   // hd2
  edge_logits<<<EE/4, 256, 0, stream>>>(src5, dst5, buf0, buf2, a2_5, elog);
  aggregate<<<NN, 256, 0, stream>>>(rp, eids, src5, elog, buf0, b2_5, buf2, 0); // h2

  // pooling + classifier
  pool_softmax<<<NN/4, 256, 0, stream>>>(buf2, W_pool, b_pool, sass);
  zero_i32<<<(KC*FDIM+255)/256, 256, 0, stream>>>((int*)xpool, KC*FDIM);
  pooled_accum<<<128, 256, 0, stream>>>(sass, buf2, xpool);
  final_cls<<<1, 64, 0, stream>>>(xpool, aggE, W_cls, b_cls, out);
}

// Round 3
// 1040.201 us; speedup vs baseline: 1.3062x; 1.1541x over previous
//
#include <hip/hip_runtime.h>
#include <math.h>

#define NN 50000      // nodes (both src and dst)
#define DIN 128
#define FDIM 256      // H*C
#define EE 200000
#define TT 6
#define DE 8
#define KC 48         // clusters

// ---------------- utility kernels ----------------
__global__ void zero_i32(int* __restrict__ p, int n){
  int i = blockIdx.x*256 + threadIdx.x;
  if (i < n) p[i] = 0;
}

__global__ void count_deg(const int* __restrict__ dst, int* __restrict__ deg){
  int i = blockIdx.x*256 + threadIdx.x;
  if (i < EE) atomicAdd(&deg[dst[i]], 1);
}

__global__ __launch_bounds__(1024) void excl_scan(const int* __restrict__ deg, int* __restrict__ rp, int n){
  __shared__ int sm[1024];
  int carry = 0;
  for (int base = 0; base < n; base += 1024){
    int i = base + (int)threadIdx.x;
    int v = (i < n) ? deg[i] : 0;
    __syncthreads();
    sm[threadIdx.x] = v;
    __syncthreads();
    for (int off = 1; off < 1024; off <<= 1){
      int t = (threadIdx.x >= (unsigned)off) ? sm[threadIdx.x - off] : 0;
      __syncthreads();
      sm[threadIdx.x] += t;
      __syncthreads();
    }
    if (i < n) rp[i] = carry + sm[threadIdx.x] - v;
    carry += sm[1023];
  }
  if (threadIdx.x == 0) rp[n] = carry;
}

__global__ void copy_i32(const int* __restrict__ a, int* __restrict__ b, int n){
  int i = blockIdx.x*256 + threadIdx.x;
  if (i < n) b[i] = a[i];
}

__global__ void scatter_edges(const int* __restrict__ dst, int* __restrict__ cursor, int* __restrict__ eids){
  int i = blockIdx.x*256 + threadIdx.x;
  if (i < EE){ int pos = atomicAdd(&cursor[dst[i]], 1); eids[pos] = i; }
}

// ---------------- GEMM: C[nrows,256] = (A * rowmask) @ W[K,256] ----------------
__global__ __launch_bounds__(256) void gemm_f32(const float* __restrict__ A, const float* __restrict__ W,
                                                const float* __restrict__ mask, float* __restrict__ Cm,
                                                int nrows, int K){
  __shared__ float As[16][68];
  __shared__ float Ws[16][64];
  int tid = threadIdx.x;
  int row0 = blockIdx.x * 64;
  int col0 = blockIdx.y * 64;
  int tx = tid & 15;
  int ty = tid >> 4;
  float acc[4][4] = {};
  for (int k0 = 0; k0 < K; k0 += 16){
    #pragma unroll
    for (int p = 0; p < 4; p++){
      int idx = tid + p*256;
      int r  = idx >> 4;
      int kk = idx & 15;
      int gr = row0 + r;
      float v = 0.f;
      if (gr < nrows){
        v = A[(size_t)gr*K + k0 + kk];
        if (mask) v *= mask[gr];
      }
      As[kk][r] = v;
    }
    #pragma unroll
    for (int p = 0; p < 4; p++){
      int idx = tid + p*256;
      int kk = idx >> 6;
      int c  = idx & 63;
      Ws[kk][c] = W[(size_t)(k0 + kk)*256 + col0 + c];
    }
    __syncthreads();
    #pragma unroll
    for (int kk = 0; kk < 16; kk++){
      float a[4], b[4];
      #pragma unroll
      for (int i = 0; i < 4; i++) a[i] = As[kk][ty*4 + i];
      #pragma unroll
      for (int j = 0; j < 4; j++) b[j] = Ws[kk][tx*4 + j];
      #pragma unroll
      for (int i = 0; i < 4; i++)
        #pragma unroll
        for (int j = 0; j < 4; j++)
          acc[i][j] = fmaf(a[i], b[j], acc[i][j]);
    }
    __syncthreads();
  }
  #pragma unroll
  for (int i = 0; i < 4; i++){
    int gr = row0 + ty*4 + i;
    if (gr < nrows){
      #pragma unroll
      for (int j = 0; j < 4; j++)
        Cm[(size_t)gr*256 + col0 + tx*4 + j] = acc[i][j];
    }
  }
}

// ---------------- edge logits: e[E][4] ----------------
__global__ __launch_bounds__(256) void edge_logits(const int* __restrict__ src, const int* __restrict__ dst,
                                                   const float* __restrict__ hs, const float* __restrict__ hd,
                                                   const float* __restrict__ att, float* __restrict__ eo){
  int eidx = blockIdx.x*4 + (threadIdx.x >> 6);
  int lane = threadIdx.x & 63;
  if (eidx >= EE) return;
  int s = src[eidx], d = dst[eidx];
  const float* ps = hs + (size_t)s*256;
  const float* pd = hd + (size_t)d*256;
  #pragma unroll
  for (int h = 0; h < 4; h++){
    float m = ps[h*64 + lane] + pd[h*64 + lane];
    float lr = (m > 0.f) ? m : 0.2f*m;
    float v = lr * att[h*64 + lane];
    #pragma unroll
    for (int off = 32; off > 0; off >>= 1) v += __shfl_down(v, off);
    if (lane == 0) eo[eidx*4 + h] = v;
  }
}

// ---------------- per-dst segment softmax + weighted aggregation ----------------
__global__ __launch_bounds__(256) void aggregate(const int* __restrict__ rp, const int* __restrict__ eids,
                                                 const int* __restrict__ src, const float* __restrict__ elog,
                                                 const float* __restrict__ hs, const float* __restrict__ bias,
                                                 float* __restrict__ out, int do_relu){
  int n = blockIdx.x;
  int t = threadIdx.x;
  int h = t >> 6;
  int beg = rp[n], end = rp[n+1];
  float mx = -INFINITY;
  for (int i = beg; i < end; i++) mx = fmaxf(mx, elog[eids[i]*4 + h]);
  float ssum = 0.f, acc = 0.f;
  for (int i = beg; i < end; i++){
    int eid = eids[i];
    float w = expf(elog[eid*4 + h] - mx);
    ssum += w;
    acc = fmaf(w, hs[(size_t)src[eid]*256 + t], acc);
  }
  float r = acc / (ssum + 1e-16f) + bias[t];
  if (do_relu) r = fmaxf(r, 0.f);
  out[(size_t)n*256 + t] = r;
}

// ---------------- pool: logits + row softmax -> s_assign[N][48] ----------------
__global__ __launch_bounds__(256) void pool_softmax(const float* __restrict__ h2, const float* __restrict__ Wp,
                                                    const float* __restrict__ bp, float* __restrict__ s_out){
  int node = blockIdx.x*4 + (threadIdx.x >> 6);
  int lane = threadIdx.x & 63;
  float acc = -INFINITY;
  if (lane < KC){
    acc = bp[lane];
    const float* hr = h2 + (size_t)node*256;
    for (int k = 0; k < 256; k++) acc = fmaf(hr[k], Wp[k*KC + lane], acc);
  }
  float mx = acc;
  #pragma unroll
  for (int off = 32; off > 0; off >>= 1) mx = fmaxf(mx, __shfl_xor(mx, off));
  float w = (lane < KC) ? expf(acc - mx) : 0.f;
  float sm = w;
  #pragma unroll
  for (int off = 32; off > 0; off >>= 1) sm += __shfl_xor(sm, off);
  if (lane < KC) s_out[(size_t)node*KC + lane] = w / sm;
}

// ---------------- x_pooled = s.T @ h2, split-K two-stage ----------------
#define PCH 64
#define NPART ((NN + PCH - 1)/PCH)   // 782
// stage 1: one block per 64-node chunk, private partial [48][256], no atomics
__global__ __launch_bounds__(256) void pooled_partial(const float* __restrict__ s, const float* __restrict__ h2,
                                                      float* __restrict__ part){
  __shared__ float sld[PCH][KC];
  int t = threadIdx.x;
  int base = blockIdx.x * PCH;
  int cnt = min(PCH, NN - base);
  for (int idx = t; idx < cnt*KC; idx += 256)
    sld[idx/KC][idx%KC] = s[(size_t)(base + idx/KC)*KC + idx%KC];
  __syncthreads();
  float acc[KC];
  #pragma unroll
  for (int k = 0; k < KC; k++) acc[k] = 0.f;
  for (int n = 0; n < cnt; n++){
    float v = h2[(size_t)(base + n)*256 + t];
    #pragma unroll
    for (int k = 0; k < KC; k++) acc[k] = fmaf(sld[n][k], v, acc[k]);
  }
  float* po = part + (size_t)blockIdx.x*KC*256;
  #pragma unroll
  for (int k = 0; k < KC; k++) po[k*256 + t] = acc[k];
}
// stage 2: reduce 782 partials; grid (48, PSPL); 8 atomic contenders/address
#define PSPL 8
__global__ __launch_bounds__(256) void pooled_reduce(const float* __restrict__ part, float* __restrict__ xp){
  int idx = blockIdx.x*256 + threadIdx.x;     // 0..12287
  const int per = (NPART + PSPL - 1)/PSPL;    // 98
  int p0 = blockIdx.y * per;
  int p1 = min(p0 + per, NPART);
  float s0 = 0.f, s1 = 0.f;
  int p = p0;
  for (; p + 1 < p1; p += 2){
    s0 += part[(size_t)p*KC*256 + idx];
    s1 += part[(size_t)(p+1)*KC*256 + idx];
  }
  if (p < p1) s0 += part[(size_t)p*KC*256 + idx];
  atomicAdd(&xp[idx], s0 + s1);
}

// ---------------- edge_attr mean over E -> [48], parallel grid-stride ----------------
#define BPT 128
__global__ __launch_bounds__(256) void edge_attr_mean(const float* __restrict__ ea, float* __restrict__ out){
  int t   = blockIdx.x / BPT;
  int blk = blockIdx.x % BPT;
  const int NF4 = EE * 2;
  const int per_blk = (NF4 + BPT - 1) / BPT;
  int i0 = blk * per_blk;
  int i1 = min(i0 + per_blk, NF4);
  const float4* base = (const float4*)(ea + (size_t)t*EE*DE);
  float s[8] = {0,0,0,0,0,0,0,0};
  for (int i = i0 + (int)threadIdx.x; i < i1; i += 256){
    float4 v = base[i];
    int db = (i & 1) * 4;
    s[db+0] += v.x; s[db+1] += v.y; s[db+2] += v.z; s[db+3] += v.w;
  }
  __shared__ float red[256];
  for (int d = 0; d < 8; d++){
    red[threadIdx.x] = s[d];
    __syncthreads();
    for (int off = 128; off > 0; off >>= 1){
      if (threadIdx.x < (unsigned)off) red[threadIdx.x] += red[threadIdx.x + off];
      __syncthreads();
    }
    if (threadIdx.x == 0) atomicAdd(&out[t*DE + d], red[0] / (float)EE);
    __syncthreads();
  }
}

// ---------------- final classifier ----------------
__global__ void final_cls(const float* __restrict__ xp, const float* __restrict__ agg,
                          const float* __restrict__ Wc, const float* __restrict__ bc,
                          float* __restrict__ out){
  int k = threadIdx.x;
  if (k < KC){
    float s = bc[0];
    for (int f = 0; f < 256; f++) s = fmaf(xp[k*256 + f], Wc[f], s);
    s = fmaf(agg[k], Wc[256], s);
    out[k] = 1.f/(1.f + expf(-s));
  }
}

extern "C" void kernel_launch(void* const* d_in, const int* in_sizes, int n_in,
                              void* d_out, int out_size, void* d_ws, size_t ws_size,
                              hipStream_t stream) {
  const float* x_pkg     = (const float*)d_in[0];
  const float* x_dst     = (const float*)d_in[1];
  const float* edge_attr = (const float*)d_in[2];
  const float* node_mask = (const float*)d_in[3];
  const float* W1_src    = (const float*)d_in[4];
  const float* W1_dst    = (const float*)d_in[5];
  const float* att1      = (const float*)d_in[6];
  const float* b1        = (const float*)d_in[7];
  const float* W2_src    = (const float*)d_in[8];
  const float* W2_dst    = (const float*)d_in[9];
  const float* att2      = (const float*)d_in[10];
  const float* b2        = (const float*)d_in[11];
  const float* W_pool    = (const float*)d_in[12];
  const float* b_pool    = (const float*)d_in[13];
  const float* W_cls     = (const float*)d_in[14];
  const float* b_cls     = (const float*)d_in[15];
  const int*   edge_index= (const int*)d_in[16];
  float* out = (float*)d_out;

  const int T5 = TT - 1;
  const float* W1s5 = W1_src + (size_t)T5*DIN*FDIM;
  const float* W1d5 = W1_dst + (size_t)T5*DIN*FDIM;
  const float* a1_5 = att1   + (size_t)T5*FDIM;
  const float* b1_5 = b1     + (size_t)T5*FDIM;
  const float* W2s5 = W2_src + (size_t)T5*DIN*FDIM;
  const float* W2d5 = W2_dst + (size_t)T5*FDIM*FDIM;
  const float* a2_5 = att2   + (size_t)T5*FDIM;
  const float* b2_5 = b2     + (size_t)T5*FDIM;
  const float* xd5  = x_dst  + (size_t)T5*NN*DIN;
  const int* src5   = edge_index + (size_t)T5*2*EE;
  const int* dst5   = src5 + EE;

  float* buf0 = (float*)d_ws;            // hs1 -> hs2 -> pooled partials
  float* buf1 = buf0 + (size_t)NN*FDIM;  // hd1 -> h1
  float* buf2 = buf1 + (size_t)NN*FDIM;  // hd2 -> h2
  float* elog = buf2 + (size_t)NN*FDIM;
  float* sass = elog + (size_t)EE*4;
  float* xpool= sass + (size_t)NN*KC;
  float* aggE = xpool + KC*FDIM;
  int* deg    = (int*)(aggE + 64);
  int* rp     = deg + NN;
  int* cursor = rp + NN + 1;
  int* eids   = cursor + NN;

  dim3 ggrid((NN + 63)/64, 4);

  // CSR over dst (shared by both GAT layers)
  zero_i32<<<(NN+255)/256, 256, 0, stream>>>(deg, NN);
  count_deg<<<(EE+255)/256, 256, 0, stream>>>(dst5, deg);
  excl_scan<<<1, 1024, 0, stream>>>(deg, rp, NN);
  copy_i32<<<(NN+255)/256, 256, 0, stream>>>(rp, cursor, NN);
  scatter_edges<<<(EE+255)/256, 256, 0, stream>>>(dst5, cursor, eids);

  // edge_attr mean (independent path)
  zero_i32<<<1, 64, 0, stream>>>((int*)aggE, 64);
  edge_attr_mean<<<TT*BPT, 256, 0, stream>>>(edge_attr, aggE);

  // layer 1
  gemm_f32<<<ggrid, 256, 0, stream>>>(x_pkg, W1s5, node_mask, buf0, NN, DIN);   // hs1
  gemm_f32<<<ggrid, 256, 0, stream>>>(xd5,   W1d5, node_mask, buf1, NN, DIN);   // hd1
  edge_logits<<<EE/4, 256, 0, stream>>>(src5, dst5, buf0, buf1, a1_5, elog);
  aggregate<<<NN, 256, 0, stream>>>(rp, eids, src5, elog, buf0, b1_5, buf1, 1); // h1 (relu)

  // layer 2
  gemm_f32<<<ggrid, 256, 0, stream>>>(x_pkg, W2s5, node_mask, buf0, NN, DIN);   // hs2
  gemm_f32<<<ggrid, 256, 0, stream>>>(buf1,  W2d5, nullptr,  buf2, NN, FDIM);   // hd2
  edge_logits<<<EE/4, 256, 0, stream>>>(src5, dst5, buf0, buf2, a2_5, elog);
  aggregate<<<NN, 256, 0, stream>>>(rp, eids, src5, elog, buf0, b2_5, buf2, 0); // h2

  // pooling + classifier (buf0 is free after layer-2 aggregate -> reuse for partials)
  pool_softmax<<<NN/4, 256, 0, stream>>>(buf2, W_pool, b_pool, sass);
  zero_i32<<<(KC*FDIM+255)/256, 256, 0, stream>>>((int*)xpool, KC*FDIM);
  pooled_partial<<<NPART, 256, 0, stream>>>(sass, buf2, buf0);
  pooled_reduce<<<dim3(KC, PSPL), 256, 0, stream>>>(buf0, xpool);
  final_cls<<<1, 64, 0, stream>>>(xpool, aggE, W_cls, b_cls, out);
}

// Round 4
// 916.242 us; speedup vs baseline: 1.4830x; 1.1353x over previous
//
#include <hip/hip_runtime.h>
#include <math.h>

#define NN 50000      // nodes (both src and dst)
#define DIN 128
#define FDIM 256      // H*C
#define EE 200000
#define TT 6
#define DE 8
#define KC 48         // clusters

// ---------------- utility kernels ----------------
__global__ void zero_i32(int* __restrict__ p, int n){
  int i = blockIdx.x*256 + threadIdx.x;
  if (i < n) p[i] = 0;
}

__global__ void count_deg(const int* __restrict__ dst, int* __restrict__ deg){
  int i = blockIdx.x*256 + threadIdx.x;
  if (i < EE) atomicAdd(&deg[dst[i]], 1);
}

__global__ __launch_bounds__(1024) void excl_scan(const int* __restrict__ deg, int* __restrict__ rp, int n){
  __shared__ int sm[1024];
  int carry = 0;
  for (int base = 0; base < n; base += 1024){
    int i = base + (int)threadIdx.x;
    int v = (i < n) ? deg[i] : 0;
    __syncthreads();
    sm[threadIdx.x] = v;
    __syncthreads();
    for (int off = 1; off < 1024; off <<= 1){
      int t = (threadIdx.x >= (unsigned)off) ? sm[threadIdx.x - off] : 0;
      __syncthreads();
      sm[threadIdx.x] += t;
      __syncthreads();
    }
    if (i < n) rp[i] = carry + sm[threadIdx.x] - v;
    carry += sm[1023];
  }
  if (threadIdx.x == 0) rp[n] = carry;
}

__global__ void copy_i32(const int* __restrict__ a, int* __restrict__ b, int n){
  int i = blockIdx.x*256 + threadIdx.x;
  if (i < n) b[i] = a[i];
}

__global__ void scatter_edges(const int* __restrict__ dst, int* __restrict__ cursor, int* __restrict__ eids){
  int i = blockIdx.x*256 + threadIdx.x;
  if (i < EE){ int pos = atomicAdd(&cursor[dst[i]], 1); eids[pos] = i; }
}

// ---------------- GEMM: C[nrows,256] = (A * rowmask) @ W[K,256] ----------------
__global__ __launch_bounds__(256) void gemm_f32(const float* __restrict__ A, const float* __restrict__ W,
                                                const float* __restrict__ mask, float* __restrict__ Cm,
                                                int nrows, int K){
  __shared__ float As[16][68];
  __shared__ float Ws[16][64];
  int tid = threadIdx.x;
  int row0 = blockIdx.x * 64;
  int col0 = blockIdx.y * 64;
  int tx = tid & 15;
  int ty = tid >> 4;
  float acc[4][4] = {};
  for (int k0 = 0; k0 < K; k0 += 16){
    #pragma unroll
    for (int p = 0; p < 4; p++){
      int idx = tid + p*256;
      int r  = idx >> 4;
      int kk = idx & 15;
      int gr = row0 + r;
      float v = 0.f;
      if (gr < nrows){
        v = A[(size_t)gr*K + k0 + kk];
        if (mask) v *= mask[gr];
      }
      As[kk][r] = v;
    }
    #pragma unroll
    for (int p = 0; p < 4; p++){
      int idx = tid + p*256;
      int kk = idx >> 6;
      int c  = idx & 63;
      Ws[kk][c] = W[(size_t)(k0 + kk)*256 + col0 + c];
    }
    __syncthreads();
    #pragma unroll
    for (int kk = 0; kk < 16; kk++){
      float a[4], b[4];
      #pragma unroll
      for (int i = 0; i < 4; i++) a[i] = As[kk][ty*4 + i];
      #pragma unroll
      for (int j = 0; j < 4; j++) b[j] = Ws[kk][tx*4 + j];
      #pragma unroll
      for (int i = 0; i < 4; i++)
        #pragma unroll
        for (int j = 0; j < 4; j++)
          acc[i][j] = fmaf(a[i], b[j], acc[i][j]);
    }
    __syncthreads();
  }
  #pragma unroll
  for (int i = 0; i < 4; i++){
    int gr = row0 + ty*4 + i;
    if (gr < nrows){
      #pragma unroll
      for (int j = 0; j < 4; j++)
        Cm[(size_t)gr*256 + col0 + tx*4 + j] = acc[i][j];
    }
  }
}

// ---------------- edge logits: e[E][4] ----------------
__global__ __launch_bounds__(256) void edge_logits(const int* __restrict__ src, const int* __restrict__ dst,
                                                   const float* __restrict__ hs, const float* __restrict__ hd,
                                                   const float* __restrict__ att, float* __restrict__ eo){
  int eidx = blockIdx.x*4 + (threadIdx.x >> 6);
  int lane = threadIdx.x & 63;
  if (eidx >= EE) return;
  int s = src[eidx], d = dst[eidx];
  const float* ps = hs + (size_t)s*256;
  const float* pd = hd + (size_t)d*256;
  #pragma unroll
  for (int h = 0; h < 4; h++){
    float m = ps[h*64 + lane] + pd[h*64 + lane];
    float lr = (m > 0.f) ? m : 0.2f*m;
    float v = lr * att[h*64 + lane];
    #pragma unroll
    for (int off = 32; off > 0; off >>= 1) v += __shfl_down(v, off);
    if (lane == 0) eo[eidx*4 + h] = v;
  }
}

// ---------------- per-dst segment softmax + weighted aggregation ----------------
__global__ __launch_bounds__(256) void aggregate(const int* __restrict__ rp, const int* __restrict__ eids,
                                                 const int* __restrict__ src, const float* __restrict__ elog,
                                                 const float* __restrict__ hs, const float* __restrict__ bias,
                                                 float* __restrict__ out, int do_relu){
  int n = blockIdx.x;
  int t = threadIdx.x;
  int h = t >> 6;
  int beg = rp[n], end = rp[n+1];
  float mx = -INFINITY;
  for (int i = beg; i < end; i++) mx = fmaxf(mx, elog[eids[i]*4 + h]);
  float ssum = 0.f, acc = 0.f;
  for (int i = beg; i < end; i++){
    int eid = eids[i];
    float w = expf(elog[eid*4 + h] - mx);
    ssum += w;
    acc = fmaf(w, hs[(size_t)src[eid]*256 + t], acc);
  }
  float r = acc / (ssum + 1e-16f) + bias[t];
  if (do_relu) r = fmaxf(r, 0.f);
  out[(size_t)n*256 + t] = r;
}

// ---------------- pool logits GEMM + fused row softmax -> s_assign[N][48] ----------------
// grid: 782 blocks of 64 rows. Thread (ty,tx): ty=tid>>4 owns 4 rows, tx=tid&15 owns 3 cols.
// Row softmax reduces across the 16-lane tx group via __shfl_xor.
__global__ __launch_bounds__(256) void pool_logits_sm(const float* __restrict__ h2, const float* __restrict__ Wp,
                                                      const float* __restrict__ bp, float* __restrict__ s_out){
  __shared__ float As[16][68];   // [kk][row]
  __shared__ float Ws[16][KC];   // [kk][col]
  int tid = threadIdx.x;
  int row0 = blockIdx.x * 64;
  int tx = tid & 15;
  int ty = tid >> 4;
  float acc[4][3] = {};
  for (int k0 = 0; k0 < 256; k0 += 16){
    #pragma unroll
    for (int p = 0; p < 4; p++){
      int idx = tid + p*256;
      int r  = idx >> 4;
      int kk = idx & 15;
      int gr = row0 + r;
      As[kk][r] = (gr < NN) ? h2[(size_t)gr*256 + k0 + kk] : 0.f;
    }
    // 16x48 = 768 elements
    {
      int idx = tid;
      if (idx < 768) Ws[idx/KC][idx%KC] = Wp[(size_t)(k0 + idx/KC)*KC + idx%KC];
      idx = tid + 256;
      Ws[idx/KC][idx%KC] = Wp[(size_t)(k0 + idx/KC)*KC + idx%KC];
      idx = tid + 512;
      Ws[idx/KC][idx%KC] = Wp[(size_t)(k0 + idx/KC)*KC + idx%KC];
    }
    __syncthreads();
    #pragma unroll
    for (int kk = 0; kk < 16; kk++){
      float a[4], b[3];
      #pragma unroll
      for (int i = 0; i < 4; i++) a[i] = As[kk][ty*4 + i];
      #pragma unroll
      for (int j = 0; j < 3; j++) b[j] = Ws[kk][tx*3 + j];
      #pragma unroll
      for (int i = 0; i < 4; i++)
        #pragma unroll
        for (int j = 0; j < 3; j++)
          acc[i][j] = fmaf(a[i], b[j], acc[i][j]);
    }
    __syncthreads();
  }
  // bias + row softmax (reduce across tx group: lanes with same ty are 16 consecutive lanes)
  float bb[3];
  #pragma unroll
  for (int j = 0; j < 3; j++) bb[j] = bp[tx*3 + j];
  #pragma unroll
  for (int i = 0; i < 4; i++){
    int gr = row0 + ty*4 + i;
    float m = -INFINITY;
    #pragma unroll
    for (int j = 0; j < 3; j++){ acc[i][j] += bb[j]; m = fmaxf(m, acc[i][j]); }
    #pragma unroll
    for (int mask = 8; mask > 0; mask >>= 1) m = fmaxf(m, __shfl_xor(m, mask));
    float e[3], s = 0.f;
    #pragma unroll
    for (int j = 0; j < 3; j++){ e[j] = expf(acc[i][j] - m); s += e[j]; }
    #pragma unroll
    for (int mask = 8; mask > 0; mask >>= 1) s += __shfl_xor(s, mask);
    float inv = 1.f / s;
    if (gr < NN){
      #pragma unroll
      for (int j = 0; j < 3; j++) s_out[(size_t)gr*KC + tx*3 + j] = e[j] * inv;
    }
  }
}

// ---------------- x_pooled = s.T @ h2, split-K two-stage ----------------
#define PCH 64
#define NPART ((NN + PCH - 1)/PCH)   // 782
__global__ __launch_bounds__(256) void pooled_partial(const float* __restrict__ s, const float* __restrict__ h2,
                                                      float* __restrict__ part){
  __shared__ float sld[PCH][KC];
  int t = threadIdx.x;
  int base = blockIdx.x * PCH;
  int cnt = min(PCH, NN - base);
  for (int idx = t; idx < cnt*KC; idx += 256)
    sld[idx/KC][idx%KC] = s[(size_t)(base + idx/KC)*KC + idx%KC];
  __syncthreads();
  float acc[KC];
  #pragma unroll
  for (int k = 0; k < KC; k++) acc[k] = 0.f;
  for (int n = 0; n < cnt; n++){
    float v = h2[(size_t)(base + n)*256 + t];
    #pragma unroll
    for (int k = 0; k < KC; k++) acc[k] = fmaf(sld[n][k], v, acc[k]);
  }
  float* po = part + (size_t)blockIdx.x*KC*256;
  #pragma unroll
  for (int k = 0; k < KC; k++) po[k*256 + t] = acc[k];
}
#define PSPL 8
__global__ __launch_bounds__(256) void pooled_reduce(const float* __restrict__ part, float* __restrict__ xp){
  int idx = blockIdx.x*256 + threadIdx.x;     // 0..12287
  const int per = (NPART + PSPL - 1)/PSPL;    // 98
  int p0 = blockIdx.y * per;
  int p1 = min(p0 + per, NPART);
  float s0 = 0.f, s1 = 0.f;
  int p = p0;
  for (; p + 1 < p1; p += 2){
    s0 += part[(size_t)p*KC*256 + idx];
    s1 += part[(size_t)(p+1)*KC*256 + idx];
  }
  if (p < p1) s0 += part[(size_t)p*KC*256 + idx];
  atomicAdd(&xp[idx], s0 + s1);
}

// ---------------- edge_attr mean over E -> [48], parallel grid-stride ----------------
#define BPT 128
__global__ __launch_bounds__(256) void edge_attr_mean(const float* __restrict__ ea, float* __restrict__ out){
  int t   = blockIdx.x / BPT;
  int blk = blockIdx.x % BPT;
  const int NF4 = EE * 2;
  const int per_blk = (NF4 + BPT - 1) / BPT;
  int i0 = blk * per_blk;
  int i1 = min(i0 + per_blk, NF4);
  const float4* base = (const float4*)(ea + (size_t)t*EE*DE);
  float s[8] = {0,0,0,0,0,0,0,0};
  for (int i = i0 + (int)threadIdx.x; i < i1; i += 256){
    float4 v = base[i];
    int db = (i & 1) * 4;
    s[db+0] += v.x; s[db+1] += v.y; s[db+2] += v.z; s[db+3] += v.w;
  }
  __shared__ float red[256];
  for (int d = 0; d < 8; d++){
    red[threadIdx.x] = s[d];
    __syncthreads();
    for (int off = 128; off > 0; off >>= 1){
      if (threadIdx.x < (unsigned)off) red[threadIdx.x] += red[threadIdx.x + off];
      __syncthreads();
    }
    if (threadIdx.x == 0) atomicAdd(&out[t*DE + d], red[0] / (float)EE);
    __syncthreads();
  }
}

// ---------------- final classifier ----------------
__global__ void final_cls(const float* __restrict__ xp, const float* __restrict__ agg,
                          const float* __restrict__ Wc, const float* __restrict__ bc,
                          float* __restrict__ out){
  int k = threadIdx.x;
  if (k < KC){
    float s = bc[0];
    for (int f = 0; f < 256; f++) s = fmaf(xp[k*256 + f], Wc[f], s);
    s = fmaf(agg[k], Wc[256], s);
    out[k] = 1.f/(1.f + expf(-s));
  }
}

extern "C" void kernel_launch(void* const* d_in, const int* in_sizes, int n_in,
                              void* d_out, int out_size, void* d_ws, size_t ws_size,
                              hipStream_t stream) {
  const float* x_pkg     = (const float*)d_in[0];
  const float* x_dst     = (const float*)d_in[1];
  const float* edge_attr = (const float*)d_in[2];
  const float* node_mask = (const float*)d_in[3];
  const float* W1_src    = (const float*)d_in[4];
  const float* W1_dst    = (const float*)d_in[5];
  const float* att1      = (const float*)d_in[6];
  const float* b1        = (const float*)d_in[7];
  const float* W2_src    = (const float*)d_in[8];
  const float* W2_dst    = (const float*)d_in[9];
  const float* att2      = (const float*)d_in[10];
  const float* b2        = (const float*)d_in[11];
  const float* W_pool    = (const float*)d_in[12];
  const float* b_pool    = (const float*)d_in[13];
  const float* W_cls     = (const float*)d_in[14];
  const float* b_cls     = (const float*)d_in[15];
  const int*   edge_index= (const int*)d_in[16];
  float* out = (float*)d_out;

  const int T5 = TT - 1;
  const float* W1s5 = W1_src + (size_t)T5*DIN*FDIM;
  const float* W1d5 = W1_dst + (size_t)T5*DIN*FDIM;
  const float* a1_5 = att1   + (size_t)T5*FDIM;
  const float* b1_5 = b1     + (size_t)T5*FDIM;
  const float* W2s5 = W2_src + (size_t)T5*DIN*FDIM;
  const float* W2d5 = W2_dst + (size_t)T5*FDIM*FDIM;
  const float* a2_5 = att2   + (size_t)T5*FDIM;
  const float* b2_5 = b2     + (size_t)T5*FDIM;
  const float* xd5  = x_dst  + (size_t)T5*NN*DIN;
  const int* src5   = edge_index + (size_t)T5*2*EE;
  const int* dst5   = src5 + EE;

  float* buf0 = (float*)d_ws;            // hs1 -> hs2 -> pooled partials
  float* buf1 = buf0 + (size_t)NN*FDIM;  // hd1 -> h1
  float* buf2 = buf1 + (size_t)NN*FDIM;  // hd2 -> h2
  float* elog = buf2 + (size_t)NN*FDIM;
  float* sass = elog + (size_t)EE*4;
  float* xpool= sass + (size_t)NN*KC;
  float* aggE = xpool + KC*FDIM;
  int* deg    = (int*)(aggE + 64);
  int* rp     = deg + NN;
  int* cursor = rp + NN + 1;
  int* eids   = cursor + NN;

  dim3 ggrid((NN + 63)/64, 4);

  // CSR over dst (shared by both GAT layers)
  zero_i32<<<(NN+255)/256, 256, 0, stream>>>(deg, NN);
  count_deg<<<(EE+255)/256, 256, 0, stream>>>(dst5, deg);
  excl_scan<<<1, 1024, 0, stream>>>(deg, rp, NN);
  copy_i32<<<(NN+255)/256, 256, 0, stream>>>(rp, cursor, NN);
  scatter_edges<<<(EE+255)/256, 256, 0, stream>>>(dst5, cursor, eids);

  // edge_attr mean (independent path)
  zero_i32<<<1, 64, 0, stream>>>((int*)aggE, 64);
  edge_attr_mean<<<TT*BPT, 256, 0, stream>>>(edge_attr, aggE);

  // layer 1
  gemm_f32<<<ggrid, 256, 0, stream>>>(x_pkg, W1s5, node_mask, buf0, NN, DIN);   // hs1
  gemm_f32<<<ggrid, 256, 0, stream>>>(xd5,   W1d5, node_mask, buf1, NN, DIN);   // hd1
  edge_logits<<<EE/4, 256, 0, stream>>>(src5, dst5, buf0, buf1, a1_5, elog);
  aggregate<<<NN, 256, 0, stream>>>(rp, eids, src5, elog, buf0, b1_5, buf1, 1); // h1 (relu)

  // layer 2
  gemm_f32<<<ggrid, 256, 0, stream>>>(x_pkg, W2s5, node_mask, buf0, NN, DIN);   // hs2
  gemm_f32<<<ggrid, 256, 0, stream>>>(buf1,  W2d5, nullptr,  buf2, NN, FDIM);   // hd2
  edge_logits<<<EE/4, 256, 0, stream>>>(src5, dst5, buf0, buf2, a2_5, elog);
  aggregate<<<NN, 256, 0, stream>>>(rp, eids, src5, elog, buf0, b2_5, buf2, 0); // h2

  // pooling + classifier (buf0 free after layer-2 aggregate -> reuse for partials)
  pool_logits_sm<<<NPART, 256, 0, stream>>>(buf2, W_pool, b_pool, sass);
  zero_i32<<<(KC*FDIM+255)/256, 256, 0, stream>>>((int*)xpool, KC*FDIM);
  pooled_partial<<<NPART, 256, 0, stream>>>(sass, buf2, buf0);
  pooled_reduce<<<dim3(KC, PSPL), 256, 0, stream>>>(buf0, xpool);
  final_cls<<<1, 64, 0, stream>>>(xpool, aggE, W_cls, b_cls, out);
}

// Round 5
// 765.378 us; speedup vs baseline: 1.7753x; 1.1971x over previous
//
#include <hip/hip_runtime.h>
#include <math.h>

#define NN 50000      // nodes (both src and dst)
#define DIN 128
#define FDIM 256      // H*C
#define EE 200000
#define TT 6
#define DE 8
#define KC 48         // clusters

// order-preserving float<->uint encoding for atomicMax-based segment max
__device__ inline unsigned enc_f(float f){ unsigned u = __float_as_uint(f); return (u & 0x80000000u) ? ~u : (u | 0x80000000u); }
__device__ inline float dec_f(unsigned e){ unsigned u = (e & 0x80000000u) ? (e & 0x7FFFFFFFu) : ~e; return __uint_as_float(u); }

// ---------------- utility kernels ----------------
__global__ void zero_i32(int* __restrict__ p, int n){
  int i = blockIdx.x*256 + threadIdx.x;
  if (i < n) p[i] = 0;
}

__global__ void count_deg(const int* __restrict__ dst, int* __restrict__ deg){
  int i = blockIdx.x*256 + threadIdx.x;
  if (i < EE) atomicAdd(&deg[dst[i]], 1);
}

__global__ __launch_bounds__(1024) void excl_scan(const int* __restrict__ deg, int* __restrict__ rp, int n){
  __shared__ int sm[1024];
  int carry = 0;
  for (int base = 0; base < n; base += 1024){
    int i = base + (int)threadIdx.x;
    int v = (i < n) ? deg[i] : 0;
    __syncthreads();
    sm[threadIdx.x] = v;
    __syncthreads();
    for (int off = 1; off < 1024; off <<= 1){
      int t = (threadIdx.x >= (unsigned)off) ? sm[threadIdx.x - off] : 0;
      __syncthreads();
      sm[threadIdx.x] += t;
      __syncthreads();
    }
    if (i < n) rp[i] = carry + sm[threadIdx.x] - v;
    carry += sm[1023];
  }
  if (threadIdx.x == 0) rp[n] = carry;
}

__global__ void copy_i32(const int* __restrict__ a, int* __restrict__ b, int n){
  int i = blockIdx.x*256 + threadIdx.x;
  if (i < n) b[i] = a[i];
}

__global__ void scatter_edges(const int* __restrict__ dst, int* __restrict__ cursor, int* __restrict__ eids){
  int i = blockIdx.x*256 + threadIdx.x;
  if (i < EE){ int pos = atomicAdd(&cursor[dst[i]], 1); eids[pos] = i; }
}

// ---------------- GEMM: C[nrows,256] = (A * rowmask) @ W[K,256] ----------------
__global__ __launch_bounds__(256) void gemm_f32(const float* __restrict__ A, const float* __restrict__ W,
                                                const float* __restrict__ mask, float* __restrict__ Cm,
                                                int nrows, int K){
  __shared__ float As[16][68];
  __shared__ float Ws[16][64];
  int tid = threadIdx.x;
  int row0 = blockIdx.x * 64;
  int col0 = blockIdx.y * 64;
  int tx = tid & 15;
  int ty = tid >> 4;
  float acc[4][4] = {};
  for (int k0 = 0; k0 < K; k0 += 16){
    #pragma unroll
    for (int p = 0; p < 4; p++){
      int idx = tid + p*256;
      int r  = idx >> 4;
      int kk = idx & 15;
      int gr = row0 + r;
      float v = 0.f;
      if (gr < nrows){
        v = A[(size_t)gr*K + k0 + kk];
        if (mask) v *= mask[gr];
      }
      As[kk][r] = v;
    }
    #pragma unroll
    for (int p = 0; p < 4; p++){
      int idx = tid + p*256;
      int kk = idx >> 6;
      int c  = idx & 63;
      Ws[kk][c] = W[(size_t)(k0 + kk)*256 + col0 + c];
    }
    __syncthreads();
    #pragma unroll
    for (int kk = 0; kk < 16; kk++){
      float a[4], b[4];
      #pragma unroll
      for (int i = 0; i < 4; i++) a[i] = As[kk][ty*4 + i];
      #pragma unroll
      for (int j = 0; j < 4; j++) b[j] = Ws[kk][tx*4 + j];
      #pragma unroll
      for (int i = 0; i < 4; i++)
        #pragma unroll
        for (int j = 0; j < 4; j++)
          acc[i][j] = fmaf(a[i], b[j], acc[i][j]);
    }
    __syncthreads();
  }
  #pragma unroll
  for (int i = 0; i < 4; i++){
    int gr = row0 + ty*4 + i;
    if (gr < nrows){
      #pragma unroll
      for (int j = 0; j < 4; j++)
        Cm[(size_t)gr*256 + col0 + tx*4 + j] = acc[i][j];
    }
  }
}

// ---------------- edge logits (wave per edge, float4) + fused segment max ----------------
__global__ __launch_bounds__(256) void edge_logits2(const int* __restrict__ src, const int* __restrict__ dst,
                                                    const float* __restrict__ hs, const float* __restrict__ hd,
                                                    const float* __restrict__ att, float* __restrict__ eo,
                                                    unsigned* __restrict__ mxu){
  int e = blockIdx.x*4 + (threadIdx.x >> 6);
  int lane = threadIdx.x & 63;
  int h = lane >> 4;
  if (e >= EE) return;
  int s = src[e], d = dst[e];
  const float4 a = *(const float4*)(hs + (size_t)s*256 + lane*4);
  const float4 b = *(const float4*)(hd + (size_t)d*256 + lane*4);
  const float4 av = *(const float4*)(att + lane*4);
  float4 m;
  m.x = a.x + b.x; m.y = a.y + b.y; m.z = a.z + b.z; m.w = a.w + b.w;
  m.x = (m.x > 0.f) ? m.x : 0.2f*m.x;
  m.y = (m.y > 0.f) ? m.y : 0.2f*m.y;
  m.z = (m.z > 0.f) ? m.z : 0.2f*m.z;
  m.w = (m.w > 0.f) ? m.w : 0.2f*m.w;
  float p = m.x*av.x + m.y*av.y + m.z*av.z + m.w*av.w;
  #pragma unroll
  for (int msk = 8; msk > 0; msk >>= 1) p += __shfl_xor(p, msk);
  if ((lane & 15) == 0){
    eo[e*4 + h] = p;
    atomicMax(&mxu[d*4 + h], enc_f(p));
  }
}

// ---------------- per-(edge,head) softmax numerator ----------------
__global__ __launch_bounds__(256) void edge_w(const int* __restrict__ dst, const float* __restrict__ elog,
                                              const unsigned* __restrict__ mxu, float* __restrict__ wbuf){
  int idx = blockIdx.x*256 + threadIdx.x;
  if (idx >= EE*4) return;
  int e = idx >> 2, h = idx & 3;
  float mx = dec_f(mxu[dst[e]*4 + h]);
  wbuf[idx] = expf(elog[idx] - mx);
}

// ---------------- weighted aggregation (wave per node, float4, single pass) ----------------
__global__ __launch_bounds__(256) void aggregate_w(const int* __restrict__ rp, const int* __restrict__ eids,
                                                   const int* __restrict__ src, const float* __restrict__ wbuf,
                                                   const float* __restrict__ hs, const float* __restrict__ bias,
                                                   float* __restrict__ outp, int do_relu){
  int n = blockIdx.x*4 + (threadIdx.x >> 6);
  int lane = threadIdx.x & 63;
  int h = lane >> 4;
  if (n >= NN) return;
  int beg = rp[n], end = rp[n+1];
  float4 acc = {0.f,0.f,0.f,0.f};
  float sw = 0.f;
  for (int i = beg; i < end; i++){
    int eid = eids[i];
    float w = wbuf[eid*4 + h];
    int s = src[eid];
    const float4 hv = *(const float4*)(hs + (size_t)s*256 + lane*4);
    acc.x = fmaf(w, hv.x, acc.x);
    acc.y = fmaf(w, hv.y, acc.y);
    acc.z = fmaf(w, hv.z, acc.z);
    acc.w = fmaf(w, hv.w, acc.w);
    sw += w;
  }
  float inv = 1.f / (sw + 1e-16f);
  const float4 b4 = *(const float4*)(bias + lane*4);
  float4 r;
  r.x = acc.x*inv + b4.x;
  r.y = acc.y*inv + b4.y;
  r.z = acc.z*inv + b4.z;
  r.w = acc.w*inv + b4.w;
  if (do_relu){
    r.x = fmaxf(r.x, 0.f); r.y = fmaxf(r.y, 0.f);
    r.z = fmaxf(r.z, 0.f); r.w = fmaxf(r.w, 0.f);
  }
  *(float4*)(outp + (size_t)n*256 + lane*4) = r;
}

// ---------------- pool logits GEMM + fused row softmax -> s_assign[N][48] ----------------
__global__ __launch_bounds__(256) void pool_logits_sm(const float* __restrict__ h2, const float* __restrict__ Wp,
                                                      const float* __restrict__ bp, float* __restrict__ s_out){
  __shared__ float As[16][68];   // [kk][row]
  __shared__ float Ws[16][KC];   // [kk][col]
  int tid = threadIdx.x;
  int row0 = blockIdx.x * 64;
  int tx = tid & 15;
  int ty = tid >> 4;
  float acc[4][3] = {};
  for (int k0 = 0; k0 < 256; k0 += 16){
    #pragma unroll
    for (int p = 0; p < 4; p++){
      int idx = tid + p*256;
      int r  = idx >> 4;
      int kk = idx & 15;
      int gr = row0 + r;
      As[kk][r] = (gr < NN) ? h2[(size_t)gr*256 + k0 + kk] : 0.f;
    }
    {
      int idx = tid;
      if (idx < 768) Ws[idx/KC][idx%KC] = Wp[(size_t)(k0 + idx/KC)*KC + idx%KC];
      idx = tid + 256;
      Ws[idx/KC][idx%KC] = Wp[(size_t)(k0 + idx/KC)*KC + idx%KC];
      idx = tid + 512;
      Ws[idx/KC][idx%KC] = Wp[(size_t)(k0 + idx/KC)*KC + idx%KC];
    }
    __syncthreads();
    #pragma unroll
    for (int kk = 0; kk < 16; kk++){
      float a[4], b[3];
      #pragma unroll
      for (int i = 0; i < 4; i++) a[i] = As[kk][ty*4 + i];
      #pragma unroll
      for (int j = 0; j < 3; j++) b[j] = Ws[kk][tx*3 + j];
      #pragma unroll
      for (int i = 0; i < 4; i++)
        #pragma unroll
        for (int j = 0; j < 3; j++)
          acc[i][j] = fmaf(a[i], b[j], acc[i][j]);
    }
    __syncthreads();
  }
  float bb[3];
  #pragma unroll
  for (int j = 0; j < 3; j++) bb[j] = bp[tx*3 + j];
  #pragma unroll
  for (int i = 0; i < 4; i++){
    int gr = row0 + ty*4 + i;
    float m = -INFINITY;
    #pragma unroll
    for (int j = 0; j < 3; j++){ acc[i][j] += bb[j]; m = fmaxf(m, acc[i][j]); }
    #pragma unroll
    for (int mask = 8; mask > 0; mask >>= 1) m = fmaxf(m, __shfl_xor(m, mask));
    float e[3], s = 0.f;
    #pragma unroll
    for (int j = 0; j < 3; j++){ e[j] = expf(acc[i][j] - m); s += e[j]; }
    #pragma unroll
    for (int mask = 8; mask > 0; mask >>= 1) s += __shfl_xor(s, mask);
    float inv = 1.f / s;
    if (gr < NN){
      #pragma unroll
      for (int j = 0; j < 3; j++) s_out[(size_t)gr*KC + tx*3 + j] = e[j] * inv;
    }
  }
}

// ---------------- x_pooled = s.T @ h2, split-K two-stage ----------------
#define PCH 64
#define NPART ((NN + PCH - 1)/PCH)   // 782
__global__ __launch_bounds__(256) void pooled_partial(const float* __restrict__ s, const float* __restrict__ h2,
                                                      float* __restrict__ part){
  __shared__ float sld[PCH][KC];
  int t = threadIdx.x;
  int base = blockIdx.x * PCH;
  int cnt = min(PCH, NN - base);
  for (int idx = t; idx < cnt*KC; idx += 256)
    sld[idx/KC][idx%KC] = s[(size_t)(base + idx/KC)*KC + idx%KC];
  __syncthreads();
  float acc[KC];
  #pragma unroll
  for (int k = 0; k < KC; k++) acc[k] = 0.f;
  for (int n = 0; n < cnt; n++){
    float v = h2[(size_t)(base + n)*256 + t];
    #pragma unroll
    for (int k = 0; k < KC; k++) acc[k] = fmaf(sld[n][k], v, acc[k]);
  }
  float* po = part + (size_t)blockIdx.x*KC*256;
  #pragma unroll
  for (int k = 0; k < KC; k++) po[k*256 + t] = acc[k];
}
#define PSPL 8
__global__ __launch_bounds__(256) void pooled_reduce(const float* __restrict__ part, float* __restrict__ xp){
  int idx = blockIdx.x*256 + threadIdx.x;     // 0..12287
  const int per = (NPART + PSPL - 1)/PSPL;    // 98
  int p0 = blockIdx.y * per;
  int p1 = min(p0 + per, NPART);
  float s0 = 0.f, s1 = 0.f;
  int p = p0;
  for (; p + 1 < p1; p += 2){
    s0 += part[(size_t)p*KC*256 + idx];
    s1 += part[(size_t)(p+1)*KC*256 + idx];
  }
  if (p < p1) s0 += part[(size_t)p*KC*256 + idx];
  atomicAdd(&xp[idx], s0 + s1);
}

// ---------------- edge_attr mean over E -> [48], parallel grid-stride ----------------
#define BPT 128
__global__ __launch_bounds__(256) void edge_attr_mean(const float* __restrict__ ea, float* __restrict__ out){
  int t   = blockIdx.x / BPT;
  int blk = blockIdx.x % BPT;
  const int NF4 = EE * 2;
  const int per_blk = (NF4 + BPT - 1) / BPT;
  int i0 = blk * per_blk;
  int i1 = min(i0 + per_blk, NF4);
  const float4* base = (const float4*)(ea + (size_t)t*EE*DE);
  float s[8] = {0,0,0,0,0,0,0,0};
  for (int i = i0 + (int)threadIdx.x; i < i1; i += 256){
    float4 v = base[i];
    int db = (i & 1) * 4;
    s[db+0] += v.x; s[db+1] += v.y; s[db+2] += v.z; s[db+3] += v.w;
  }
  __shared__ float red[256];
  for (int d = 0; d < 8; d++){
    red[threadIdx.x] = s[d];
    __syncthreads();
    for (int off = 128; off > 0; off >>= 1){
      if (threadIdx.x < (unsigned)off) red[threadIdx.x] += red[threadIdx.x + off];
      __syncthreads();
    }
    if (threadIdx.x == 0) atomicAdd(&out[t*DE + d], red[0] / (float)EE);
    __syncthreads();
  }
}

// ---------------- final classifier ----------------
__global__ void final_cls(const float* __restrict__ xp, const float* __restrict__ agg,
                          const float* __restrict__ Wc, const float* __restrict__ bc,
                          float* __restrict__ out){
  int k = threadIdx.x;
  if (k < KC){
    float s = bc[0];
    for (int f = 0; f < 256; f++) s = fmaf(xp[k*256 + f], Wc[f], s);
    s = fmaf(agg[k], Wc[256], s);
    out[k] = 1.f/(1.f + expf(-s));
  }
}

extern "C" void kernel_launch(void* const* d_in, const int* in_sizes, int n_in,
                              void* d_out, int out_size, void* d_ws, size_t ws_size,
                              hipStream_t stream) {
  const float* x_pkg     = (const float*)d_in[0];
  const float* x_dst     = (const float*)d_in[1];
  const float* edge_attr = (const float*)d_in[2];
  const float* node_mask = (const float*)d_in[3];
  const float* W1_src    = (const float*)d_in[4];
  const float* W1_dst    = (const float*)d_in[5];
  const float* att1      = (const float*)d_in[6];
  const float* b1        = (const float*)d_in[7];
  const float* W2_src    = (const float*)d_in[8];
  const float* W2_dst    = (const float*)d_in[9];
  const float* att2      = (const float*)d_in[10];
  const float* b2        = (const float*)d_in[11];
  const float* W_pool    = (const float*)d_in[12];
  const float* b_pool    = (const float*)d_in[13];
  const float* W_cls     = (const float*)d_in[14];
  const float* b_cls     = (const float*)d_in[15];
  const int*   edge_index= (const int*)d_in[16];
  float* out = (float*)d_out;

  const int T5 = TT - 1;
  const float* W1s5 = W1_src + (size_t)T5*DIN*FDIM;
  const float* W1d5 = W1_dst + (size_t)T5*DIN*FDIM;
  const float* a1_5 = att1   + (size_t)T5*FDIM;
  const float* b1_5 = b1     + (size_t)T5*FDIM;
  const float* W2s5 = W2_src + (size_t)T5*DIN*FDIM;
  const float* W2d5 = W2_dst + (size_t)T5*FDIM*FDIM;
  const float* a2_5 = att2   + (size_t)T5*FDIM;
  const float* b2_5 = b2     + (size_t)T5*FDIM;
  const float* xd5  = x_dst  + (size_t)T5*NN*DIN;
  const int* src5   = edge_index + (size_t)T5*2*EE;
  const int* dst5   = src5 + EE;

  float* buf0 = (float*)d_ws;            // hs1 -> hs2 -> pooled partials
  float* buf1 = buf0 + (size_t)NN*FDIM;  // hd1 -> h1
  float* buf2 = buf1 + (size_t)NN*FDIM;  // hd2 -> h2
  float* elog = buf2 + (size_t)NN*FDIM;  // [EE*4]
  float* sass = elog + (size_t)EE*4;     // [NN*KC]
  float* xpool= sass + (size_t)NN*KC;    // [KC*256]
  float* aggE = xpool + KC*FDIM;         // [64]
  float* wbuf = aggE + 64;               // [EE*4]
  unsigned* mxu = (unsigned*)(wbuf + (size_t)EE*4); // [NN*4]
  int* deg    = (int*)(mxu + (size_t)NN*4);
  int* rp     = deg + NN;
  int* cursor = rp + NN + 1;
  int* eids   = cursor + NN;

  dim3 ggrid((NN + 63)/64, 4);

  // CSR over dst (shared by both GAT layers)
  zero_i32<<<(NN+255)/256, 256, 0, stream>>>(deg, NN);
  count_deg<<<(EE+255)/256, 256, 0, stream>>>(dst5, deg);
  excl_scan<<<1, 1024, 0, stream>>>(deg, rp, NN);
  copy_i32<<<(NN+255)/256, 256, 0, stream>>>(rp, cursor, NN);
  scatter_edges<<<(EE+255)/256, 256, 0, stream>>>(dst5, cursor, eids);

  // edge_attr mean (independent path)
  zero_i32<<<1, 64, 0, stream>>>((int*)aggE, 64);
  edge_attr_mean<<<TT*BPT, 256, 0, stream>>>(edge_attr, aggE);

  // layer 1
  gemm_f32<<<ggrid, 256, 0, stream>>>(x_pkg, W1s5, node_mask, buf0, NN, DIN);   // hs1
  gemm_f32<<<ggrid, 256, 0, stream>>>(xd5,   W1d5, node_mask, buf1, NN, DIN);   // hd1
  zero_i32<<<(NN*4+255)/256, 256, 0, stream>>>((int*)mxu, NN*4);
  edge_logits2<<<EE/4, 256, 0, stream>>>(src5, dst5, buf0, buf1, a1_5, elog, mxu);
  edge_w<<<(EE*4+255)/256, 256, 0, stream>>>(dst5, elog, mxu, wbuf);
  aggregate_w<<<NN/4, 256, 0, stream>>>(rp, eids, src5, wbuf, buf0, b1_5, buf1, 1); // h1 (relu)

  // layer 2
  gemm_f32<<<ggrid, 256, 0, stream>>>(x_pkg, W2s5, node_mask, buf0, NN, DIN);   // hs2
  gemm_f32<<<ggrid, 256, 0, stream>>>(buf1,  W2d5, nullptr,  buf2, NN, FDIM);   // hd2
  zero_i32<<<(NN*4+255)/256, 256, 0, stream>>>((int*)mxu, NN*4);
  edge_logits2<<<EE/4, 256, 0, stream>>>(src5, dst5, buf0, buf2, a2_5, elog, mxu);
  edge_w<<<(EE*4+255)/256, 256, 0, stream>>>(dst5, elog, mxu, wbuf);
  aggregate_w<<<NN/4, 256, 0, stream>>>(rp, eids, src5, wbuf, buf0, b2_5, buf2, 0); // h2

  // pooling + classifier (buf0 free after layer-2 aggregate -> reuse for partials)
  pool_logits_sm<<<NPART, 256, 0, stream>>>(buf2, W_pool, b_pool, sass);
  zero_i32<<<(KC*FDIM+255)/256, 256, 0, stream>>>((int*)xpool, KC*FDIM);
  pooled_partial<<<NPART, 256, 0, stream>>>(sass, buf2, buf0);
  pooled_reduce<<<dim3(KC, PSPL), 256, 0, stream>>>(buf0, xpool);
  final_cls<<<1, 64, 0, stream>>>(xpool, aggE, W_cls, b_cls, out);
}

// Round 6
// 601.366 us; speedup vs baseline: 2.2594x; 1.2727x over previous
//
#include <hip/hip_runtime.h>
#include <math.h>

#define NN 50000      // nodes (both src and dst)
#define DIN 128
#define FDIM 256      // H*C
#define EE 200000
#define TT 6
#define DE 8
#define KC 48         // clusters

typedef __attribute__((ext_vector_type(8))) short bf16x8;
typedef __attribute__((ext_vector_type(8))) unsigned short u16x8;
typedef __attribute__((ext_vector_type(4))) float f32x4;

// order-preserving float<->uint encoding for atomicMax-based segment max
__device__ inline unsigned enc_f(float f){ unsigned u = __float_as_uint(f); return (u & 0x80000000u) ? ~u : (u | 0x80000000u); }
__device__ inline float dec_f(unsigned e){ unsigned u = (e & 0x80000000u) ? (e & 0x7FFFFFFFu) : ~e; return __uint_as_float(u); }
// f32 -> bf16 round-to-nearest-even
__device__ inline unsigned short f2b(float f){
  unsigned u = __float_as_uint(f);
  unsigned r = u + 0x7FFFu + ((u >> 16) & 1u);
  return (unsigned short)(r >> 16);
}

// ---------------- utility kernels ----------------
__global__ void zero_i32(int* __restrict__ p, int n){
  int i = blockIdx.x*256 + threadIdx.x;
  if (i < n) p[i] = 0;
}

__global__ void count_deg(const int* __restrict__ dst, int* __restrict__ deg){
  int i = blockIdx.x*256 + threadIdx.x;
  if (i < EE) atomicAdd(&deg[dst[i]], 1);
}

__global__ __launch_bounds__(1024) void excl_scan(const int* __restrict__ deg, int* __restrict__ rp, int n){
  __shared__ int sm[1024];
  int carry = 0;
  for (int base = 0; base < n; base += 1024){
    int i = base + (int)threadIdx.x;
    int v = (i < n) ? deg[i] : 0;
    __syncthreads();
    sm[threadIdx.x] = v;
    __syncthreads();
    for (int off = 1; off < 1024; off <<= 1){
      int t = (threadIdx.x >= (unsigned)off) ? sm[threadIdx.x - off] : 0;
      __syncthreads();
      sm[threadIdx.x] += t;
      __syncthreads();
    }
    if (i < n) rp[i] = carry + sm[threadIdx.x] - v;
    carry += sm[1023];
  }
  if (threadIdx.x == 0) rp[n] = carry;
}

__global__ void copy_i32(const int* __restrict__ a, int* __restrict__ b, int n){
  int i = blockIdx.x*256 + threadIdx.x;
  if (i < n) b[i] = a[i];
}

__global__ void scatter_edges(const int* __restrict__ dst, int* __restrict__ cursor, int* __restrict__ eids){
  int i = blockIdx.x*256 + threadIdx.x;
  if (i < EE){ int pos = atomicAdd(&cursor[dst[i]], 1); eids[pos] = i; }
}

// ---------------- conversions ----------------
// out_bf16[i] = in[i] * mask[i/K]  (8 elems/thread, K%8==0)
__global__ __launch_bounds__(256) void cvt_mask(const float* __restrict__ in, const float* __restrict__ mask,
                                                unsigned short* __restrict__ outb, int total, int K){
  int i = (blockIdx.x*256 + threadIdx.x)*8;
  if (i >= total) return;
  float m = mask[i / K];
  float4 a = *(const float4*)(in + i);
  float4 b = *(const float4*)(in + i + 4);
  u16x8 o;
  o[0]=f2b(a.x*m); o[1]=f2b(a.y*m); o[2]=f2b(a.z*m); o[3]=f2b(a.w*m);
  o[4]=f2b(b.x*m); o[5]=f2b(b.y*m); o[6]=f2b(b.z*m); o[7]=f2b(b.w*m);
  *(u16x8*)(outb + i) = o;
}

// Wt[n][k] = bf16(W[k][n]); W is [K][256]. tiny (<=64K elems)
__global__ void cvt_wt(const float* __restrict__ W, unsigned short* __restrict__ Wt, int K){
  int n = blockIdx.x;
  for (int k = threadIdx.x; k < K; k += 256)
    Wt[(size_t)n*K + k] = f2b(W[(size_t)k*256 + n]);
}

// ---------------- MFMA GEMM: C[M,256] = A[M,K](bf16) @ Wt[256,K](bf16)^T ----------------
// tile 128x128, BK=32, 4 waves (2x2 of 64x64). Fragment layouts per learn_hip m89/m91.
__global__ __launch_bounds__(256) void gemm_bf16(const short* __restrict__ A, const short* __restrict__ Wt,
                                                 float* __restrict__ C, int M, int K){
  __shared__ short Al[128][56];   // stride 112B: 16B-aligned, ~2-way banks
  __shared__ short Bl[128][56];
  int tid = threadIdx.x;
  int lane = tid & 63;
  int w = tid >> 6;
  int wm = w >> 1, wn = w & 1;
  int row0 = blockIdx.x * 128, col0 = blockIdx.y * 128;
  int fr = lane & 15;   // fragment row (A) / col (B)
  int kb = lane >> 4;   // k-block 0..3 (8 bf16 each)
  f32x4 acc[4][4];
  #pragma unroll
  for (int i = 0; i < 4; i++)
    #pragma unroll
    for (int j = 0; j < 4; j++)
      acc[i][j] = (f32x4){0.f, 0.f, 0.f, 0.f};

  for (int k0 = 0; k0 < K; k0 += 32){
    bf16x8 ra[2], rb[2];
    #pragma unroll
    for (int p = 0; p < 2; p++){
      int idx = tid + p*256;          // 0..511
      int r = idx >> 2, ch = idx & 3; // row/col in tile, 8-elem chunk
      int gr = row0 + r;
      if (gr < M) ra[p] = *(const bf16x8*)(A + (size_t)gr*K + k0 + ch*8);
      else        ra[p] = (bf16x8){0,0,0,0,0,0,0,0};
      rb[p] = *(const bf16x8*)(Wt + (size_t)(col0 + r)*K + k0 + ch*8);
    }
    __syncthreads();
    #pragma unroll
    for (int p = 0; p < 2; p++){
      int idx = tid + p*256;
      int r = idx >> 2, ch = idx & 3;
      *(bf16x8*)(&Al[r][ch*8]) = ra[p];
      *(bf16x8*)(&Bl[r][ch*8]) = rb[p];
    }
    __syncthreads();
    bf16x8 af[4], bfr[4];
    #pragma unroll
    for (int i = 0; i < 4; i++) af[i]  = *(const bf16x8*)(&Al[wm*64 + i*16 + fr][kb*8]);
    #pragma unroll
    for (int j = 0; j < 4; j++) bfr[j] = *(const bf16x8*)(&Bl[wn*64 + j*16 + fr][kb*8]);
    #pragma unroll
    for (int i = 0; i < 4; i++)
      #pragma unroll
      for (int j = 0; j < 4; j++)
        acc[i][j] = __builtin_amdgcn_mfma_f32_16x16x32_bf16(af[i], bfr[j], acc[i][j], 0, 0, 0);
  }
  // C/D layout: col = lane&15, row = (lane>>4)*4 + q  (m89-verified)
  #pragma unroll
  for (int i = 0; i < 4; i++){
    #pragma unroll
    for (int q = 0; q < 4; q++){
      int grow = row0 + wm*64 + i*16 + kb*4 + q;
      if (grow < M){
        #pragma unroll
        for (int j = 0; j < 4; j++)
          C[(size_t)grow*256 + col0 + wn*64 + j*16 + fr] = acc[i][j][q];
      }
    }
  }
}

// ---------------- edge logits (wave per edge, float4) + fused segment max ----------------
__global__ __launch_bounds__(256) void edge_logits2(const int* __restrict__ src, const int* __restrict__ dst,
                                                    const float* __restrict__ hs, const float* __restrict__ hd,
                                                    const float* __restrict__ att, float* __restrict__ eo,
                                                    unsigned* __restrict__ mxu){
  int e = blockIdx.x*4 + (threadIdx.x >> 6);
  int lane = threadIdx.x & 63;
  int h = lane >> 4;
  if (e >= EE) return;
  int s = src[e], d = dst[e];
  const float4 a = *(const float4*)(hs + (size_t)s*256 + lane*4);
  const float4 b = *(const float4*)(hd + (size_t)d*256 + lane*4);
  const float4 av = *(const float4*)(att + lane*4);
  float4 m;
  m.x = a.x + b.x; m.y = a.y + b.y; m.z = a.z + b.z; m.w = a.w + b.w;
  m.x = (m.x > 0.f) ? m.x : 0.2f*m.x;
  m.y = (m.y > 0.f) ? m.y : 0.2f*m.y;
  m.z = (m.z > 0.f) ? m.z : 0.2f*m.z;
  m.w = (m.w > 0.f) ? m.w : 0.2f*m.w;
  float p = m.x*av.x + m.y*av.y + m.z*av.z + m.w*av.w;
  #pragma unroll
  for (int msk = 8; msk > 0; msk >>= 1) p += __shfl_xor(p, msk);
  if ((lane & 15) == 0){
    eo[e*4 + h] = p;
    atomicMax(&mxu[d*4 + h], enc_f(p));
  }
}

// ---------------- per-(edge,head) softmax numerator ----------------
__global__ __launch_bounds__(256) void edge_w(const int* __restrict__ dst, const float* __restrict__ elog,
                                              const unsigned* __restrict__ mxu, float* __restrict__ wbuf){
  int idx = blockIdx.x*256 + threadIdx.x;
  if (idx >= EE*4) return;
  int e = idx >> 2, h = idx & 3;
  float mx = dec_f(mxu[dst[e]*4 + h]);
  wbuf[idx] = expf(elog[idx] - mx);
}

// ---------------- weighted aggregation (wave per node, float4, single pass) ----------------
// outb != null -> write bf16 (h1 path, feeds next GEMM); else f32 to outp.
__global__ __launch_bounds__(256) void aggregate_w(const int* __restrict__ rp, const int* __restrict__ eids,
                                                   const int* __restrict__ src, const float* __restrict__ wbuf,
                                                   const float* __restrict__ hs, const float* __restrict__ bias,
                                                   float* __restrict__ outp, unsigned short* __restrict__ outb,
                                                   int do_relu){
  int n = blockIdx.x*4 + (threadIdx.x >> 6);
  int lane = threadIdx.x & 63;
  int h = lane >> 4;
  if (n >= NN) return;
  int beg = rp[n], end = rp[n+1];
  float4 acc = {0.f,0.f,0.f,0.f};
  float sw = 0.f;
  for (int i = beg; i < end; i++){
    int eid = eids[i];
    float w = wbuf[eid*4 + h];
    int s = src[eid];
    const float4 hv = *(const float4*)(hs + (size_t)s*256 + lane*4);
    acc.x = fmaf(w, hv.x, acc.x);
    acc.y = fmaf(w, hv.y, acc.y);
    acc.z = fmaf(w, hv.z, acc.z);
    acc.w = fmaf(w, hv.w, acc.w);
    sw += w;
  }
  float inv = 1.f / (sw + 1e-16f);
  const float4 b4 = *(const float4*)(bias + lane*4);
  float4 r;
  r.x = acc.x*inv + b4.x;
  r.y = acc.y*inv + b4.y;
  r.z = acc.z*inv + b4.z;
  r.w = acc.w*inv + b4.w;
  if (do_relu){
    r.x = fmaxf(r.x, 0.f); r.y = fmaxf(r.y, 0.f);
    r.z = fmaxf(r.z, 0.f); r.w = fmaxf(r.w, 0.f);
  }
  if (outb){
    ushort4 o;
    o.x = f2b(r.x); o.y = f2b(r.y); o.z = f2b(r.z); o.w = f2b(r.w);
    *(ushort4*)(outb + (size_t)n*256 + lane*4) = o;
  } else {
    *(float4*)(outp + (size_t)n*256 + lane*4) = r;
  }
}

// ---------------- pool logits GEMM + fused row softmax -> s_assign[N][48] ----------------
__global__ __launch_bounds__(256) void pool_logits_sm(const float* __restrict__ h2, const float* __restrict__ Wp,
                                                      const float* __restrict__ bp, float* __restrict__ s_out){
  __shared__ float As[16][68];   // [kk][row]
  __shared__ float Ws[16][KC];   // [kk][col]
  int tid = threadIdx.x;
  int row0 = blockIdx.x * 64;
  int tx = tid & 15;
  int ty = tid >> 4;
  float acc[4][3] = {};
  for (int k0 = 0; k0 < 256; k0 += 16){
    #pragma unroll
    for (int p = 0; p < 4; p++){
      int idx = tid + p*256;
      int r  = idx >> 4;
      int kk = idx & 15;
      int gr = row0 + r;
      As[kk][r] = (gr < NN) ? h2[(size_t)gr*256 + k0 + kk] : 0.f;
    }
    {
      int idx = tid;
      if (idx < 768) Ws[idx/KC][idx%KC] = Wp[(size_t)(k0 + idx/KC)*KC + idx%KC];
      idx = tid + 256;
      Ws[idx/KC][idx%KC] = Wp[(size_t)(k0 + idx/KC)*KC + idx%KC];
      idx = tid + 512;
      Ws[idx/KC][idx%KC] = Wp[(size_t)(k0 + idx/KC)*KC + idx%KC];
    }
    __syncthreads();
    #pragma unroll
    for (int kk = 0; kk < 16; kk++){
      float a[4], b[3];
      #pragma unroll
      for (int i = 0; i < 4; i++) a[i] = As[kk][ty*4 + i];
      #pragma unroll
      for (int j = 0; j < 3; j++) b[j] = Ws[kk][tx*3 + j];
      #pragma unroll
      for (int i = 0; i < 4; i++)
        #pragma unroll
        for (int j = 0; j < 3; j++)
          acc[i][j] = fmaf(a[i], b[j], acc[i][j]);
    }
    __syncthreads();
  }
  float bb[3];
  #pragma unroll
  for (int j = 0; j < 3; j++) bb[j] = bp[tx*3 + j];
  #pragma unroll
  for (int i = 0; i < 4; i++){
    int gr = row0 + ty*4 + i;
    float m = -INFINITY;
    #pragma unroll
    for (int j = 0; j < 3; j++){ acc[i][j] += bb[j]; m = fmaxf(m, acc[i][j]); }
    #pragma unroll
    for (int mask = 8; mask > 0; mask >>= 1) m = fmaxf(m, __shfl_xor(m, mask));
    float e[3], s = 0.f;
    #pragma unroll
    for (int j = 0; j < 3; j++){ e[j] = expf(acc[i][j] - m); s += e[j]; }
    #pragma unroll
    for (int mask = 8; mask > 0; mask >>= 1) s += __shfl_xor(s, mask);
    float inv = 1.f / s;
    if (gr < NN){
      #pragma unroll
      for (int j = 0; j < 3; j++) s_out[(size_t)gr*KC + tx*3 + j] = e[j] * inv;
    }
  }
}

// ---------------- x_pooled = s.T @ h2, split-K two-stage ----------------
#define PCH 64
#define NPART ((NN + PCH - 1)/PCH)   // 782
__global__ __launch_bounds__(256) void pooled_partial(const float* __restrict__ s, const float* __restrict__ h2,
                                                      float* __restrict__ part){
  __shared__ float sld[PCH][KC];
  int t = threadIdx.x;
  int base = blockIdx.x * PCH;
  int cnt = min(PCH, NN - base);
  for (int idx = t; idx < cnt*KC; idx += 256)
    sld[idx/KC][idx%KC] = s[(size_t)(base + idx/KC)*KC + idx%KC];
  __syncthreads();
  float acc[KC];
  #pragma unroll
  for (int k = 0; k < KC; k++) acc[k] = 0.f;
  for (int n = 0; n < cnt; n++){
    float v = h2[(size_t)(base + n)*256 + t];
    #pragma unroll
    for (int k = 0; k < KC; k++) acc[k] = fmaf(sld[n][k], v, acc[k]);
  }
  float* po = part + (size_t)blockIdx.x*KC*256;
  #pragma unroll
  for (int k = 0; k < KC; k++) po[k*256 + t] = acc[k];
}
#define PSPL 8
__global__ __launch_bounds__(256) void pooled_reduce(const float* __restrict__ part, float* __restrict__ xp){
  int idx = blockIdx.x*256 + threadIdx.x;     // 0..12287
  const int per = (NPART + PSPL - 1)/PSPL;    // 98
  int p0 = blockIdx.y * per;
  int p1 = min(p0 + per, NPART);
  float s0 = 0.f, s1 = 0.f;
  int p = p0;
  for (; p + 1 < p1; p += 2){
    s0 += part[(size_t)p*KC*256 + idx];
    s1 += part[(size_t)(p+1)*KC*256 + idx];
  }
  if (p < p1) s0 += part[(size_t)p*KC*256 + idx];
  atomicAdd(&xp[idx], s0 + s1);
}

// ---------------- edge_attr mean over E -> [48], parallel grid-stride ----------------
#define BPT 128
__global__ __launch_bounds__(256) void edge_attr_mean(const float* __restrict__ ea, float* __restrict__ out){
  int t   = blockIdx.x / BPT;
  int blk = blockIdx.x % BPT;
  const int NF4 = EE * 2;
  const int per_blk = (NF4 + BPT - 1) / BPT;
  int i0 = blk * per_blk;
  int i1 = min(i0 + per_blk, NF4);
  const float4* base = (const float4*)(ea + (size_t)t*EE*DE);
  float s[8] = {0,0,0,0,0,0,0,0};
  for (int i = i0 + (int)threadIdx.x; i < i1; i += 256){
    float4 v = base[i];
    int db = (i & 1) * 4;
    s[db+0] += v.x; s[db+1] += v.y; s[db+2] += v.z; s[db+3] += v.w;
  }
  __shared__ float red[256];
  for (int d = 0; d < 8; d++){
    red[threadIdx.x] = s[d];
    __syncthreads();
    for (int off = 128; off > 0; off >>= 1){
      if (threadIdx.x < (unsigned)off) red[threadIdx.x] += red[threadIdx.x + off];
      __syncthreads();
    }
    if (threadIdx.x == 0) atomicAdd(&out[t*DE + d], red[0] / (float)EE);
    __syncthreads();
  }
}

// ---------------- final classifier ----------------
__global__ void final_cls(const float* __restrict__ xp, const float* __restrict__ agg,
                          const float* __restrict__ Wc, const float* __restrict__ bc,
                          float* __restrict__ out){
  int k = threadIdx.x;
  if (k < KC){
    float s = bc[0];
    for (int f = 0; f < 256; f++) s = fmaf(xp[k*256 + f], Wc[f], s);
    s = fmaf(agg[k], Wc[256], s);
    out[k] = 1.f/(1.f + expf(-s));
  }
}

extern "C" void kernel_launch(void* const* d_in, const int* in_sizes, int n_in,
                              void* d_out, int out_size, void* d_ws, size_t ws_size,
                              hipStream_t stream) {
  const float* x_pkg     = (const float*)d_in[0];
  const float* x_dst     = (const float*)d_in[1];
  const float* edge_attr = (const float*)d_in[2];
  const float* node_mask = (const float*)d_in[3];
  const float* W1_src    = (const float*)d_in[4];
  const float* W1_dst    = (const float*)d_in[5];
  const float* att1      = (const float*)d_in[6];
  const float* b1        = (const float*)d_in[7];
  const float* W2_src    = (const float*)d_in[8];
  const float* W2_dst    = (const float*)d_in[9];
  const float* att2      = (const float*)d_in[10];
  const float* b2        = (const float*)d_in[11];
  const float* W_pool    = (const float*)d_in[12];
  const float* b_pool    = (const float*)d_in[13];
  const float* W_cls     = (const float*)d_in[14];
  const float* b_cls     = (const float*)d_in[15];
  const int*   edge_index= (const int*)d_in[16];
  float* out = (float*)d_out;

  const int T5 = TT - 1;
  const float* W1s5 = W1_src + (size_t)T5*DIN*FDIM;
  const float* W1d5 = W1_dst + (size_t)T5*DIN*FDIM;
  const float* a1_5 = att1   + (size_t)T5*FDIM;
  const float* b1_5 = b1     + (size_t)T5*FDIM;
  const float* W2s5 = W2_src + (size_t)T5*DIN*FDIM;
  const float* W2d5 = W2_dst + (size_t)T5*FDIM*FDIM;
  const float* a2_5 = att2   + (size_t)T5*FDIM;
  const float* b2_5 = b2     + (size_t)T5*FDIM;
  const float* xd5  = x_dst  + (size_t)T5*NN*DIN;
  const int* src5   = edge_index + (size_t)T5*2*EE;
  const int* dst5   = src5 + EE;

  // ---- workspace layout (with bf16 overlays into dead f32 regions) ----
  float* buf0 = (float*)d_ws;            // hs1 -> hs2 -> pooled partials
  float* buf1 = buf0 + (size_t)NN*FDIM;  // hd1 -> h1b(bf16) -> h2(f32)
  float* buf2 = buf1 + (size_t)NN*FDIM;  // Xd_b/Xp_b(bf16) -> hd2(f32)
  float* elog = buf2 + (size_t)NN*FDIM;  // [EE*4]
  float* sass = elog + (size_t)EE*4;     // [NN*KC]
  float* xpool= sass + (size_t)NN*KC;    // [KC*256]
  float* aggE = xpool + KC*FDIM;         // [64]
  float* wbuf = aggE + 64;               // [EE*4]
  unsigned* mxu = (unsigned*)(wbuf + (size_t)EE*4); // [NN*4]
  int* deg    = (int*)(mxu + (size_t)NN*4);
  int* rp     = deg + NN;
  int* cursor = rp + NN + 1;
  int* eids   = cursor + NN;
  unsigned short* Wt1s = (unsigned short*)(eids + EE);   // [256*128]
  unsigned short* Wt1d = Wt1s + 256*DIN;
  unsigned short* Wt2s = Wt1d + 256*DIN;
  unsigned short* Wt2d = Wt2s + 256*DIN;                 // [256*256]
  // bf16 overlays (dead-region reuse):
  unsigned short* Xd_b = (unsigned short*)buf2;                    // 12.8 MB, dead after hd1 gemm
  unsigned short* Xp_b = (unsigned short*)buf2 + 8u*1024u*1024u;   // @16 MB, dead after hs2 gemm
  unsigned short* h1b  = (unsigned short*)buf1;                    // 25.6 MB, dead after hd2 gemm

  dim3 ggrid((NN + 127)/128, 2);

  // CSR over dst (shared by both GAT layers)
  zero_i32<<<(NN+255)/256, 256, 0, stream>>>(deg, NN);
  count_deg<<<(EE+255)/256, 256, 0, stream>>>(dst5, deg);
  excl_scan<<<1, 1024, 0, stream>>>(deg, rp, NN);
  copy_i32<<<(NN+255)/256, 256, 0, stream>>>(rp, cursor, NN);
  scatter_edges<<<(EE+255)/256, 256, 0, stream>>>(dst5, cursor, eids);

  // edge_attr mean (independent path)
  zero_i32<<<1, 64, 0, stream>>>((int*)aggE, 64);
  edge_attr_mean<<<TT*BPT, 256, 0, stream>>>(edge_attr, aggE);

  // conversions: masked inputs + transposed weights -> bf16
  cvt_mask<<<(NN*DIN/8 + 255)/256, 256, 0, stream>>>(x_pkg, node_mask, Xp_b, NN*DIN, DIN);
  cvt_mask<<<(NN*DIN/8 + 255)/256, 256, 0, stream>>>(xd5,   node_mask, Xd_b, NN*DIN, DIN);
  cvt_wt<<<256, 256, 0, stream>>>(W1s5, Wt1s, DIN);
  cvt_wt<<<256, 256, 0, stream>>>(W1d5, Wt1d, DIN);
  cvt_wt<<<256, 256, 0, stream>>>(W2s5, Wt2s, DIN);
  cvt_wt<<<256, 256, 0, stream>>>(W2d5, Wt2d, FDIM);

  // layer 1
  gemm_bf16<<<ggrid, 256, 0, stream>>>((const short*)Xp_b, (const short*)Wt1s, buf0, NN, DIN); // hs1
  gemm_bf16<<<ggrid, 256, 0, stream>>>((const short*)Xd_b, (const short*)Wt1d, buf1, NN, DIN); // hd1
  zero_i32<<<(NN*4+255)/256, 256, 0, stream>>>((int*)mxu, NN*4);
  edge_logits2<<<EE/4, 256, 0, stream>>>(src5, dst5, buf0, buf1, a1_5, elog, mxu);
  edge_w<<<(EE*4+255)/256, 256, 0, stream>>>(dst5, elog, mxu, wbuf);
  aggregate_w<<<NN/4, 256, 0, stream>>>(rp, eids, src5, wbuf, buf0, b1_5, nullptr, h1b, 1); // h1 -> bf16

  // layer 2
  gemm_bf16<<<ggrid, 256, 0, stream>>>((const short*)Xp_b, (const short*)Wt2s, buf0, NN, DIN);  // hs2
  gemm_bf16<<<ggrid, 256, 0, stream>>>((const short*)h1b,  (const short*)Wt2d, buf2, NN, FDIM); // hd2
  zero_i32<<<(NN*4+255)/256, 256, 0, stream>>>((int*)mxu, NN*4);
  edge_logits2<<<EE/4, 256, 0, stream>>>(src5, dst5, buf0, buf2, a2_5, elog, mxu);
  edge_w<<<(EE*4+255)/256, 256, 0, stream>>>(dst5, elog, mxu, wbuf);
  aggregate_w<<<NN/4, 256, 0, stream>>>(rp, eids, src5, wbuf, buf0, b2_5, buf1, nullptr, 0); // h2 -> buf1 (f32)

  // pooling + classifier (h2 = buf1; buf0 free -> partials)
  pool_logits_sm<<<NPART, 256, 0, stream>>>(buf1, W_pool, b_pool, sass);
  zero_i32<<<(KC*FDIM+255)/256, 256, 0, stream>>>((int*)xpool, KC*FDIM);
  pooled_partial<<<NPART, 256, 0, stream>>>(sass, buf1, buf0);
  pooled_reduce<<<dim3(KC, PSPL), 256, 0, stream>>>(buf0, xpool);
  final_cls<<<1, 64, 0, stream>>>(xpool, aggE, W_cls, b_cls, out);
}

// Round 7
// 519.372 us; speedup vs baseline: 2.6161x; 1.1579x over previous
//
#include <hip/hip_runtime.h>
#include <math.h>

#define NN 50000      // nodes (both src and dst)
#define DIN 128
#define FDIM 256      // H*C
#define EE 200000
#define TT 6
#define DE 8
#define KC 48         // clusters
#define NB ((NN + 255)/256)   // 196 scan blocks

typedef __attribute__((ext_vector_type(8))) short bf16x8;
typedef __attribute__((ext_vector_type(8))) unsigned short u16x8;
typedef __attribute__((ext_vector_type(4))) float f32x4;

// order-preserving float<->uint encoding for atomicMax-based segment max
__device__ inline unsigned enc_f(float f){ unsigned u = __float_as_uint(f); return (u & 0x80000000u) ? ~u : (u | 0x80000000u); }
__device__ inline float dec_f(unsigned e){ unsigned u = (e & 0x80000000u) ? (e & 0x7FFFFFFFu) : ~e; return __uint_as_float(u); }
// f32 -> bf16 round-to-nearest-even
__device__ inline unsigned short f2b(float f){
  unsigned u = __float_as_uint(f);
  unsigned r = u + 0x7FFFu + ((u >> 16) & 1u);
  return (unsigned short)(r >> 16);
}

// ---------------- utility kernels ----------------
__global__ void zero_i32(int* __restrict__ p, int n){
  int i = blockIdx.x*256 + threadIdx.x;
  if (i < n) p[i] = 0;
}

__global__ void count_deg(const int* __restrict__ dst, int* __restrict__ deg){
  int i = blockIdx.x*256 + threadIdx.x;
  if (i < EE) atomicAdd(&deg[dst[i]], 1);
}

// ---------------- hierarchical exclusive scan (3 kernels, 196-way parallel) ----------------
__global__ __launch_bounds__(256) void scan_blk(const int* __restrict__ deg, int* __restrict__ rp,
                                                int* __restrict__ bsum){
  __shared__ int sm[256];
  int i = blockIdx.x*256 + threadIdx.x;
  int v = (i < NN) ? deg[i] : 0;
  sm[threadIdx.x] = v;
  __syncthreads();
  #pragma unroll
  for (int off = 1; off < 256; off <<= 1){
    int t = (threadIdx.x >= (unsigned)off) ? sm[threadIdx.x - off] : 0;
    __syncthreads();
    sm[threadIdx.x] += t;
    __syncthreads();
  }
  if (i < NN) rp[i] = sm[threadIdx.x] - v;   // block-local exclusive
  if (threadIdx.x == 255) bsum[blockIdx.x] = sm[255];
}

__global__ __launch_bounds__(256) void scan_sums(const int* __restrict__ bsum, int* __restrict__ boff){
  __shared__ int sm[256];
  int v = (threadIdx.x < NB) ? bsum[threadIdx.x] : 0;
  sm[threadIdx.x] = v;
  __syncthreads();
  #pragma unroll
  for (int off = 1; off < 256; off <<= 1){
    int t = (threadIdx.x >= (unsigned)off) ? sm[threadIdx.x - off] : 0;
    __syncthreads();
    sm[threadIdx.x] += t;
    __syncthreads();
  }
  if (threadIdx.x < NB) boff[threadIdx.x] = sm[threadIdx.x] - v;
}

// add block offsets; fuse cursor copy; set rp[NN]=EE (sum of deg is EE by construction)
__global__ __launch_bounds__(256) void scan_add(int* __restrict__ rp, const int* __restrict__ boff,
                                                int* __restrict__ cursor){
  int i = blockIdx.x*256 + threadIdx.x;
  if (i < NN){
    int r = rp[i] + boff[blockIdx.x];
    rp[i] = r;
    cursor[i] = r;
  }
  if (i == 0) rp[NN] = EE;
}

__global__ void scatter_edges(const int* __restrict__ dst, int* __restrict__ cursor, int* __restrict__ eids){
  int i = blockIdx.x*256 + threadIdx.x;
  if (i < EE){ int pos = atomicAdd(&cursor[dst[i]], 1); eids[pos] = i; }
}

// ---------------- conversions ----------------
// out_bf16[i] = in[i] * mask[i/K]  (8 elems/thread, K%8==0)
__global__ __launch_bounds__(256) void cvt_mask(const float* __restrict__ in, const float* __restrict__ mask,
                                                unsigned short* __restrict__ outb, int total, int K){
  int i = (blockIdx.x*256 + threadIdx.x)*8;
  if (i >= total) return;
  float m = mask[i / K];
  float4 a = *(const float4*)(in + i);
  float4 b = *(const float4*)(in + i + 4);
  u16x8 o;
  o[0]=f2b(a.x*m); o[1]=f2b(a.y*m); o[2]=f2b(a.z*m); o[3]=f2b(a.w*m);
  o[4]=f2b(b.x*m); o[5]=f2b(b.y*m); o[6]=f2b(b.z*m); o[7]=f2b(b.w*m);
  *(u16x8*)(outb + i) = o;
}

// Wt[n][k] = bf16(W[k][n]); W is [K][256]. tiny (<=64K elems)
__global__ void cvt_wt(const float* __restrict__ W, unsigned short* __restrict__ Wt, int K){
  int n = blockIdx.x;
  for (int k = threadIdx.x; k < K; k += 256)
    Wt[(size_t)n*K + k] = f2b(W[(size_t)k*256 + n]);
}

// ---------------- MFMA GEMM: C[M,256] = A[M,K](bf16) @ Wt[256,K](bf16)^T ----------------
// tile 128x128, BK=32, 4 waves (2x2 of 64x64). Fragment layouts per learn_hip m89/m91.
__global__ __launch_bounds__(256) void gemm_bf16(const short* __restrict__ A, const short* __restrict__ Wt,
                                                 float* __restrict__ C, int M, int K){
  __shared__ short Al[128][56];   // stride 112B: 16B-aligned, ~2-way banks
  __shared__ short Bl[128][56];
  int tid = threadIdx.x;
  int lane = tid & 63;
  int w = tid >> 6;
  int wm = w >> 1, wn = w & 1;
  int row0 = blockIdx.x * 128, col0 = blockIdx.y * 128;
  int fr = lane & 15;   // fragment row (A) / col (B)
  int kb = lane >> 4;   // k-block 0..3 (8 bf16 each)
  f32x4 acc[4][4];
  #pragma unroll
  for (int i = 0; i < 4; i++)
    #pragma unroll
    for (int j = 0; j < 4; j++)
      acc[i][j] = (f32x4){0.f, 0.f, 0.f, 0.f};

  for (int k0 = 0; k0 < K; k0 += 32){
    bf16x8 ra[2], rb[2];
    #pragma unroll
    for (int p = 0; p < 2; p++){
      int idx = tid + p*256;          // 0..511
      int r = idx >> 2, ch = idx & 3; // row/col in tile, 8-elem chunk
      int gr = row0 + r;
      if (gr < M) ra[p] = *(const bf16x8*)(A + (size_t)gr*K + k0 + ch*8);
      else        ra[p] = (bf16x8){0,0,0,0,0,0,0,0};
      rb[p] = *(const bf16x8*)(Wt + (size_t)(col0 + r)*K + k0 + ch*8);
    }
    __syncthreads();
    #pragma unroll
    for (int p = 0; p < 2; p++){
      int idx = tid + p*256;
      int r = idx >> 2, ch = idx & 3;
      *(bf16x8*)(&Al[r][ch*8]) = ra[p];
      *(bf16x8*)(&Bl[r][ch*8]) = rb[p];
    }
    __syncthreads();
    bf16x8 af[4], bfr[4];
    #pragma unroll
    for (int i = 0; i < 4; i++) af[i]  = *(const bf16x8*)(&Al[wm*64 + i*16 + fr][kb*8]);
    #pragma unroll
    for (int j = 0; j < 4; j++) bfr[j] = *(const bf16x8*)(&Bl[wn*64 + j*16 + fr][kb*8]);
    #pragma unroll
    for (int i = 0; i < 4; i++)
      #pragma unroll
      for (int j = 0; j < 4; j++)
        acc[i][j] = __builtin_amdgcn_mfma_f32_16x16x32_bf16(af[i], bfr[j], acc[i][j], 0, 0, 0);
  }
  // C/D layout: col = lane&15, row = (lane>>4)*4 + q  (m89-verified)
  #pragma unroll
  for (int i = 0; i < 4; i++){
    #pragma unroll
    for (int q = 0; q < 4; q++){
      int grow = row0 + wm*64 + i*16 + kb*4 + q;
      if (grow < M){
        #pragma unroll
        for (int j = 0; j < 4; j++)
          C[(size_t)grow*256 + col0 + wn*64 + j*16 + fr] = acc[i][j][q];
      }
    }
  }
}

// ---------------- edge logits (wave per edge, float4) + fused segment max ----------------
__global__ __launch_bounds__(256) void edge_logits2(const int* __restrict__ src, const int* __restrict__ dst,
                                                    const float* __restrict__ hs, const float* __restrict__ hd,
                                                    const float* __restrict__ att, float* __restrict__ eo,
                                                    unsigned* __restrict__ mxu){
  int e = blockIdx.x*4 + (threadIdx.x >> 6);
  int lane = threadIdx.x & 63;
  int h = lane >> 4;
  if (e >= EE) return;
  int s = src[e], d = dst[e];
  const float4 a = *(const float4*)(hs + (size_t)s*256 + lane*4);
  const float4 b = *(const float4*)(hd + (size_t)d*256 + lane*4);
  const float4 av = *(const float4*)(att + lane*4);
  float4 m;
  m.x = a.x + b.x; m.y = a.y + b.y; m.z = a.z + b.z; m.w = a.w + b.w;
  m.x = (m.x > 0.f) ? m.x : 0.2f*m.x;
  m.y = (m.y > 0.f) ? m.y : 0.2f*m.y;
  m.z = (m.z > 0.f) ? m.z : 0.2f*m.z;
  m.w = (m.w > 0.f) ? m.w : 0.2f*m.w;
  float p = m.x*av.x + m.y*av.y + m.z*av.z + m.w*av.w;
  #pragma unroll
  for (int msk = 8; msk > 0; msk >>= 1) p += __shfl_xor(p, msk);
  if ((lane & 15) == 0){
    eo[e*4 + h] = p;
    atomicMax(&mxu[d*4 + h], enc_f(p));
  }
}

// ---------------- per-(edge,head) softmax numerator ----------------
__global__ __launch_bounds__(256) void edge_w(const int* __restrict__ dst, const float* __restrict__ elog,
                                              const unsigned* __restrict__ mxu, float* __restrict__ wbuf){
  int idx = blockIdx.x*256 + threadIdx.x;
  if (idx >= EE*4) return;
  int e = idx >> 2, h = idx & 3;
  float mx = dec_f(mxu[dst[e]*4 + h]);
  wbuf[idx] = expf(elog[idx] - mx);
}

// ---------------- weighted aggregation (wave per node, float4, single pass) ----------------
// outb != null -> write bf16 (h1 path, feeds next GEMM); else f32 to outp.
__global__ __launch_bounds__(256) void aggregate_w(const int* __restrict__ rp, const int* __restrict__ eids,
                                                   const int* __restrict__ src, const float* __restrict__ wbuf,
                                                   const float* __restrict__ hs, const float* __restrict__ bias,
                                                   float* __restrict__ outp, unsigned short* __restrict__ outb,
                                                   int do_relu){
  int n = blockIdx.x*4 + (threadIdx.x >> 6);
  int lane = threadIdx.x & 63;
  int h = lane >> 4;
  if (n >= NN) return;
  int beg = rp[n], end = rp[n+1];
  float4 acc = {0.f,0.f,0.f,0.f};
  float sw = 0.f;
  for (int i = beg; i < end; i++){
    int eid = eids[i];
    float w = wbuf[eid*4 + h];
    int s = src[eid];
    const float4 hv = *(const float4*)(hs + (size_t)s*256 + lane*4);
    acc.x = fmaf(w, hv.x, acc.x);
    acc.y = fmaf(w, hv.y, acc.y);
    acc.z = fmaf(w, hv.z, acc.z);
    acc.w = fmaf(w, hv.w, acc.w);
    sw += w;
  }
  float inv = 1.f / (sw + 1e-16f);
  const float4 b4 = *(const float4*)(bias + lane*4);
  float4 r;
  r.x = acc.x*inv + b4.x;
  r.y = acc.y*inv + b4.y;
  r.z = acc.z*inv + b4.z;
  r.w = acc.w*inv + b4.w;
  if (do_relu){
    r.x = fmaxf(r.x, 0.f); r.y = fmaxf(r.y, 0.f);
    r.z = fmaxf(r.z, 0.f); r.w = fmaxf(r.w, 0.f);
  }
  if (outb){
    ushort4 o;
    o.x = f2b(r.x); o.y = f2b(r.y); o.z = f2b(r.z); o.w = f2b(r.w);
    *(ushort4*)(outb + (size_t)n*256 + lane*4) = o;
  } else {
    *(float4*)(outp + (size_t)n*256 + lane*4) = r;
  }
}

// ---------------- pool logits GEMM + fused row softmax -> s_assign[N][48] ----------------
__global__ __launch_bounds__(256) void pool_logits_sm(const float* __restrict__ h2, const float* __restrict__ Wp,
                                                      const float* __restrict__ bp, float* __restrict__ s_out){
  __shared__ float As[16][68];   // [kk][row]
  __shared__ float Ws[16][KC];   // [kk][col]
  int tid = threadIdx.x;
  int row0 = blockIdx.x * 64;
  int tx = tid & 15;
  int ty = tid >> 4;
  float acc[4][3] = {};
  for (int k0 = 0; k0 < 256; k0 += 16){
    #pragma unroll
    for (int p = 0; p < 4; p++){
      int idx = tid + p*256;
      int r  = idx >> 4;
      int kk = idx & 15;
      int gr = row0 + r;
      As[kk][r] = (gr < NN) ? h2[(size_t)gr*256 + k0 + kk] : 0.f;
    }
    {
      int idx = tid;
      if (idx < 768) Ws[idx/KC][idx%KC] = Wp[(size_t)(k0 + idx/KC)*KC + idx%KC];
      idx = tid + 256;
      Ws[idx/KC][idx%KC] = Wp[(size_t)(k0 + idx/KC)*KC + idx%KC];
      idx = tid + 512;
      Ws[idx/KC][idx%KC] = Wp[(size_t)(k0 + idx/KC)*KC + idx%KC];
    }
    __syncthreads();
    #pragma unroll
    for (int kk = 0; kk < 16; kk++){
      float a[4], b[3];
      #pragma unroll
      for (int i = 0; i < 4; i++) a[i] = As[kk][ty*4 + i];
      #pragma unroll
      for (int j = 0; j < 3; j++) b[j] = Ws[kk][tx*3 + j];
      #pragma unroll
      for (int i = 0; i < 4; i++)
        #pragma unroll
        for (int j = 0; j < 3; j++)
          acc[i][j] = fmaf(a[i], b[j], acc[i][j]);
    }
    __syncthreads();
  }
  float bb[3];
  #pragma unroll
  for (int j = 0; j < 3; j++) bb[j] = bp[tx*3 + j];
  #pragma unroll
  for (int i = 0; i < 4; i++){
    int gr = row0 + ty*4 + i;
    float m = -INFINITY;
    #pragma unroll
    for (int j = 0; j < 3; j++){ acc[i][j] += bb[j]; m = fmaxf(m, acc[i][j]); }
    #pragma unroll
    for (int mask = 8; mask > 0; mask >>= 1) m = fmaxf(m, __shfl_xor(m, mask));
    float e[3], s = 0.f;
    #pragma unroll
    for (int j = 0; j < 3; j++){ e[j] = expf(acc[i][j] - m); s += e[j]; }
    #pragma unroll
    for (int mask = 8; mask > 0; mask >>= 1) s += __shfl_xor(s, mask);
    float inv = 1.f / s;
    if (gr < NN){
      #pragma unroll
      for (int j = 0; j < 3; j++) s_out[(size_t)gr*KC + tx*3 + j] = e[j] * inv;
    }
  }
}

// ---------------- x_pooled = s.T @ h2, split-K two-stage ----------------
#define PCH 64
#define NPART ((NN + PCH - 1)/PCH)   // 782
__global__ __launch_bounds__(256) void pooled_partial(const float* __restrict__ s, const float* __restrict__ h2,
                                                      float* __restrict__ part){
  __shared__ float sld[PCH][KC];
  int t = threadIdx.x;
  int base = blockIdx.x * PCH;
  int cnt = min(PCH, NN - base);
  for (int idx = t; idx < cnt*KC; idx += 256)
    sld[idx/KC][idx%KC] = s[(size_t)(base + idx/KC)*KC + idx%KC];
  __syncthreads();
  float acc[KC];
  #pragma unroll
  for (int k = 0; k < KC; k++) acc[k] = 0.f;
  for (int n = 0; n < cnt; n++){
    float v = h2[(size_t)(base + n)*256 + t];
    #pragma unroll
    for (int k = 0; k < KC; k++) acc[k] = fmaf(sld[n][k], v, acc[k]);
  }
  float* po = part + (size_t)blockIdx.x*KC*256;
  #pragma unroll
  for (int k = 0; k < KC; k++) po[k*256 + t] = acc[k];
}
#define PSPL 8
__global__ __launch_bounds__(256) void pooled_reduce(const float* __restrict__ part, float* __restrict__ xp){
  int idx = blockIdx.x*256 + threadIdx.x;     // 0..12287
  const int per = (NPART + PSPL - 1)/PSPL;    // 98
  int p0 = blockIdx.y * per;
  int p1 = min(p0 + per, NPART);
  float s0 = 0.f, s1 = 0.f;
  int p = p0;
  for (; p + 1 < p1; p += 2){
    s0 += part[(size_t)p*KC*256 + idx];
    s1 += part[(size_t)(p+1)*KC*256 + idx];
  }
  if (p < p1) s0 += part[(size_t)p*KC*256 + idx];
  atomicAdd(&xp[idx], s0 + s1);
}

// ---------------- edge_attr mean over E -> [48], parallel grid-stride ----------------
#define BPT 128
__global__ __launch_bounds__(256) void edge_attr_mean(const float* __restrict__ ea, float* __restrict__ out){
  int t   = blockIdx.x / BPT;
  int blk = blockIdx.x % BPT;
  const int NF4 = EE * 2;
  const int per_blk = (NF4 + BPT - 1) / BPT;
  int i0 = blk * per_blk;
  int i1 = min(i0 + per_blk, NF4);
  const float4* base = (const float4*)(ea + (size_t)t*EE*DE);
  float s[8] = {0,0,0,0,0,0,0,0};
  for (int i = i0 + (int)threadIdx.x; i < i1; i += 256){
    float4 v = base[i];
    int db = (i & 1) * 4;
    s[db+0] += v.x; s[db+1] += v.y; s[db+2] += v.z; s[db+3] += v.w;
  }
  __shared__ float red[256];
  for (int d = 0; d < 8; d++){
    red[threadIdx.x] = s[d];
    __syncthreads();
    for (int off = 128; off > 0; off >>= 1){
      if (threadIdx.x < (unsigned)off) red[threadIdx.x] += red[threadIdx.x + off];
      __syncthreads();
    }
    if (threadIdx.x == 0) atomicAdd(&out[t*DE + d], red[0] / (float)EE);
    __syncthreads();
  }
}

// ---------------- final classifier ----------------
__global__ void final_cls(const float* __restrict__ xp, const float* __restrict__ agg,
                          const float* __restrict__ Wc, const float* __restrict__ bc,
                          float* __restrict__ out){
  int k = threadIdx.x;
  if (k < KC){
    float s = bc[0];
    for (int f = 0; f < 256; f++) s = fmaf(xp[k*256 + f], Wc[f], s);
    s = fmaf(agg[k], Wc[256], s);
    out[k] = 1.f/(1.f + expf(-s));
  }
}

extern "C" void kernel_launch(void* const* d_in, const int* in_sizes, int n_in,
                              void* d_out, int out_size, void* d_ws, size_t ws_size,
                              hipStream_t stream) {
  const float* x_pkg     = (const float*)d_in[0];
  const float* x_dst     = (const float*)d_in[1];
  const float* edge_attr = (const float*)d_in[2];
  const float* node_mask = (const float*)d_in[3];
  const float* W1_src    = (const float*)d_in[4];
  const float* W1_dst    = (const float*)d_in[5];
  const float* att1      = (const float*)d_in[6];
  const float* b1        = (const float*)d_in[7];
  const float* W2_src    = (const float*)d_in[8];
  const float* W2_dst    = (const float*)d_in[9];
  const float* att2      = (const float*)d_in[10];
  const float* b2        = (const float*)d_in[11];
  const float* W_pool    = (const float*)d_in[12];
  const float* b_pool    = (const float*)d_in[13];
  const float* W_cls     = (const float*)d_in[14];
  const float* b_cls     = (const float*)d_in[15];
  const int*   edge_index= (const int*)d_in[16];
  float* out = (float*)d_out;

  const int T5 = TT - 1;
  const float* W1s5 = W1_src + (size_t)T5*DIN*FDIM;
  const float* W1d5 = W1_dst + (size_t)T5*DIN*FDIM;
  const float* a1_5 = att1   + (size_t)T5*FDIM;
  const float* b1_5 = b1     + (size_t)T5*FDIM;
  const float* W2s5 = W2_src + (size_t)T5*DIN*FDIM;
  const float* W2d5 = W2_dst + (size_t)T5*FDIM*FDIM;
  const float* a2_5 = att2   + (size_t)T5*FDIM;
  const float* b2_5 = b2     + (size_t)T5*FDIM;
  const float* xd5  = x_dst  + (size_t)T5*NN*DIN;
  const int* src5   = edge_index + (size_t)T5*2*EE;
  const int* dst5   = src5 + EE;

  // ---- workspace layout (with bf16 overlays into dead f32 regions) ----
  float* buf0 = (float*)d_ws;            // hs1 -> hs2 -> pooled partials
  float* buf1 = buf0 + (size_t)NN*FDIM;  // hd1 -> h1b(bf16) -> h2(f32)
  float* buf2 = buf1 + (size_t)NN*FDIM;  // Xd_b/Xp_b(bf16) -> hd2(f32)
  float* elog = buf2 + (size_t)NN*FDIM;  // [EE*4]
  float* sass = elog + (size_t)EE*4;     // [NN*KC]
  float* xpool= sass + (size_t)NN*KC;    // [KC*256]
  float* aggE = xpool + KC*FDIM;         // [64]
  float* wbuf = aggE + 64;               // [EE*4]
  unsigned* mxu = (unsigned*)(wbuf + (size_t)EE*4); // [NN*4]
  int* deg    = (int*)(mxu + (size_t)NN*4);
  int* rp     = deg + NN;
  int* cursor = rp + NN + 1;
  int* eids   = cursor + NN;
  unsigned short* Wt1s = (unsigned short*)(eids + EE);   // [256*128]
  unsigned short* Wt1d = Wt1s + 256*DIN;
  unsigned short* Wt2s = Wt1d + 256*DIN;
  unsigned short* Wt2d = Wt2s + 256*DIN;                 // [256*256]
  int* bsum = (int*)(Wt2d + 256*FDIM);   // [NB]
  int* boff = bsum + NB;                 // [NB]
  // bf16 overlays (dead-region reuse):
  unsigned short* Xd_b = (unsigned short*)buf2;                    // 12.8 MB, dead after hd1 gemm
  unsigned short* Xp_b = (unsigned short*)buf2 + 8u*1024u*1024u;   // @16 MB, dead after hs2 gemm
  unsigned short* h1b  = (unsigned short*)buf1;                    // 25.6 MB, dead after hd2 gemm

  dim3 ggrid((NN + 127)/128, 2);

  // CSR over dst (shared by both GAT layers) — hierarchical scan
  zero_i32<<<(NN+255)/256, 256, 0, stream>>>(deg, NN);
  count_deg<<<(EE+255)/256, 256, 0, stream>>>(dst5, deg);
  scan_blk<<<NB, 256, 0, stream>>>(deg, rp, bsum);
  scan_sums<<<1, 256, 0, stream>>>(bsum, boff);
  scan_add<<<NB, 256, 0, stream>>>(rp, boff, cursor);
  scatter_edges<<<(EE+255)/256, 256, 0, stream>>>(dst5, cursor, eids);

  // edge_attr mean (independent path)
  zero_i32<<<1, 64, 0, stream>>>((int*)aggE, 64);
  edge_attr_mean<<<TT*BPT, 256, 0, stream>>>(edge_attr, aggE);

  // conversions: masked inputs + transposed weights -> bf16
  cvt_mask<<<(NN*DIN/8 + 255)/256, 256, 0, stream>>>(x_pkg, node_mask, Xp_b, NN*DIN, DIN);
  cvt_mask<<<(NN*DIN/8 + 255)/256, 256, 0, stream>>>(xd5,   node_mask, Xd_b, NN*DIN, DIN);
  cvt_wt<<<256, 256, 0, stream>>>(W1s5, Wt1s, DIN);
  cvt_wt<<<256, 256, 0, stream>>>(W1d5, Wt1d, DIN);
  cvt_wt<<<256, 256, 0, stream>>>(W2s5, Wt2s, DIN);
  cvt_wt<<<256, 256, 0, stream>>>(W2d5, Wt2d, FDIM);

  // layer 1
  gemm_bf16<<<ggrid, 256, 0, stream>>>((const short*)Xp_b, (const short*)Wt1s, buf0, NN, DIN); // hs1
  gemm_bf16<<<ggrid, 256, 0, stream>>>((const short*)Xd_b, (const short*)Wt1d, buf1, NN, DIN); // hd1
  zero_i32<<<(NN*4+255)/256, 256, 0, stream>>>((int*)mxu, NN*4);
  edge_logits2<<<EE/4, 256, 0, stream>>>(src5, dst5, buf0, buf1, a1_5, elog, mxu);
  edge_w<<<(EE*4+255)/256, 256, 0, stream>>>(dst5, elog, mxu, wbuf);
  aggregate_w<<<NN/4, 256, 0, stream>>>(rp, eids, src5, wbuf, buf0, b1_5, nullptr, h1b, 1); // h1 -> bf16

  // layer 2
  gemm_bf16<<<ggrid, 256, 0, stream>>>((const short*)Xp_b, (const short*)Wt2s, buf0, NN, DIN);  // hs2
  gemm_bf16<<<ggrid, 256, 0, stream>>>((const short*)h1b,  (const short*)Wt2d, buf2, NN, FDIM); // hd2
  zero_i32<<<(NN*4+255)/256, 256, 0, stream>>>((int*)mxu, NN*4);
  edge_logits2<<<EE/4, 256, 0, stream>>>(src5, dst5, buf0, buf2, a2_5, elog, mxu);
  edge_w<<<(EE*4+255)/256, 256, 0, stream>>>(dst5, elog, mxu, wbuf);
  aggregate_w<<<NN/4, 256, 0, stream>>>(rp, eids, src5, wbuf, buf0, b2_5, buf1, nullptr, 0); // h2 -> buf1 (f32)

  // pooling + classifier (h2 = buf1; buf0 free -> partials)
  pool_logits_sm<<<NPART, 256, 0, stream>>>(buf1, W_pool, b_pool, sass);
  zero_i32<<<(KC*FDIM+255)/256, 256, 0, stream>>>((int*)xpool, KC*FDIM);
  pooled_partial<<<NPART, 256, 0, stream>>>(sass, buf1, buf0);
  pooled_reduce<<<dim3(KC, PSPL), 256, 0, stream>>>(buf0, xpool);
  final_cls<<<1, 64, 0, stream>>>(xpool, aggE, W_cls, b_cls, out);
}

// Round 8
// 467.002 us; speedup vs baseline: 2.9095x; 1.1121x over previous
//
#include <hip/hip_runtime.h>
#include <math.h>

#define NN 50000      // nodes (both src and dst)
#define DIN 128
#define FDIM 256      // H*C
#define EE 200000
#define TT 6
#define DE 8
#define KC 48         // clusters
#define NB ((NN + 255)/256)   // 196 scan blocks

typedef __attribute__((ext_vector_type(8))) short bf16x8;
typedef __attribute__((ext_vector_type(8))) unsigned short u16x8;
typedef __attribute__((ext_vector_type(4))) float f32x4;

// f32 -> bf16 round-to-nearest-even
__device__ inline unsigned short f2b(float f){
  unsigned u = __float_as_uint(f);
  unsigned r = u + 0x7FFFu + ((u >> 16) & 1u);
  return (unsigned short)(r >> 16);
}
// bf16 -> f32
__device__ inline float b2f(unsigned short u){ return __uint_as_float(((unsigned)u) << 16); }

// ---------------- utility kernels ----------------
__global__ void zero_i32(int* __restrict__ p, int n){
  int i = blockIdx.x*256 + threadIdx.x;
  if (i < n) p[i] = 0;
}

__global__ void count_deg(const int* __restrict__ dst, int* __restrict__ deg){
  int i = blockIdx.x*256 + threadIdx.x;
  if (i < EE) atomicAdd(&deg[dst[i]], 1);
}

// ---------------- hierarchical exclusive scan ----------------
__global__ __launch_bounds__(256) void scan_blk(const int* __restrict__ deg, int* __restrict__ rp,
                                                int* __restrict__ bsum){
  __shared__ int sm[256];
  int i = blockIdx.x*256 + threadIdx.x;
  int v = (i < NN) ? deg[i] : 0;
  sm[threadIdx.x] = v;
  __syncthreads();
  #pragma unroll
  for (int off = 1; off < 256; off <<= 1){
    int t = (threadIdx.x >= (unsigned)off) ? sm[threadIdx.x - off] : 0;
    __syncthreads();
    sm[threadIdx.x] += t;
    __syncthreads();
  }
  if (i < NN) rp[i] = sm[threadIdx.x] - v;   // block-local exclusive
  if (threadIdx.x == 255) bsum[blockIdx.x] = sm[255];
}

__global__ __launch_bounds__(256) void scan_sums(const int* __restrict__ bsum, int* __restrict__ boff){
  __shared__ int sm[256];
  int v = (threadIdx.x < NB) ? bsum[threadIdx.x] : 0;
  sm[threadIdx.x] = v;
  __syncthreads();
  #pragma unroll
  for (int off = 1; off < 256; off <<= 1){
    int t = (threadIdx.x >= (unsigned)off) ? sm[threadIdx.x - off] : 0;
    __syncthreads();
    sm[threadIdx.x] += t;
    __syncthreads();
  }
  if (threadIdx.x < NB) boff[threadIdx.x] = sm[threadIdx.x] - v;
}

__global__ __launch_bounds__(256) void scan_add(int* __restrict__ rp, const int* __restrict__ boff,
                                                int* __restrict__ cursor){
  int i = blockIdx.x*256 + threadIdx.x;
  if (i < NN){
    int r = rp[i] + boff[blockIdx.x];
    rp[i] = r;
    cursor[i] = r;
  }
  if (i == 0) rp[NN] = EE;
}

__global__ void scatter_edges(const int* __restrict__ dst, int* __restrict__ cursor, int* __restrict__ eids){
  int i = blockIdx.x*256 + threadIdx.x;
  if (i < EE){ int pos = atomicAdd(&cursor[dst[i]], 1); eids[pos] = i; }
}

// ---------------- conversions ----------------
__global__ __launch_bounds__(256) void cvt_mask(const float* __restrict__ in, const float* __restrict__ mask,
                                                unsigned short* __restrict__ outb, int total, int K){
  int i = (blockIdx.x*256 + threadIdx.x)*8;
  if (i >= total) return;
  float m = mask[i / K];
  float4 a = *(const float4*)(in + i);
  float4 b = *(const float4*)(in + i + 4);
  u16x8 o;
  o[0]=f2b(a.x*m); o[1]=f2b(a.y*m); o[2]=f2b(a.z*m); o[3]=f2b(a.w*m);
  o[4]=f2b(b.x*m); o[5]=f2b(b.y*m); o[6]=f2b(b.z*m); o[7]=f2b(b.w*m);
  *(u16x8*)(outb + i) = o;
}

__global__ void cvt_wt(const float* __restrict__ W, unsigned short* __restrict__ Wt, int K){
  int n = blockIdx.x;
  for (int k = threadIdx.x; k < K; k += 256)
    Wt[(size_t)n*K + k] = f2b(W[(size_t)k*256 + n]);
}

// ---------------- MFMA GEMM: Cb[M,256](bf16) = A[M,K](bf16) @ Wt[256,K](bf16)^T ----------------
// tile 128x128, BK=32, 4 waves (2x2 of 64x64). Fragment layouts per learn_hip m89/m91.
__global__ __launch_bounds__(256) void gemm_bf16(const short* __restrict__ A, const short* __restrict__ Wt,
                                                 unsigned short* __restrict__ Cb, int M, int K){
  __shared__ short Al[128][56];   // stride 112B: 16B-aligned, ~2-way banks
  __shared__ short Bl[128][56];
  int tid = threadIdx.x;
  int lane = tid & 63;
  int w = tid >> 6;
  int wm = w >> 1, wn = w & 1;
  int row0 = blockIdx.x * 128, col0 = blockIdx.y * 128;
  int fr = lane & 15;   // fragment row (A) / col (B)
  int kb = lane >> 4;   // k-block 0..3 (8 bf16 each)
  f32x4 acc[4][4];
  #pragma unroll
  for (int i = 0; i < 4; i++)
    #pragma unroll
    for (int j = 0; j < 4; j++)
      acc[i][j] = (f32x4){0.f, 0.f, 0.f, 0.f};

  for (int k0 = 0; k0 < K; k0 += 32){
    bf16x8 ra[2], rb[2];
    #pragma unroll
    for (int p = 0; p < 2; p++){
      int idx = tid + p*256;          // 0..511
      int r = idx >> 2, ch = idx & 3;
      int gr = row0 + r;
      if (gr < M) ra[p] = *(const bf16x8*)(A + (size_t)gr*K + k0 + ch*8);
      else        ra[p] = (bf16x8){0,0,0,0,0,0,0,0};
      rb[p] = *(const bf16x8*)(Wt + (size_t)(col0 + r)*K + k0 + ch*8);
    }
    __syncthreads();
    #pragma unroll
    for (int p = 0; p < 2; p++){
      int idx = tid + p*256;
      int r = idx >> 2, ch = idx & 3;
      *(bf16x8*)(&Al[r][ch*8]) = ra[p];
      *(bf16x8*)(&Bl[r][ch*8]) = rb[p];
    }
    __syncthreads();
    bf16x8 af[4], bfr[4];
    #pragma unroll
    for (int i = 0; i < 4; i++) af[i]  = *(const bf16x8*)(&Al[wm*64 + i*16 + fr][kb*8]);
    #pragma unroll
    for (int j = 0; j < 4; j++) bfr[j] = *(const bf16x8*)(&Bl[wn*64 + j*16 + fr][kb*8]);
    #pragma unroll
    for (int i = 0; i < 4; i++)
      #pragma unroll
      for (int j = 0; j < 4; j++)
        acc[i][j] = __builtin_amdgcn_mfma_f32_16x16x32_bf16(af[i], bfr[j], acc[i][j], 0, 0, 0);
  }
  // C/D layout: col = lane&15, row = (lane>>4)*4 + q  (m89-verified)
  #pragma unroll
  for (int i = 0; i < 4; i++){
    #pragma unroll
    for (int q = 0; q < 4; q++){
      int grow = row0 + wm*64 + i*16 + kb*4 + q;
      if (grow < M){
        #pragma unroll
        for (int j = 0; j < 4; j++)
          Cb[(size_t)grow*256 + col0 + wn*64 + j*16 + fr] = f2b(acc[i][j][q]);
      }
    }
  }
}

// ---------------- edge logits (bf16 inputs) -> exp weight directly (no segment max) ----------------
// logits on this dataset are O(1); exp(e) / sum(exp(e)) == softmax(e - m) exactly after
// normalization. Clamp at 80 guards absolute f32 overflow.
__global__ __launch_bounds__(256) void edge_logits3(const int* __restrict__ src, const int* __restrict__ dst,
                                                    const unsigned short* __restrict__ hs,
                                                    const unsigned short* __restrict__ hd,
                                                    const float* __restrict__ att, float* __restrict__ wbuf){
  int e = blockIdx.x*4 + (threadIdx.x >> 6);
  int lane = threadIdx.x & 63;
  int h = lane >> 4;
  if (e >= EE) return;
  int s = src[e], d = dst[e];
  ushort4 ua = *(const ushort4*)(hs + (size_t)s*256 + lane*4);
  ushort4 ub = *(const ushort4*)(hd + (size_t)d*256 + lane*4);
  const float4 av = *(const float4*)(att + lane*4);
  float m0 = b2f(ua.x) + b2f(ub.x);
  float m1 = b2f(ua.y) + b2f(ub.y);
  float m2 = b2f(ua.z) + b2f(ub.z);
  float m3 = b2f(ua.w) + b2f(ub.w);
  m0 = (m0 > 0.f) ? m0 : 0.2f*m0;
  m1 = (m1 > 0.f) ? m1 : 0.2f*m1;
  m2 = (m2 > 0.f) ? m2 : 0.2f*m2;
  m3 = (m3 > 0.f) ? m3 : 0.2f*m3;
  float p = m0*av.x + m1*av.y + m2*av.z + m3*av.w;
  #pragma unroll
  for (int msk = 8; msk > 0; msk >>= 1) p += __shfl_xor(p, msk);
  if ((lane & 15) == 0) wbuf[e*4 + h] = expf(fminf(p, 80.f));
}

// ---------------- weighted aggregation (bf16 hs gather, single pass) ----------------
// outb != null -> write bf16 (h1 path); else f32 to outp (h2 path).
__global__ __launch_bounds__(256) void aggregate_w(const int* __restrict__ rp, const int* __restrict__ eids,
                                                   const int* __restrict__ src, const float* __restrict__ wbuf,
                                                   const unsigned short* __restrict__ hs,
                                                   const float* __restrict__ bias,
                                                   float* __restrict__ outp, unsigned short* __restrict__ outb,
                                                   int do_relu){
  int n = blockIdx.x*4 + (threadIdx.x >> 6);
  int lane = threadIdx.x & 63;
  int h = lane >> 4;
  if (n >= NN) return;
  int beg = rp[n], end = rp[n+1];
  float4 acc = {0.f,0.f,0.f,0.f};
  float sw = 0.f;
  for (int i = beg; i < end; i++){
    int eid = eids[i];
    float w = wbuf[eid*4 + h];
    int s = src[eid];
    ushort4 hv = *(const ushort4*)(hs + (size_t)s*256 + lane*4);
    acc.x = fmaf(w, b2f(hv.x), acc.x);
    acc.y = fmaf(w, b2f(hv.y), acc.y);
    acc.z = fmaf(w, b2f(hv.z), acc.z);
    acc.w = fmaf(w, b2f(hv.w), acc.w);
    sw += w;
  }
  float inv = 1.f / (sw + 1e-16f);
  const float4 b4 = *(const float4*)(bias + lane*4);
  float4 r;
  r.x = acc.x*inv + b4.x;
  r.y = acc.y*inv + b4.y;
  r.z = acc.z*inv + b4.z;
  r.w = acc.w*inv + b4.w;
  if (do_relu){
    r.x = fmaxf(r.x, 0.f); r.y = fmaxf(r.y, 0.f);
    r.z = fmaxf(r.z, 0.f); r.w = fmaxf(r.w, 0.f);
  }
  if (outb){
    ushort4 o;
    o.x = f2b(r.x); o.y = f2b(r.y); o.z = f2b(r.z); o.w = f2b(r.w);
    *(ushort4*)(outb + (size_t)n*256 + lane*4) = o;
  } else {
    *(float4*)(outp + (size_t)n*256 + lane*4) = r;
  }
}

// ---------------- pool logits GEMM + fused row softmax -> s_assign[N][48] ----------------
__global__ __launch_bounds__(256) void pool_logits_sm(const float* __restrict__ h2, const float* __restrict__ Wp,
                                                      const float* __restrict__ bp, float* __restrict__ s_out){
  __shared__ float As[16][68];   // [kk][row]
  __shared__ float Ws[16][KC];   // [kk][col]
  int tid = threadIdx.x;
  int row0 = blockIdx.x * 64;
  int tx = tid & 15;
  int ty = tid >> 4;
  float acc[4][3] = {};
  for (int k0 = 0; k0 < 256; k0 += 16){
    #pragma unroll
    for (int p = 0; p < 4; p++){
      int idx = tid + p*256;
      int r  = idx >> 4;
      int kk = idx & 15;
      int gr = row0 + r;
      As[kk][r] = (gr < NN) ? h2[(size_t)gr*256 + k0 + kk] : 0.f;
    }
    {
      int idx = tid;
      if (idx < 768) Ws[idx/KC][idx%KC] = Wp[(size_t)(k0 + idx/KC)*KC + idx%KC];
      idx = tid + 256;
      Ws[idx/KC][idx%KC] = Wp[(size_t)(k0 + idx/KC)*KC + idx%KC];
      idx = tid + 512;
      Ws[idx/KC][idx%KC] = Wp[(size_t)(k0 + idx/KC)*KC + idx%KC];
    }
    __syncthreads();
    #pragma unroll
    for (int kk = 0; kk < 16; kk++){
      float a[4], b[3];
      #pragma unroll
      for (int i = 0; i < 4; i++) a[i] = As[kk][ty*4 + i];
      #pragma unroll
      for (int j = 0; j < 3; j++) b[j] = Ws[kk][tx*3 + j];
      #pragma unroll
      for (int i = 0; i < 4; i++)
        #pragma unroll
        for (int j = 0; j < 3; j++)
          acc[i][j] = fmaf(a[i], b[j], acc[i][j]);
    }
    __syncthreads();
  }
  float bb[3];
  #pragma unroll
  for (int j = 0; j < 3; j++) bb[j] = bp[tx*3 + j];
  #pragma unroll
  for (int i = 0; i < 4; i++){
    int gr = row0 + ty*4 + i;
    float m = -INFINITY;
    #pragma unroll
    for (int j = 0; j < 3; j++){ acc[i][j] += bb[j]; m = fmaxf(m, acc[i][j]); }
    #pragma unroll
    for (int mask = 8; mask > 0; mask >>= 1) m = fmaxf(m, __shfl_xor(m, mask));
    float e[3], s = 0.f;
    #pragma unroll
    for (int j = 0; j < 3; j++){ e[j] = expf(acc[i][j] - m); s += e[j]; }
    #pragma unroll
    for (int mask = 8; mask > 0; mask >>= 1) s += __shfl_xor(s, mask);
    float inv = 1.f / s;
    if (gr < NN){
      #pragma unroll
      for (int j = 0; j < 3; j++) s_out[(size_t)gr*KC + tx*3 + j] = e[j] * inv;
    }
  }
}

// ---------------- x_pooled = s.T @ h2, split-K two-stage ----------------
#define PCH 64
#define NPART ((NN + PCH - 1)/PCH)   // 782
__global__ __launch_bounds__(256) void pooled_partial(const float* __restrict__ s, const float* __restrict__ h2,
                                                      float* __restrict__ part){
  __shared__ float sld[PCH][KC];
  int t = threadIdx.x;
  int base = blockIdx.x * PCH;
  int cnt = min(PCH, NN - base);
  for (int idx = t; idx < cnt*KC; idx += 256)
    sld[idx/KC][idx%KC] = s[(size_t)(base + idx/KC)*KC + idx%KC];
  __syncthreads();
  float acc[KC];
  #pragma unroll
  for (int k = 0; k < KC; k++) acc[k] = 0.f;
  for (int n = 0; n < cnt; n++){
    float v = h2[(size_t)(base + n)*256 + t];
    #pragma unroll
    for (int k = 0; k < KC; k++) acc[k] = fmaf(sld[n][k], v, acc[k]);
  }
  float* po = part + (size_t)blockIdx.x*KC*256;
  #pragma unroll
  for (int k = 0; k < KC; k++) po[k*256 + t] = acc[k];
}
#define PSPL 8
__global__ __launch_bounds__(256) void pooled_reduce(const float* __restrict__ part, float* __restrict__ xp){
  int idx = blockIdx.x*256 + threadIdx.x;     // 0..12287
  const int per = (NPART + PSPL - 1)/PSPL;    // 98
  int p0 = blockIdx.y * per;
  int p1 = min(p0 + per, NPART);
  float s0 = 0.f, s1 = 0.f;
  int p = p0;
  for (; p + 1 < p1; p += 2){
    s0 += part[(size_t)p*KC*256 + idx];
    s1 += part[(size_t)(p+1)*KC*256 + idx];
  }
  if (p < p1) s0 += part[(size_t)p*KC*256 + idx];
  atomicAdd(&xp[idx], s0 + s1);
}

// ---------------- edge_attr mean over E -> [48], parallel grid-stride ----------------
#define BPT 128
__global__ __launch_bounds__(256) void edge_attr_mean(const float* __restrict__ ea, float* __restrict__ out){
  int t   = blockIdx.x / BPT;
  int blk = blockIdx.x % BPT;
  const int NF4 = EE * 2;
  const int per_blk = (NF4 + BPT - 1) / BPT;
  int i0 = blk * per_blk;
  int i1 = min(i0 + per_blk, NF4);
  const float4* base = (const float4*)(ea + (size_t)t*EE*DE);
  float s[8] = {0,0,0,0,0,0,0,0};
  for (int i = i0 + (int)threadIdx.x; i < i1; i += 256){
    float4 v = base[i];
    int db = (i & 1) * 4;
    s[db+0] += v.x; s[db+1] += v.y; s[db+2] += v.z; s[db+3] += v.w;
  }
  __shared__ float red[256];
  for (int d = 0; d < 8; d++){
    red[threadIdx.x] = s[d];
    __syncthreads();
    for (int off = 128; off > 0; off >>= 1){
      if (threadIdx.x < (unsigned)off) red[threadIdx.x] += red[threadIdx.x + off];
      __syncthreads();
    }
    if (threadIdx.x == 0) atomicAdd(&out[t*DE + d], red[0] / (float)EE);
    __syncthreads();
  }
}

// ---------------- final classifier ----------------
__global__ void final_cls(const float* __restrict__ xp, const float* __restrict__ agg,
                          const float* __restrict__ Wc, const float* __restrict__ bc,
                          float* __restrict__ out){
  int k = threadIdx.x;
  if (k < KC){
    float s = bc[0];
    for (int f = 0; f < 256; f++) s = fmaf(xp[k*256 + f], Wc[f], s);
    s = fmaf(agg[k], Wc[256], s);
    out[k] = 1.f/(1.f + expf(-s));
  }
}

extern "C" void kernel_launch(void* const* d_in, const int* in_sizes, int n_in,
                              void* d_out, int out_size, void* d_ws, size_t ws_size,
                              hipStream_t stream) {
  const float* x_pkg     = (const float*)d_in[0];
  const float* x_dst     = (const float*)d_in[1];
  const float* edge_attr = (const float*)d_in[2];
  const float* node_mask = (const float*)d_in[3];
  const float* W1_src    = (const float*)d_in[4];
  const float* W1_dst    = (const float*)d_in[5];
  const float* att1      = (const float*)d_in[6];
  const float* b1        = (const float*)d_in[7];
  const float* W2_src    = (const float*)d_in[8];
  const float* W2_dst    = (const float*)d_in[9];
  const float* att2      = (const float*)d_in[10];
  const float* b2        = (const float*)d_in[11];
  const float* W_pool    = (const float*)d_in[12];
  const float* b_pool    = (const float*)d_in[13];
  const float* W_cls     = (const float*)d_in[14];
  const float* b_cls     = (const float*)d_in[15];
  const int*   edge_index= (const int*)d_in[16];
  float* out = (float*)d_out;

  const int T5 = TT - 1;
  const float* W1s5 = W1_src + (size_t)T5*DIN*FDIM;
  const float* W1d5 = W1_dst + (size_t)T5*DIN*FDIM;
  const float* a1_5 = att1   + (size_t)T5*FDIM;
  const float* b1_5 = b1     + (size_t)T5*FDIM;
  const float* W2s5 = W2_src + (size_t)T5*DIN*FDIM;
  const float* W2d5 = W2_dst + (size_t)T5*FDIM*FDIM;
  const float* a2_5 = att2   + (size_t)T5*FDIM;
  const float* b2_5 = b2     + (size_t)T5*FDIM;
  const float* xd5  = x_dst  + (size_t)T5*NN*DIN;
  const int* src5   = edge_index + (size_t)T5*2*EE;
  const int* dst5   = src5 + EE;

  // ---- workspace layout (bf16 overlays inside the three f32 buf slots) ----
  float* buf0 = (float*)d_ws;            // hs1b|hs2b (bf16) -> pooled partials (f32)
  float* buf1 = buf0 + (size_t)NN*FDIM;  // hd1b|h1b (bf16)  -> h2 (f32, full slot)
  float* buf2 = buf1 + (size_t)NN*FDIM;  // Xp_b|Xd_b|hd2b (bf16)
  float* sass = buf2 + (size_t)NN*FDIM;  // [NN*KC]
  float* xpool= sass + (size_t)NN*KC;    // [KC*256]
  float* aggE = xpool + KC*FDIM;         // [64]
  float* wbuf = aggE + 64;               // [EE*4]
  int* deg    = (int*)(wbuf + (size_t)EE*4);
  int* rp     = deg + NN;
  int* cursor = rp + NN + 1;
  int* eids   = cursor + NN;
  unsigned short* Wt1s = (unsigned short*)(eids + EE);   // [256*128]
  unsigned short* Wt1d = Wt1s + 256*DIN;
  unsigned short* Wt2s = Wt1d + 256*DIN;
  unsigned short* Wt2d = Wt2s + 256*DIN;                 // [256*256]
  int* bsum = (int*)(Wt2d + 256*FDIM);   // [NB]
  int* boff = bsum + NB;                 // [NB]
  // bf16 overlays:
  unsigned short* hs1b = (unsigned short*)buf0;                   // dead after L1 aggregate
  unsigned short* hs2b = hs1b + (size_t)NN*FDIM;                  // dead after L2 aggregate
  unsigned short* hd1b = (unsigned short*)buf1;                   // dead after L1 edge_logits
  unsigned short* h1b  = hd1b + (size_t)NN*FDIM;                  // dead after hd2 gemm
  unsigned short* Xp_b = (unsigned short*)buf2;                   // dead after hs2 gemm
  unsigned short* Xd_b = Xp_b + (size_t)NN*DIN;                   // dead after hd1 gemm
  unsigned short* hd2b = Xp_b + (size_t)2*NN*DIN;                 // dead after L2 edge_logits

  dim3 ggrid((NN + 127)/128, 2);

  // CSR over dst (shared by both GAT layers) — hierarchical scan
  zero_i32<<<(NN+255)/256, 256, 0, stream>>>(deg, NN);
  count_deg<<<(EE+255)/256, 256, 0, stream>>>(dst5, deg);
  scan_blk<<<NB, 256, 0, stream>>>(deg, rp, bsum);
  scan_sums<<<1, 256, 0, stream>>>(bsum, boff);
  scan_add<<<NB, 256, 0, stream>>>(rp, boff, cursor);
  scatter_edges<<<(EE+255)/256, 256, 0, stream>>>(dst5, cursor, eids);

  // edge_attr mean (independent path)
  zero_i32<<<1, 64, 0, stream>>>((int*)aggE, 64);
  edge_attr_mean<<<TT*BPT, 256, 0, stream>>>(edge_attr, aggE);

  // conversions: masked inputs + transposed weights -> bf16
  cvt_mask<<<(NN*DIN/8 + 255)/256, 256, 0, stream>>>(x_pkg, node_mask, Xp_b, NN*DIN, DIN);
  cvt_mask<<<(NN*DIN/8 + 255)/256, 256, 0, stream>>>(xd5,   node_mask, Xd_b, NN*DIN, DIN);
  cvt_wt<<<256, 256, 0, stream>>>(W1s5, Wt1s, DIN);
  cvt_wt<<<256, 256, 0, stream>>>(W1d5, Wt1d, DIN);
  cvt_wt<<<256, 256, 0, stream>>>(W2s5, Wt2s, DIN);
  cvt_wt<<<256, 256, 0, stream>>>(W2d5, Wt2d, FDIM);

  // layer 1
  gemm_bf16<<<ggrid, 256, 0, stream>>>((const short*)Xp_b, (const short*)Wt1s, hs1b, NN, DIN); // hs1
  gemm_bf16<<<ggrid, 256, 0, stream>>>((const short*)Xd_b, (const short*)Wt1d, hd1b, NN, DIN); // hd1
  edge_logits3<<<EE/4, 256, 0, stream>>>(src5, dst5, hs1b, hd1b, a1_5, wbuf);
  aggregate_w<<<NN/4, 256, 0, stream>>>(rp, eids, src5, wbuf, hs1b, b1_5, nullptr, h1b, 1); // h1 -> bf16

  // layer 2
  gemm_bf16<<<ggrid, 256, 0, stream>>>((const short*)Xp_b, (const short*)Wt2s, hs2b, NN, DIN);  // hs2
  gemm_bf16<<<ggrid, 256, 0, stream>>>((const short*)h1b,  (const short*)Wt2d, hd2b, NN, FDIM); // hd2
  edge_logits3<<<EE/4, 256, 0, stream>>>(src5, dst5, hs2b, hd2b, a2_5, wbuf);
  aggregate_w<<<NN/4, 256, 0, stream>>>(rp, eids, src5, wbuf, hs2b, b2_5, buf1, nullptr, 0); // h2 -> buf1 (f32)

  // pooling + classifier (h2 = buf1; buf0 free -> partials)
  pool_logits_sm<<<NPART, 256, 0, stream>>>(buf1, W_pool, b_pool, sass);
  zero_i32<<<(KC*FDIM+255)/256, 256, 0, stream>>>((int*)xpool, KC*FDIM);
  pooled_partial<<<NPART, 256, 0, stream>>>(sass, buf1, buf0);
  pooled_reduce<<<dim3(KC, PSPL), 256, 0, stream>>>(buf0, xpool);
  final_cls<<<1, 64, 0, stream>>>(xpool, aggE, W_cls, b_cls, out);
}

// Round 9
// 388.617 us; speedup vs baseline: 3.4964x; 1.2017x over previous
//
#include <hip/hip_runtime.h>
#include <math.h>

#define NN 50000      // nodes (both src and dst)
#define DIN 128
#define FDIM 256      // H*C
#define EE 200000
#define TT 6
#define DE 8
#define KC 48         // clusters
#define NB ((NN + 255)/256)   // 196 scan blocks

typedef __attribute__((ext_vector_type(8))) short bf16x8;
typedef __attribute__((ext_vector_type(8))) unsigned short u16x8;
typedef __attribute__((ext_vector_type(4))) float f32x4;

// f32 -> bf16 round-to-nearest-even
__device__ inline unsigned short f2b(float f){
  unsigned u = __float_as_uint(f);
  unsigned r = u + 0x7FFFu + ((u >> 16) & 1u);
  return (unsigned short)(r >> 16);
}
// bf16 -> f32
__device__ inline float b2f(unsigned short u){ return __uint_as_float(((unsigned)u) << 16); }

// ---------------- utility kernels ----------------
__global__ void zero_i32(int* __restrict__ p, int n){
  int i = blockIdx.x*256 + threadIdx.x;
  if (i < n) p[i] = 0;
}

__global__ void count_deg(const int* __restrict__ dst, int* __restrict__ deg){
  int i = blockIdx.x*256 + threadIdx.x;
  if (i < EE) atomicAdd(&deg[dst[i]], 1);
}

// ---------------- hierarchical exclusive scan ----------------
__global__ __launch_bounds__(256) void scan_blk(const int* __restrict__ deg, int* __restrict__ rp,
                                                int* __restrict__ bsum){
  __shared__ int sm[256];
  int i = blockIdx.x*256 + threadIdx.x;
  int v = (i < NN) ? deg[i] : 0;
  sm[threadIdx.x] = v;
  __syncthreads();
  #pragma unroll
  for (int off = 1; off < 256; off <<= 1){
    int t = (threadIdx.x >= (unsigned)off) ? sm[threadIdx.x - off] : 0;
    __syncthreads();
    sm[threadIdx.x] += t;
    __syncthreads();
  }
  if (i < NN) rp[i] = sm[threadIdx.x] - v;   // block-local exclusive
  if (threadIdx.x == 255) bsum[blockIdx.x] = sm[255];
}

__global__ __launch_bounds__(256) void scan_sums(const int* __restrict__ bsum, int* __restrict__ boff){
  __shared__ int sm[256];
  int v = (threadIdx.x < NB) ? bsum[threadIdx.x] : 0;
  sm[threadIdx.x] = v;
  __syncthreads();
  #pragma unroll
  for (int off = 1; off < 256; off <<= 1){
    int t = (threadIdx.x >= (unsigned)off) ? sm[threadIdx.x - off] : 0;
    __syncthreads();
    sm[threadIdx.x] += t;
    __syncthreads();
  }
  if (threadIdx.x < NB) boff[threadIdx.x] = sm[threadIdx.x] - v;
}

__global__ __launch_bounds__(256) void scan_add(int* __restrict__ rp, const int* __restrict__ boff,
                                                int* __restrict__ cursor){
  int i = blockIdx.x*256 + threadIdx.x;
  if (i < NN){
    int r = rp[i] + boff[blockIdx.x];
    rp[i] = r;
    cursor[i] = r;
  }
  if (i == 0) rp[NN] = EE;
}

__global__ void scatter_edges(const int* __restrict__ dst, int* __restrict__ cursor, int* __restrict__ eids){
  int i = blockIdx.x*256 + threadIdx.x;
  if (i < EE){ int pos = atomicAdd(&cursor[dst[i]], 1); eids[pos] = i; }
}

// ---------------- conversions ----------------
__global__ __launch_bounds__(256) void cvt_mask(const float* __restrict__ in, const float* __restrict__ mask,
                                                unsigned short* __restrict__ outb, int total, int K){
  int i = (blockIdx.x*256 + threadIdx.x)*8;
  if (i >= total) return;
  float m = mask[i / K];
  float4 a = *(const float4*)(in + i);
  float4 b = *(const float4*)(in + i + 4);
  u16x8 o;
  o[0]=f2b(a.x*m); o[1]=f2b(a.y*m); o[2]=f2b(a.z*m); o[3]=f2b(a.w*m);
  o[4]=f2b(b.x*m); o[5]=f2b(b.y*m); o[6]=f2b(b.z*m); o[7]=f2b(b.w*m);
  *(u16x8*)(outb + i) = o;
}

__global__ void cvt_wt(const float* __restrict__ W, unsigned short* __restrict__ Wt, int K){
  int n = blockIdx.x;
  for (int k = threadIdx.x; k < K; k += 256)
    Wt[(size_t)n*K + k] = f2b(W[(size_t)k*256 + n]);
}

// ---------------- MFMA GEMM: Cb[M,256](bf16) = A[M,K](bf16) @ Wt[256,K](bf16)^T ----------------
// tile 128x128, BK=32, 4 waves (2x2 of 64x64). Fragment layouts per learn_hip m89/m91.
__global__ __launch_bounds__(256) void gemm_bf16(const short* __restrict__ A, const short* __restrict__ Wt,
                                                 unsigned short* __restrict__ Cb, int M, int K){
  __shared__ short Al[128][56];   // stride 112B: 16B-aligned, ~2-way banks
  __shared__ short Bl[128][56];
  int tid = threadIdx.x;
  int lane = tid & 63;
  int w = tid >> 6;
  int wm = w >> 1, wn = w & 1;
  int row0 = blockIdx.x * 128, col0 = blockIdx.y * 128;
  int fr = lane & 15;   // fragment row (A) / col (B)
  int kb = lane >> 4;   // k-block 0..3 (8 bf16 each)
  f32x4 acc[4][4];
  #pragma unroll
  for (int i = 0; i < 4; i++)
    #pragma unroll
    for (int j = 0; j < 4; j++)
      acc[i][j] = (f32x4){0.f, 0.f, 0.f, 0.f};

  for (int k0 = 0; k0 < K; k0 += 32){
    bf16x8 ra[2], rb[2];
    #pragma unroll
    for (int p = 0; p < 2; p++){
      int idx = tid + p*256;          // 0..511
      int r = idx >> 2, ch = idx & 3;
      int gr = row0 + r;
      if (gr < M) ra[p] = *(const bf16x8*)(A + (size_t)gr*K + k0 + ch*8);
      else        ra[p] = (bf16x8){0,0,0,0,0,0,0,0};
      rb[p] = *(const bf16x8*)(Wt + (size_t)(col0 + r)*K + k0 + ch*8);
    }
    __syncthreads();
    #pragma unroll
    for (int p = 0; p < 2; p++){
      int idx = tid + p*256;
      int r = idx >> 2, ch = idx & 3;
      *(bf16x8*)(&Al[r][ch*8]) = ra[p];
      *(bf16x8*)(&Bl[r][ch*8]) = rb[p];
    }
    __syncthreads();
    bf16x8 af[4], bfr[4];
    #pragma unroll
    for (int i = 0; i < 4; i++) af[i]  = *(const bf16x8*)(&Al[wm*64 + i*16 + fr][kb*8]);
    #pragma unroll
    for (int j = 0; j < 4; j++) bfr[j] = *(const bf16x8*)(&Bl[wn*64 + j*16 + fr][kb*8]);
    #pragma unroll
    for (int i = 0; i < 4; i++)
      #pragma unroll
      for (int j = 0; j < 4; j++)
        acc[i][j] = __builtin_amdgcn_mfma_f32_16x16x32_bf16(af[i], bfr[j], acc[i][j], 0, 0, 0);
  }
  // C/D layout: col = lane&15, row = (lane>>4)*4 + q  (m89-verified)
  #pragma unroll
  for (int i = 0; i < 4; i++){
    #pragma unroll
    for (int q = 0; q < 4; q++){
      int grow = row0 + wm*64 + i*16 + kb*4 + q;
      if (grow < M){
        #pragma unroll
        for (int j = 0; j < 4; j++)
          Cb[(size_t)grow*256 + col0 + wn*64 + j*16 + fr] = f2b(acc[i][j][q]);
      }
    }
  }
}

// ---------------- FUSED GAT edge phase: logits + exp + weighted aggregation ----------------
// Wave per dst node. hd[n] row is wave-invariant -> registers. Per edge: one hs[src] gather,
// per-lane leaky·att partial, 16-lane shfl reduce -> p per head group, w=exp(p) (no segment max:
// ratio cancels after normalization; clamp guards overflow), FMA the SAME hs regs into acc.
__global__ __launch_bounds__(256) void gat_fused(const int* __restrict__ rp, const int* __restrict__ eids,
                                                 const int* __restrict__ src,
                                                 const unsigned short* __restrict__ hs,
                                                 const unsigned short* __restrict__ hd,
                                                 const float* __restrict__ att, const float* __restrict__ bias,
                                                 float* __restrict__ outp, unsigned short* __restrict__ outb,
                                                 int do_relu){
  int n = blockIdx.x*4 + (threadIdx.x >> 6);
  int lane = threadIdx.x & 63;
  if (n >= NN) return;
  const float4 av = *(const float4*)(att + lane*4);
  ushort4 ud = *(const ushort4*)(hd + (size_t)n*256 + lane*4);
  float d0 = b2f(ud.x), d1 = b2f(ud.y), d2 = b2f(ud.z), d3 = b2f(ud.w);
  int beg = rp[n], end = rp[n+1];
  float4 acc = {0.f,0.f,0.f,0.f};
  float sw = 0.f;
  for (int i = beg; i < end; i++){
    int s = src[eids[i]];
    ushort4 uh = *(const ushort4*)(hs + (size_t)s*256 + lane*4);
    float h0 = b2f(uh.x), h1 = b2f(uh.y), h2 = b2f(uh.z), h3 = b2f(uh.w);
    float m0 = h0 + d0, m1 = h1 + d1, m2 = h2 + d2, m3 = h3 + d3;
    m0 = (m0 > 0.f) ? m0 : 0.2f*m0;
    m1 = (m1 > 0.f) ? m1 : 0.2f*m1;
    m2 = (m2 > 0.f) ? m2 : 0.2f*m2;
    m3 = (m3 > 0.f) ? m3 : 0.2f*m3;
    float p = m0*av.x + m1*av.y + m2*av.z + m3*av.w;
    #pragma unroll
    for (int msk = 8; msk > 0; msk >>= 1) p += __shfl_xor(p, msk);  // reduce within 16-lane head group
    float w = expf(fminf(p, 80.f));
    acc.x = fmaf(w, h0, acc.x);
    acc.y = fmaf(w, h1, acc.y);
    acc.z = fmaf(w, h2, acc.z);
    acc.w = fmaf(w, h3, acc.w);
    sw += w;
  }
  float inv = 1.f / (sw + 1e-16f);
  const float4 b4 = *(const float4*)(bias + lane*4);
  float4 r;
  r.x = acc.x*inv + b4.x;
  r.y = acc.y*inv + b4.y;
  r.z = acc.z*inv + b4.z;
  r.w = acc.w*inv + b4.w;
  if (do_relu){
    r.x = fmaxf(r.x, 0.f); r.y = fmaxf(r.y, 0.f);
    r.z = fmaxf(r.z, 0.f); r.w = fmaxf(r.w, 0.f);
  }
  if (outb){
    ushort4 o;
    o.x = f2b(r.x); o.y = f2b(r.y); o.z = f2b(r.z); o.w = f2b(r.w);
    *(ushort4*)(outb + (size_t)n*256 + lane*4) = o;
  } else {
    *(float4*)(outp + (size_t)n*256 + lane*4) = r;
  }
}

// ---------------- pool logits GEMM + fused row softmax -> s_assign[N][48] (h2 in bf16) ----------------
__global__ __launch_bounds__(256) void pool_logits_sm(const unsigned short* __restrict__ h2b,
                                                      const float* __restrict__ Wp,
                                                      const float* __restrict__ bp, float* __restrict__ s_out){
  __shared__ float As[16][68];   // [kk][row]
  __shared__ float Ws[16][KC];   // [kk][col]
  int tid = threadIdx.x;
  int row0 = blockIdx.x * 64;
  int tx = tid & 15;
  int ty = tid >> 4;
  float acc[4][3] = {};
  for (int k0 = 0; k0 < 256; k0 += 16){
    #pragma unroll
    for (int p = 0; p < 4; p++){
      int idx = tid + p*256;
      int r  = idx >> 4;
      int kk = idx & 15;
      int gr = row0 + r;
      As[kk][r] = (gr < NN) ? b2f(h2b[(size_t)gr*256 + k0 + kk]) : 0.f;
    }
    {
      int idx = tid;
      if (idx < 768) Ws[idx/KC][idx%KC] = Wp[(size_t)(k0 + idx/KC)*KC + idx%KC];
      idx = tid + 256;
      Ws[idx/KC][idx%KC] = Wp[(size_t)(k0 + idx/KC)*KC + idx%KC];
      idx = tid + 512;
      Ws[idx/KC][idx%KC] = Wp[(size_t)(k0 + idx/KC)*KC + idx%KC];
    }
    __syncthreads();
    #pragma unroll
    for (int kk = 0; kk < 16; kk++){
      float a[4], b[3];
      #pragma unroll
      for (int i = 0; i < 4; i++) a[i] = As[kk][ty*4 + i];
      #pragma unroll
      for (int j = 0; j < 3; j++) b[j] = Ws[kk][tx*3 + j];
      #pragma unroll
      for (int i = 0; i < 4; i++)
        #pragma unroll
        for (int j = 0; j < 3; j++)
          acc[i][j] = fmaf(a[i], b[j], acc[i][j]);
    }
    __syncthreads();
  }
  float bb[3];
  #pragma unroll
  for (int j = 0; j < 3; j++) bb[j] = bp[tx*3 + j];
  #pragma unroll
  for (int i = 0; i < 4; i++){
    int gr = row0 + ty*4 + i;
    float m = -INFINITY;
    #pragma unroll
    for (int j = 0; j < 3; j++){ acc[i][j] += bb[j]; m = fmaxf(m, acc[i][j]); }
    #pragma unroll
    for (int mask = 8; mask > 0; mask >>= 1) m = fmaxf(m, __shfl_xor(m, mask));
    float e[3], s = 0.f;
    #pragma unroll
    for (int j = 0; j < 3; j++){ e[j] = expf(acc[i][j] - m); s += e[j]; }
    #pragma unroll
    for (int mask = 8; mask > 0; mask >>= 1) s += __shfl_xor(s, mask);
    float inv = 1.f / s;
    if (gr < NN){
      #pragma unroll
      for (int j = 0; j < 3; j++) s_out[(size_t)gr*KC + tx*3 + j] = e[j] * inv;
    }
  }
}

// ---------------- x_pooled = s.T @ h2 (bf16 h2), split-K two-stage ----------------
#define PCH 64
#define NPART ((NN + PCH - 1)/PCH)   // 782
__global__ __launch_bounds__(256) void pooled_partial(const float* __restrict__ s,
                                                      const unsigned short* __restrict__ h2b,
                                                      float* __restrict__ part){
  __shared__ float sld[PCH][KC];
  int t = threadIdx.x;
  int base = blockIdx.x * PCH;
  int cnt = min(PCH, NN - base);
  for (int idx = t; idx < cnt*KC; idx += 256)
    sld[idx/KC][idx%KC] = s[(size_t)(base + idx/KC)*KC + idx%KC];
  __syncthreads();
  float acc[KC];
  #pragma unroll
  for (int k = 0; k < KC; k++) acc[k] = 0.f;
  for (int n = 0; n < cnt; n++){
    float v = b2f(h2b[(size_t)(base + n)*256 + t]);
    #pragma unroll
    for (int k = 0; k < KC; k++) acc[k] = fmaf(sld[n][k], v, acc[k]);
  }
  float* po = part + (size_t)blockIdx.x*KC*256;
  #pragma unroll
  for (int k = 0; k < KC; k++) po[k*256 + t] = acc[k];
}
#define PSPL 8
__global__ __launch_bounds__(256) void pooled_reduce(const float* __restrict__ part, float* __restrict__ xp){
  int idx = blockIdx.x*256 + threadIdx.x;     // 0..12287
  const int per = (NPART + PSPL - 1)/PSPL;    // 98
  int p0 = blockIdx.y * per;
  int p1 = min(p0 + per, NPART);
  float s0 = 0.f, s1 = 0.f;
  int p = p0;
  for (; p + 1 < p1; p += 2){
    s0 += part[(size_t)p*KC*256 + idx];
    s1 += part[(size_t)(p+1)*KC*256 + idx];
  }
  if (p < p1) s0 += part[(size_t)p*KC*256 + idx];
  atomicAdd(&xp[idx], s0 + s1);
}

// ---------------- edge_attr mean over E -> [48], parallel grid-stride ----------------
#define BPT 128
__global__ __launch_bounds__(256) void edge_attr_mean(const float* __restrict__ ea, float* __restrict__ out){
  int t   = blockIdx.x / BPT;
  int blk = blockIdx.x % BPT;
  const int NF4 = EE * 2;
  const int per_blk = (NF4 + BPT - 1) / BPT;
  int i0 = blk * per_blk;
  int i1 = min(i0 + per_blk, NF4);
  const float4* base = (const float4*)(ea + (size_t)t*EE*DE);
  float s[8] = {0,0,0,0,0,0,0,0};
  for (int i = i0 + (int)threadIdx.x; i < i1; i += 256){
    float4 v = base[i];
    int db = (i & 1) * 4;
    s[db+0] += v.x; s[db+1] += v.y; s[db+2] += v.z; s[db+3] += v.w;
  }
  __shared__ float red[256];
  for (int d = 0; d < 8; d++){
    red[threadIdx.x] = s[d];
    __syncthreads();
    for (int off = 128; off > 0; off >>= 1){
      if (threadIdx.x < (unsigned)off) red[threadIdx.x] += red[threadIdx.x + off];
      __syncthreads();
    }
    if (threadIdx.x == 0) atomicAdd(&out[t*DE + d], red[0] / (float)EE);
    __syncthreads();
  }
}

// ---------------- final classifier ----------------
__global__ void final_cls(const float* __restrict__ xp, const float* __restrict__ agg,
                          const float* __restrict__ Wc, const float* __restrict__ bc,
                          float* __restrict__ out){
  int k = threadIdx.x;
  if (k < KC){
    float s = bc[0];
    for (int f = 0; f < 256; f++) s = fmaf(xp[k*256 + f], Wc[f], s);
    s = fmaf(agg[k], Wc[256], s);
    out[k] = 1.f/(1.f + expf(-s));
  }
}

extern "C" void kernel_launch(void* const* d_in, const int* in_sizes, int n_in,
                              void* d_out, int out_size, void* d_ws, size_t ws_size,
                              hipStream_t stream) {
  const float* x_pkg     = (const float*)d_in[0];
  const float* x_dst     = (const float*)d_in[1];
  const float* edge_attr = (const float*)d_in[2];
  const float* node_mask = (const float*)d_in[3];
  const float* W1_src    = (const float*)d_in[4];
  const float* W1_dst    = (const float*)d_in[5];
  const float* att1      = (const float*)d_in[6];
  const float* b1        = (const float*)d_in[7];
  const float* W2_src    = (const float*)d_in[8];
  const float* W2_dst    = (const float*)d_in[9];
  const float* att2      = (const float*)d_in[10];
  const float* b2        = (const float*)d_in[11];
  const float* W_pool    = (const float*)d_in[12];
  const float* b_pool    = (const float*)d_in[13];
  const float* W_cls     = (const float*)d_in[14];
  const float* b_cls     = (const float*)d_in[15];
  const int*   edge_index= (const int*)d_in[16];
  float* out = (float*)d_out;

  const int T5 = TT - 1;
  const float* W1s5 = W1_src + (size_t)T5*DIN*FDIM;
  const float* W1d5 = W1_dst + (size_t)T5*DIN*FDIM;
  const float* a1_5 = att1   + (size_t)T5*FDIM;
  const float* b1_5 = b1     + (size_t)T5*FDIM;
  const float* W2s5 = W2_src + (size_t)T5*DIN*FDIM;
  const float* W2d5 = W2_dst + (size_t)T5*FDIM*FDIM;
  const float* a2_5 = att2   + (size_t)T5*FDIM;
  const float* b2_5 = b2     + (size_t)T5*FDIM;
  const float* xd5  = x_dst  + (size_t)T5*NN*DIN;
  const int* src5   = edge_index + (size_t)T5*2*EE;
  const int* dst5   = src5 + EE;

  // ---- workspace layout (bf16 overlays inside the three f32-sized slots) ----
  float* buf0 = (float*)d_ws;            // hs1b|hs2b (bf16) -> pooled partials (f32)
  float* buf1 = buf0 + (size_t)NN*FDIM;  // hd1b|h1b (bf16)  -> h2b (bf16)
  float* buf2 = buf1 + (size_t)NN*FDIM;  // Xp_b|Xd_b|hd2b (bf16)
  float* sass = buf2 + (size_t)NN*FDIM;  // [NN*KC]
  float* xpool= sass + (size_t)NN*KC;    // [KC*256]
  float* aggE = xpool + KC*FDIM;         // [64]
  int* deg    = (int*)(aggE + 64);
  int* rp     = deg + NN;
  int* cursor = rp + NN + 1;
  int* eids   = cursor + NN;
  unsigned short* Wt1s = (unsigned short*)(eids + EE);   // [256*128]
  unsigned short* Wt1d = Wt1s + 256*DIN;
  unsigned short* Wt2s = Wt1d + 256*DIN;
  unsigned short* Wt2d = Wt2s + 256*DIN;                 // [256*256]
  int* bsum = (int*)(Wt2d + 256*FDIM);   // [NB]
  int* boff = bsum + NB;                 // [NB]
  // bf16 overlays:
  unsigned short* hs1b = (unsigned short*)buf0;                   // dead after L1 fused
  unsigned short* hs2b = hs1b + (size_t)NN*FDIM;                  // dead after L2 fused
  unsigned short* hd1b = (unsigned short*)buf1;                   // dead after L1 fused
  unsigned short* h1b  = hd1b + (size_t)NN*FDIM;                  // dead after hd2 gemm
  unsigned short* h2b  = (unsigned short*)buf1;                   // written by L2 fused (hd1b/h1b dead)
  unsigned short* Xp_b = (unsigned short*)buf2;                   // dead after hs2 gemm
  unsigned short* Xd_b = Xp_b + (size_t)NN*DIN;                   // dead after hd1 gemm
  unsigned short* hd2b = Xp_b + (size_t)2*NN*DIN;                 // dead after L2 fused

  dim3 ggrid((NN + 127)/128, 2);

  // CSR over dst (shared by both GAT layers) — hierarchical scan
  zero_i32<<<(NN+255)/256, 256, 0, stream>>>(deg, NN);
  count_deg<<<(EE+255)/256, 256, 0, stream>>>(dst5, deg);
  scan_blk<<<NB, 256, 0, stream>>>(deg, rp, bsum);
  scan_sums<<<1, 256, 0, stream>>>(bsum, boff);
  scan_add<<<NB, 256, 0, stream>>>(rp, boff, cursor);
  scatter_edges<<<(EE+255)/256, 256, 0, stream>>>(dst5, cursor, eids);

  // edge_attr mean (independent path)
  zero_i32<<<1, 64, 0, stream>>>((int*)aggE, 64);
  edge_attr_mean<<<TT*BPT, 256, 0, stream>>>(edge_attr, aggE);

  // conversions: masked inputs + transposed weights -> bf16
  cvt_mask<<<(NN*DIN/8 + 255)/256, 256, 0, stream>>>(x_pkg, node_mask, Xp_b, NN*DIN, DIN);
  cvt_mask<<<(NN*DIN/8 + 255)/256, 256, 0, stream>>>(xd5,   node_mask, Xd_b, NN*DIN, DIN);
  cvt_wt<<<256, 256, 0, stream>>>(W1s5, Wt1s, DIN);
  cvt_wt<<<256, 256, 0, stream>>>(W1d5, Wt1d, DIN);
  cvt_wt<<<256, 256, 0, stream>>>(W2s5, Wt2s, DIN);
  cvt_wt<<<256, 256, 0, stream>>>(W2d5, Wt2d, FDIM);

  // layer 1
  gemm_bf16<<<ggrid, 256, 0, stream>>>((const short*)Xp_b, (const short*)Wt1s, hs1b, NN, DIN); // hs1
  gemm_bf16<<<ggrid, 256, 0, stream>>>((const short*)Xd_b, (const short*)Wt1d, hd1b, NN, DIN); // hd1
  gat_fused<<<NN/4, 256, 0, stream>>>(rp, eids, src5, hs1b, hd1b, a1_5, b1_5, nullptr, h1b, 1); // h1 -> bf16

  // layer 2
  gemm_bf16<<<ggrid, 256, 0, stream>>>((const short*)Xp_b, (const short*)Wt2s, hs2b, NN, DIN);  // hs2
  gemm_bf16<<<ggrid, 256, 0, stream>>>((const short*)h1b,  (const short*)Wt2d, hd2b, NN, FDIM); // hd2
  gat_fused<<<NN/4, 256, 0, stream>>>(rp, eids, src5, hs2b, hd2b, a2_5, b2_5, nullptr, h2b, 0); // h2 -> bf16

  // pooling + classifier (h2 = h2b; buf0 free -> partials)
  pool_logits_sm<<<NPART, 256, 0, stream>>>(h2b, W_pool, b_pool, sass);
  zero_i32<<<(KC*FDIM+255)/256, 256, 0, stream>>>((int*)xpool, KC*FDIM);
  pooled_partial<<<NPART, 256, 0, stream>>>(sass, h2b, buf0);
  pooled_reduce<<<dim3(KC, PSPL), 256, 0, stream>>>(buf0, xpool);
  final_cls<<<1, 64, 0, stream>>>(xpool, aggE, W_cls, b_cls, out);
}

// Round 10
// 355.496 us; speedup vs baseline: 3.8221x; 1.0932x over previous
//
#include <hip/hip_runtime.h>
#include <math.h>

#define NN 50000      // nodes (both src and dst)
#define DIN 128
#define FDIM 256      // H*C
#define EE 200000
#define TT 6
#define DE 8
#define KC 48         // clusters
#define NB ((NN + 255)/256)   // 196 scan blocks

typedef __attribute__((ext_vector_type(8))) short bf16x8;
typedef __attribute__((ext_vector_type(8))) unsigned short u16x8;
typedef __attribute__((ext_vector_type(4))) float f32x4;

// f32 -> bf16 round-to-nearest-even
__device__ inline unsigned short f2b(float f){
  unsigned u = __float_as_uint(f);
  unsigned r = u + 0x7FFFu + ((u >> 16) & 1u);
  return (unsigned short)(r >> 16);
}
// bf16 -> f32
__device__ inline float b2f(unsigned short u){ return __uint_as_float(((unsigned)u) << 16); }

// ---------------- utility kernels ----------------
__global__ void zero_i32(int* __restrict__ p, int n){
  int i = blockIdx.x*256 + threadIdx.x;
  if (i < n) p[i] = 0;
}

__global__ void count_deg(const int* __restrict__ dst, int* __restrict__ deg){
  int i = blockIdx.x*256 + threadIdx.x;
  if (i < EE) atomicAdd(&deg[dst[i]], 1);
}

// ---------------- hierarchical exclusive scan ----------------
__global__ __launch_bounds__(256) void scan_blk(const int* __restrict__ deg, int* __restrict__ rp,
                                                int* __restrict__ bsum){
  __shared__ int sm[256];
  int i = blockIdx.x*256 + threadIdx.x;
  int v = (i < NN) ? deg[i] : 0;
  sm[threadIdx.x] = v;
  __syncthreads();
  #pragma unroll
  for (int off = 1; off < 256; off <<= 1){
    int t = (threadIdx.x >= (unsigned)off) ? sm[threadIdx.x - off] : 0;
    __syncthreads();
    sm[threadIdx.x] += t;
    __syncthreads();
  }
  if (i < NN) rp[i] = sm[threadIdx.x] - v;   // block-local exclusive
  if (threadIdx.x == 255) bsum[blockIdx.x] = sm[255];
}

__global__ __launch_bounds__(256) void scan_sums(const int* __restrict__ bsum, int* __restrict__ boff){
  __shared__ int sm[256];
  int v = (threadIdx.x < NB) ? bsum[threadIdx.x] : 0;
  sm[threadIdx.x] = v;
  __syncthreads();
  #pragma unroll
  for (int off = 1; off < 256; off <<= 1){
    int t = (threadIdx.x >= (unsigned)off) ? sm[threadIdx.x - off] : 0;
    __syncthreads();
    sm[threadIdx.x] += t;
    __syncthreads();
  }
  if (threadIdx.x < NB) boff[threadIdx.x] = sm[threadIdx.x] - v;
}

__global__ __launch_bounds__(256) void scan_add(int* __restrict__ rp, const int* __restrict__ boff,
                                                int* __restrict__ cursor){
  int i = blockIdx.x*256 + threadIdx.x;
  if (i < NN){
    int r = rp[i] + boff[blockIdx.x];
    rp[i] = r;
    cursor[i] = r;
  }
  if (i == 0) rp[NN] = EE;
}

// scatter SRC VALUES (not edge ids): removes one indirection in the fused edge loop
__global__ void scatter_edges(const int* __restrict__ src, const int* __restrict__ dst,
                              int* __restrict__ cursor, int* __restrict__ srt){
  int i = blockIdx.x*256 + threadIdx.x;
  if (i < EE){ int pos = atomicAdd(&cursor[dst[i]], 1); srt[pos] = src[i]; }
}

// ---------------- weight transpose conversion ----------------
__global__ void cvt_wt(const float* __restrict__ W, unsigned short* __restrict__ Wt, int K){
  int n = blockIdx.x;
  for (int k = threadIdx.x; k < K; k += 256)
    Wt[(size_t)n*K + k] = f2b(W[(size_t)k*256 + n]);
}

// ---------------- MFMA GEMM, f32 A with fused mask+convert ----------------
// C[M, 128*gridDim.y] = (A .* mask) @ Wt^T ; output col0>=256 goes to C2 (dual-N mode).
// tile 128x128, BK=32, 4 waves. Fragment layouts per learn_hip m89/m91.
__global__ __launch_bounds__(256) void gemm_f32A(const float* __restrict__ A,
                                                 const unsigned short* __restrict__ Wt,
                                                 const float* __restrict__ mask,
                                                 unsigned short* __restrict__ C1,
                                                 unsigned short* __restrict__ C2,
                                                 int M, int K){
  __shared__ short Al[128][56];
  __shared__ short Bl[128][56];
  int tid = threadIdx.x;
  int lane = tid & 63;
  int w = tid >> 6;
  int wm = w >> 1, wn = w & 1;
  int row0 = blockIdx.x * 128, col0 = blockIdx.y * 128;
  int fr = lane & 15;
  int kb = lane >> 4;
  f32x4 acc[4][4];
  #pragma unroll
  for (int i = 0; i < 4; i++)
    #pragma unroll
    for (int j = 0; j < 4; j++)
      acc[i][j] = (f32x4){0.f, 0.f, 0.f, 0.f};

  for (int k0 = 0; k0 < K; k0 += 32){
    u16x8 ra[2]; bf16x8 rb[2];
    #pragma unroll
    for (int p = 0; p < 2; p++){
      int idx = tid + p*256;          // 0..511
      int r = idx >> 2, ch = idx & 3;
      int gr = row0 + r;
      u16x8 o = (u16x8){0,0,0,0,0,0,0,0};
      if (gr < M){
        float mv = mask ? mask[gr] : 1.f;
        const float* ap = A + (size_t)gr*K + k0 + ch*8;
        float4 a0 = *(const float4*)(ap);
        float4 a1 = *(const float4*)(ap + 4);
        o[0]=f2b(a0.x*mv); o[1]=f2b(a0.y*mv); o[2]=f2b(a0.z*mv); o[3]=f2b(a0.w*mv);
        o[4]=f2b(a1.x*mv); o[5]=f2b(a1.y*mv); o[6]=f2b(a1.z*mv); o[7]=f2b(a1.w*mv);
      }
      ra[p] = o;
      rb[p] = *(const bf16x8*)(Wt + (size_t)(col0 + r)*K + k0 + ch*8);
    }
    __syncthreads();
    #pragma unroll
    for (int p = 0; p < 2; p++){
      int idx = tid + p*256;
      int r = idx >> 2, ch = idx & 3;
      *(u16x8*)(&Al[r][ch*8]) = ra[p];
      *(bf16x8*)(&Bl[r][ch*8]) = rb[p];
    }
    __syncthreads();
    bf16x8 af[4], bfr[4];
    #pragma unroll
    for (int i = 0; i < 4; i++) af[i]  = *(const bf16x8*)(&Al[wm*64 + i*16 + fr][kb*8]);
    #pragma unroll
    for (int j = 0; j < 4; j++) bfr[j] = *(const bf16x8*)(&Bl[wn*64 + j*16 + fr][kb*8]);
    #pragma unroll
    for (int i = 0; i < 4; i++)
      #pragma unroll
      for (int j = 0; j < 4; j++)
        acc[i][j] = __builtin_amdgcn_mfma_f32_16x16x32_bf16(af[i], bfr[j], acc[i][j], 0, 0, 0);
  }
  unsigned short* Co = (col0 >= 256) ? C2 : C1;
  int cb = col0 & 255;
  #pragma unroll
  for (int i = 0; i < 4; i++){
    #pragma unroll
    for (int q = 0; q < 4; q++){
      int grow = row0 + wm*64 + i*16 + kb*4 + q;
      if (grow < M){
        #pragma unroll
        for (int j = 0; j < 4; j++)
          Co[(size_t)grow*256 + cb + wn*64 + j*16 + fr] = f2b(acc[i][j][q]);
      }
    }
  }
}

// ---------------- MFMA GEMM, bf16 A (h1 @ W2_dst) ----------------
__global__ __launch_bounds__(256) void gemm_bf16(const short* __restrict__ A, const short* __restrict__ Wt,
                                                 unsigned short* __restrict__ Cb, int M, int K){
  __shared__ short Al[128][56];
  __shared__ short Bl[128][56];
  int tid = threadIdx.x;
  int lane = tid & 63;
  int w = tid >> 6;
  int wm = w >> 1, wn = w & 1;
  int row0 = blockIdx.x * 128, col0 = blockIdx.y * 128;
  int fr = lane & 15;
  int kb = lane >> 4;
  f32x4 acc[4][4];
  #pragma unroll
  for (int i = 0; i < 4; i++)
    #pragma unroll
    for (int j = 0; j < 4; j++)
      acc[i][j] = (f32x4){0.f, 0.f, 0.f, 0.f};

  for (int k0 = 0; k0 < K; k0 += 32){
    bf16x8 ra[2], rb[2];
    #pragma unroll
    for (int p = 0; p < 2; p++){
      int idx = tid + p*256;
      int r = idx >> 2, ch = idx & 3;
      int gr = row0 + r;
      if (gr < M) ra[p] = *(const bf16x8*)(A + (size_t)gr*K + k0 + ch*8);
      else        ra[p] = (bf16x8){0,0,0,0,0,0,0,0};
      rb[p] = *(const bf16x8*)(Wt + (size_t)(col0 + r)*K + k0 + ch*8);
    }
    __syncthreads();
    #pragma unroll
    for (int p = 0; p < 2; p++){
      int idx = tid + p*256;
      int r = idx >> 2, ch = idx & 3;
      *(bf16x8*)(&Al[r][ch*8]) = ra[p];
      *(bf16x8*)(&Bl[r][ch*8]) = rb[p];
    }
    __syncthreads();
    bf16x8 af[4], bfr[4];
    #pragma unroll
    for (int i = 0; i < 4; i++) af[i]  = *(const bf16x8*)(&Al[wm*64 + i*16 + fr][kb*8]);
    #pragma unroll
    for (int j = 0; j < 4; j++) bfr[j] = *(const bf16x8*)(&Bl[wn*64 + j*16 + fr][kb*8]);
    #pragma unroll
    for (int i = 0; i < 4; i++)
      #pragma unroll
      for (int j = 0; j < 4; j++)
        acc[i][j] = __builtin_amdgcn_mfma_f32_16x16x32_bf16(af[i], bfr[j], acc[i][j], 0, 0, 0);
  }
  #pragma unroll
  for (int i = 0; i < 4; i++){
    #pragma unroll
    for (int q = 0; q < 4; q++){
      int grow = row0 + wm*64 + i*16 + kb*4 + q;
      if (grow < M){
        #pragma unroll
        for (int j = 0; j < 4; j++)
          Cb[(size_t)grow*256 + col0 + wn*64 + j*16 + fr] = f2b(acc[i][j][q]);
      }
    }
  }
}

// ---------------- FUSED GAT edge phase: logits + exp + weighted aggregation ----------------
// Wave per dst node; srt[] holds pre-gathered src node ids (CSR order).
__global__ __launch_bounds__(256) void gat_fused(const int* __restrict__ rp, const int* __restrict__ srt,
                                                 const unsigned short* __restrict__ hs,
                                                 const unsigned short* __restrict__ hd,
                                                 const float* __restrict__ att, const float* __restrict__ bias,
                                                 unsigned short* __restrict__ outb, int do_relu){
  int n = blockIdx.x*4 + (threadIdx.x >> 6);
  int lane = threadIdx.x & 63;
  if (n >= NN) return;
  const float4 av = *(const float4*)(att + lane*4);
  ushort4 ud = *(const ushort4*)(hd + (size_t)n*256 + lane*4);
  float d0 = b2f(ud.x), d1 = b2f(ud.y), d2 = b2f(ud.z), d3 = b2f(ud.w);
  int beg = rp[n], end = rp[n+1];
  float4 acc = {0.f,0.f,0.f,0.f};
  float sw = 0.f;
  for (int i = beg; i < end; i++){
    int s = srt[i];
    ushort4 uh = *(const ushort4*)(hs + (size_t)s*256 + lane*4);
    float h0 = b2f(uh.x), h1 = b2f(uh.y), h2 = b2f(uh.z), h3 = b2f(uh.w);
    float m0 = h0 + d0, m1 = h1 + d1, m2 = h2 + d2, m3 = h3 + d3;
    m0 = (m0 > 0.f) ? m0 : 0.2f*m0;
    m1 = (m1 > 0.f) ? m1 : 0.2f*m1;
    m2 = (m2 > 0.f) ? m2 : 0.2f*m2;
    m3 = (m3 > 0.f) ? m3 : 0.2f*m3;
    float p = m0*av.x + m1*av.y + m2*av.z + m3*av.w;
    #pragma unroll
    for (int msk = 8; msk > 0; msk >>= 1) p += __shfl_xor(p, msk);  // 16-lane head-group reduce
    float w = expf(fminf(p, 80.f));     // no segment max: ratio cancels after normalization
    acc.x = fmaf(w, h0, acc.x);
    acc.y = fmaf(w, h1, acc.y);
    acc.z = fmaf(w, h2, acc.z);
    acc.w = fmaf(w, h3, acc.w);
    sw += w;
  }
  float inv = 1.f / (sw + 1e-16f);
  const float4 b4 = *(const float4*)(bias + lane*4);
  float4 r;
  r.x = acc.x*inv + b4.x;
  r.y = acc.y*inv + b4.y;
  r.z = acc.z*inv + b4.z;
  r.w = acc.w*inv + b4.w;
  if (do_relu){
    r.x = fmaxf(r.x, 0.f); r.y = fmaxf(r.y, 0.f);
    r.z = fmaxf(r.z, 0.f); r.w = fmaxf(r.w, 0.f);
  }
  ushort4 o;
  o.x = f2b(r.x); o.y = f2b(r.y); o.z = f2b(r.z); o.w = f2b(r.w);
  *(ushort4*)(outb + (size_t)n*256 + lane*4) = o;
}

// ---------------- FUSED pool: logits GEMM + row softmax (LDS) + partial s^T@h2 ----------------
// One block per 64 rows. Phase A: 64x48 logits (LDS-tiled GEMM). Phase B: softmax -> sld LDS.
// Phase C: partial[k][t] = sum_n sld[n][k]*h2[n][t] (h2 re-read, L2-hot). No global sass.
#define PCH 64
#define NPART ((NN + PCH - 1)/PCH)   // 782
__global__ __launch_bounds__(256) void pool_fused(const unsigned short* __restrict__ h2b,
                                                  const float* __restrict__ Wp,
                                                  const float* __restrict__ bp,
                                                  float* __restrict__ part){
  __shared__ float As[16][68];   // [kk][row]
  __shared__ float Ws[16][KC];   // [kk][col]
  __shared__ float sld[PCH][KC];
  int tid = threadIdx.x;
  int row0 = blockIdx.x * 64;
  int tx = tid & 15;
  int ty = tid >> 4;
  float acc[4][3] = {};
  for (int k0 = 0; k0 < 256; k0 += 16){
    #pragma unroll
    for (int p = 0; p < 4; p++){
      int idx = tid + p*256;
      int r  = idx >> 4;
      int kk = idx & 15;
      int gr = row0 + r;
      As[kk][r] = (gr < NN) ? b2f(h2b[(size_t)gr*256 + k0 + kk]) : 0.f;
    }
    {
      int idx = tid;
      if (idx < 768) Ws[idx/KC][idx%KC] = Wp[(size_t)(k0 + idx/KC)*KC + idx%KC];
      idx = tid + 256;
      Ws[idx/KC][idx%KC] = Wp[(size_t)(k0 + idx/KC)*KC + idx%KC];
      idx = tid + 512;
      Ws[idx/KC][idx%KC] = Wp[(size_t)(k0 + idx/KC)*KC + idx%KC];
    }
    __syncthreads();
    #pragma unroll
    for (int kk = 0; kk < 16; kk++){
      float a[4], b[3];
      #pragma unroll
      for (int i = 0; i < 4; i++) a[i] = As[kk][ty*4 + i];
      #pragma unroll
      for (int j = 0; j < 3; j++) b[j] = Ws[kk][tx*3 + j];
      #pragma unroll
      for (int i = 0; i < 4; i++)
        #pragma unroll
        for (int j = 0; j < 3; j++)
          acc[i][j] = fmaf(a[i], b[j], acc[i][j]);
    }
    __syncthreads();
  }
  // bias + row softmax -> sld (rows >= NN produce benign values; excluded in phase C)
  float bb[3];
  #pragma unroll
  for (int j = 0; j < 3; j++) bb[j] = bp[tx*3 + j];
  #pragma unroll
  for (int i = 0; i < 4; i++){
    float m = -INFINITY;
    #pragma unroll
    for (int j = 0; j < 3; j++){ acc[i][j] += bb[j]; m = fmaxf(m, acc[i][j]); }
    #pragma unroll
    for (int mask = 8; mask > 0; mask >>= 1) m = fmaxf(m, __shfl_xor(m, mask));
    float e[3], s = 0.f;
    #pragma unroll
    for (int j = 0; j < 3; j++){ e[j] = expf(acc[i][j] - m); s += e[j]; }
    #pragma unroll
    for (int mask = 8; mask > 0; mask >>= 1) s += __shfl_xor(s, mask);
    float inv = 1.f / s;
    #pragma unroll
    for (int j = 0; j < 3; j++) sld[ty*4 + i][tx*3 + j] = e[j] * inv;
  }
  __syncthreads();
  // phase C: per-column partial over this block's rows
  int cnt = min(PCH, NN - row0);
  float pacc[KC];
  #pragma unroll
  for (int k = 0; k < KC; k++) pacc[k] = 0.f;
  for (int n = 0; n < cnt; n++){
    float v = b2f(h2b[(size_t)(row0 + n)*256 + tid]);
    #pragma unroll
    for (int k = 0; k < KC; k++) pacc[k] = fmaf(sld[n][k], v, pacc[k]);
  }
  float* po = part + (size_t)blockIdx.x*KC*256;
  #pragma unroll
  for (int k = 0; k < KC; k++) po[k*256 + tid] = pacc[k];
}

#define PSPL 8
__global__ __launch_bounds__(256) void pooled_reduce(const float* __restrict__ part, float* __restrict__ xp){
  int idx = blockIdx.x*256 + threadIdx.x;     // 0..12287
  const int per = (NPART + PSPL - 1)/PSPL;    // 98
  int p0 = blockIdx.y * per;
  int p1 = min(p0 + per, NPART);
  float s0 = 0.f, s1 = 0.f;
  int p = p0;
  for (; p + 1 < p1; p += 2){
    s0 += part[(size_t)p*KC*256 + idx];
    s1 += part[(size_t)(p+1)*KC*256 + idx];
  }
  if (p < p1) s0 += part[(size_t)p*KC*256 + idx];
  atomicAdd(&xp[idx], s0 + s1);
}

// ---------------- edge_attr mean over E -> [48], parallel grid-stride ----------------
#define BPT 128
__global__ __launch_bounds__(256) void edge_attr_mean(const float* __restrict__ ea, float* __restrict__ out){
  int t   = blockIdx.x / BPT;
  int blk = blockIdx.x % BPT;
  const int NF4 = EE * 2;
  const int per_blk = (NF4 + BPT - 1) / BPT;
  int i0 = blk * per_blk;
  int i1 = min(i0 + per_blk, NF4);
  const float4* base = (const float4*)(ea + (size_t)t*EE*DE);
  float s[8] = {0,0,0,0,0,0,0,0};
  for (int i = i0 + (int)threadIdx.x; i < i1; i += 256){
    float4 v = base[i];
    int db = (i & 1) * 4;
    s[db+0] += v.x; s[db+1] += v.y; s[db+2] += v.z; s[db+3] += v.w;
  }
  __shared__ float red[256];
  for (int d = 0; d < 8; d++){
    red[threadIdx.x] = s[d];
    __syncthreads();
    for (int off = 128; off > 0; off >>= 1){
      if (threadIdx.x < (unsigned)off) red[threadIdx.x] += red[threadIdx.x + off];
      __syncthreads();
    }
    if (threadIdx.x == 0) atomicAdd(&out[t*DE + d], red[0] / (float)EE);
    __syncthreads();
  }
}

// ---------------- final classifier ----------------
__global__ void final_cls(const float* __restrict__ xp, const float* __restrict__ agg,
                          const float* __restrict__ Wc, const float* __restrict__ bc,
                          float* __restrict__ out){
  int k = threadIdx.x;
  if (k < KC){
    float s = bc[0];
    for (int f = 0; f < 256; f++) s = fmaf(xp[k*256 + f], Wc[f], s);
    s = fmaf(agg[k], Wc[256], s);
    out[k] = 1.f/(1.f + expf(-s));
  }
}

extern "C" void kernel_launch(void* const* d_in, const int* in_sizes, int n_in,
                              void* d_out, int out_size, void* d_ws, size_t ws_size,
                              hipStream_t stream) {
  const float* x_pkg     = (const float*)d_in[0];
  const float* x_dst     = (const float*)d_in[1];
  const float* edge_attr = (const float*)d_in[2];
  const float* node_mask = (const float*)d_in[3];
  const float* W1_src    = (const float*)d_in[4];
  const float* W1_dst    = (const float*)d_in[5];
  const float* att1      = (const float*)d_in[6];
  const float* b1        = (const float*)d_in[7];
  const float* W2_src    = (const float*)d_in[8];
  const float* W2_dst    = (const float*)d_in[9];
  const float* att2      = (const float*)d_in[10];
  const float* b2        = (const float*)d_in[11];
  const float* W_pool    = (const float*)d_in[12];
  const float* b_pool    = (const float*)d_in[13];
  const float* W_cls     = (const float*)d_in[14];
  const float* b_cls     = (const float*)d_in[15];
  const int*   edge_index= (const int*)d_in[16];
  float* out = (float*)d_out;

  const int T5 = TT - 1;
  const float* W1s5 = W1_src + (size_t)T5*DIN*FDIM;
  const float* W1d5 = W1_dst + (size_t)T5*DIN*FDIM;
  const float* a1_5 = att1   + (size_t)T5*FDIM;
  const float* b1_5 = b1     + (size_t)T5*FDIM;
  const float* W2s5 = W2_src + (size_t)T5*DIN*FDIM;
  const float* W2d5 = W2_dst + (size_t)T5*FDIM*FDIM;
  const float* a2_5 = att2   + (size_t)T5*FDIM;
  const float* b2_5 = b2     + (size_t)T5*FDIM;
  const float* xd5  = x_dst  + (size_t)T5*NN*DIN;
  const int* src5   = edge_index + (size_t)T5*2*EE;
  const int* dst5   = src5 + EE;

  // ---- workspace layout (bf16 overlays inside three f32-sized slots) ----
  float* buf0 = (float*)d_ws;            // hs1b|hs2b (bf16) -> pooled partials (f32)
  float* buf1 = buf0 + (size_t)NN*FDIM;  // hd1b|h1b (bf16)  -> h2b (bf16)
  float* buf2 = buf1 + (size_t)NN*FDIM;  // hd2b (bf16)
  float* xpool= buf2 + (size_t)NN*FDIM;  // [KC*256]
  float* aggE = xpool + KC*FDIM;         // [64]
  int* deg    = (int*)(aggE + 64);
  int* rp     = deg + NN;
  int* cursor = rp + NN + 1;
  int* srt    = cursor + NN;             // [EE] pre-gathered src ids
  unsigned short* Wt12s = (unsigned short*)(srt + EE);   // stacked [512][128]: W1s then W2s
  unsigned short* Wt1s = Wt12s;
  unsigned short* Wt2s = Wt12s + (size_t)256*DIN;
  unsigned short* Wt1d = Wt2s  + (size_t)256*DIN;
  unsigned short* Wt2d = Wt1d  + (size_t)256*DIN;        // [256][256]
  int* bsum = (int*)(Wt2d + (size_t)256*FDIM);   // [NB]
  int* boff = bsum + NB;                 // [NB]
  // bf16 overlays:
  unsigned short* hs1b = (unsigned short*)buf0;                   // dead after L1 fused
  unsigned short* hs2b = hs1b + (size_t)NN*FDIM;                  // dead after L2 fused
  unsigned short* hd1b = (unsigned short*)buf1;                   // dead after L1 fused
  unsigned short* h1b  = hd1b + (size_t)NN*FDIM;                  // dead after hd2 gemm
  unsigned short* h2b  = (unsigned short*)buf1;                   // L2 fused output (hd1b region dead)
  unsigned short* hd2b = (unsigned short*)buf2;                   // dead after L2 fused

  // CSR over dst (shared by both GAT layers) — hierarchical scan
  zero_i32<<<(NN+255)/256, 256, 0, stream>>>(deg, NN);
  count_deg<<<(EE+255)/256, 256, 0, stream>>>(dst5, deg);
  scan_blk<<<NB, 256, 0, stream>>>(deg, rp, bsum);
  scan_sums<<<1, 256, 0, stream>>>(bsum, boff);
  scan_add<<<NB, 256, 0, stream>>>(rp, boff, cursor);
  scatter_edges<<<(EE+255)/256, 256, 0, stream>>>(src5, dst5, cursor, srt);

  // edge_attr mean (independent path)
  zero_i32<<<1, 64, 0, stream>>>((int*)aggE, 64);
  edge_attr_mean<<<TT*BPT, 256, 0, stream>>>(edge_attr, aggE);

  // transposed bf16 weights
  cvt_wt<<<256, 256, 0, stream>>>(W1s5, Wt1s, DIN);
  cvt_wt<<<256, 256, 0, stream>>>(W2s5, Wt2s, DIN);
  cvt_wt<<<256, 256, 0, stream>>>(W1d5, Wt1d, DIN);
  cvt_wt<<<256, 256, 0, stream>>>(W2d5, Wt2d, FDIM);

  dim3 g2((NN + 127)/128, 2), g4((NN + 127)/128, 4);

  // layer 1 (+ hs2 piggybacked: same A operand x_pkg)
  gemm_f32A<<<g4, 256, 0, stream>>>(x_pkg, Wt12s, node_mask, hs1b, hs2b, NN, DIN); // hs1 | hs2
  gemm_f32A<<<g2, 256, 0, stream>>>(xd5,   Wt1d,  node_mask, hd1b, nullptr, NN, DIN); // hd1
  gat_fused<<<NN/4, 256, 0, stream>>>(rp, srt, hs1b, hd1b, a1_5, b1_5, h1b, 1);   // h1 -> bf16

  // layer 2
  gemm_bf16<<<g2, 256, 0, stream>>>((const short*)h1b, (const short*)Wt2d, hd2b, NN, FDIM); // hd2
  gat_fused<<<NN/4, 256, 0, stream>>>(rp, srt, hs2b, hd2b, a2_5, b2_5, h2b, 0);   // h2 -> bf16

  // pooling + classifier (buf0 free -> partials)
  pool_fused<<<NPART, 256, 0, stream>>>(h2b, W_pool, b_pool, buf0);
  zero_i32<<<(KC*FDIM+255)/256, 256, 0, stream>>>((int*)xpool, KC*FDIM);
  pooled_reduce<<<dim3(KC, PSPL), 256, 0, stream>>>(buf0, xpool);
  final_cls<<<1, 64, 0, stream>>>(xpool, aggE, W_cls, b_cls, out);
}

// Round 11
// 338.754 us; speedup vs baseline: 4.0110x; 1.0494x over previous
//
#include <hip/hip_runtime.h>
#include <math.h>

#define NN 50000      // nodes (both src and dst)
#define DIN 128
#define FDIM 256      // H*C
#define EE 200000
#define TT 6
#define DE 8
#define KC 48         // clusters
#define NB ((NN + 255)/256)   // 196 scan blocks

typedef __attribute__((ext_vector_type(8))) short bf16x8;
typedef __attribute__((ext_vector_type(8))) unsigned short u16x8;
typedef __attribute__((ext_vector_type(4))) float f32x4;

// f32 -> bf16 round-to-nearest-even
__device__ inline unsigned short f2b(float f){
  unsigned u = __float_as_uint(f);
  unsigned r = u + 0x7FFFu + ((u >> 16) & 1u);
  return (unsigned short)(r >> 16);
}
// bf16 -> f32
__device__ inline float b2f(unsigned short u){ return __uint_as_float(((unsigned)u) << 16); }

// ---------------- utility kernels ----------------
__global__ void zero_i32(int* __restrict__ p, int n){
  int i = blockIdx.x*256 + threadIdx.x;
  if (i < n) p[i] = 0;
}

// zero deg[NN] and aggE[64] in one pass (aggE consumed later by edge_attr_mean atomics)
__global__ void zero_deg_agg(int* __restrict__ deg, int* __restrict__ aggE){
  int i = blockIdx.x*256 + threadIdx.x;
  if (i < NN) deg[i] = 0;
  if (i < 64) aggE[i] = 0;
}

__global__ void count_deg(const int* __restrict__ dst, int* __restrict__ deg){
  int i = blockIdx.x*256 + threadIdx.x;
  if (i < EE) atomicAdd(&deg[dst[i]], 1);
}

// ---------------- hierarchical exclusive scan ----------------
__global__ __launch_bounds__(256) void scan_blk(const int* __restrict__ deg, int* __restrict__ rp,
                                                int* __restrict__ bsum){
  __shared__ int sm[256];
  int i = blockIdx.x*256 + threadIdx.x;
  int v = (i < NN) ? deg[i] : 0;
  sm[threadIdx.x] = v;
  __syncthreads();
  #pragma unroll
  for (int off = 1; off < 256; off <<= 1){
    int t = (threadIdx.x >= (unsigned)off) ? sm[threadIdx.x - off] : 0;
    __syncthreads();
    sm[threadIdx.x] += t;
    __syncthreads();
  }
  if (i < NN) rp[i] = sm[threadIdx.x] - v;   // block-local exclusive
  if (threadIdx.x == 255) bsum[blockIdx.x] = sm[255];
}

__global__ __launch_bounds__(256) void scan_sums(const int* __restrict__ bsum, int* __restrict__ boff){
  __shared__ int sm[256];
  int v = (threadIdx.x < NB) ? bsum[threadIdx.x] : 0;
  sm[threadIdx.x] = v;
  __syncthreads();
  #pragma unroll
  for (int off = 1; off < 256; off <<= 1){
    int t = (threadIdx.x >= (unsigned)off) ? sm[threadIdx.x - off] : 0;
    __syncthreads();
    sm[threadIdx.x] += t;
    __syncthreads();
  }
  if (threadIdx.x < NB) boff[threadIdx.x] = sm[threadIdx.x] - v;
}

__global__ __launch_bounds__(256) void scan_add(int* __restrict__ rp, const int* __restrict__ boff,
                                                int* __restrict__ cursor){
  int i = blockIdx.x*256 + threadIdx.x;
  if (i < NN){
    int r = rp[i] + boff[blockIdx.x];
    rp[i] = r;
    cursor[i] = r;
  }
  if (i == 0) rp[NN] = EE;
}

// scatter SRC VALUES (not edge ids): removes one indirection in the fused edge loop
__global__ void scatter_edges(const int* __restrict__ src, const int* __restrict__ dst,
                              int* __restrict__ cursor, int* __restrict__ srt){
  int i = blockIdx.x*256 + threadIdx.x;
  if (i < EE){ int pos = atomicAdd(&cursor[dst[i]], 1); srt[pos] = src[i]; }
}

// ---------------- weight transpose conversion, all four in one launch ----------------
// grid (256, 4): y=0 W1s, y=1 W2s, y=2 W1d (K=128, into stacked Wtall), y=3 W2d (K=256)
__global__ void cvt_wt_all(const float* __restrict__ W1s, const float* __restrict__ W2s,
                           const float* __restrict__ W1d, const float* __restrict__ W2d,
                           unsigned short* __restrict__ Wtall, unsigned short* __restrict__ Wt2d){
  int n = blockIdx.x;
  int which = blockIdx.y;
  if (which == 3){
    for (int k = threadIdx.x; k < FDIM; k += 256)
      Wt2d[(size_t)n*FDIM + k] = f2b(W2d[(size_t)k*256 + n]);
  } else {
    const float* W = (which == 0) ? W1s : (which == 1) ? W2s : W1d;
    unsigned short* o = Wtall + (size_t)which*256*DIN + (size_t)n*DIN;
    for (int k = threadIdx.x; k < DIN; k += 256)
      o[k] = f2b(W[(size_t)k*256 + n]);
  }
}

// ---------------- layer-1 triple GEMM (hs1 | hs2 | hd1), fused mask+convert ----------------
// grid (392, 6): y in {0,1}->hs1 (A=x_pkg, Wt1s), {2,3}->hs2 (A=x_pkg, Wt2s), {4,5}->hd1 (A=xd5, Wt1d).
// col0 = (y&1)*128. tile 128x128, BK=32, 4 waves. Fragment layouts per learn_hip m89/m91.
__global__ __launch_bounds__(256) void gemm_l1(const float* __restrict__ Apkg, const float* __restrict__ Adst,
                                               const unsigned short* __restrict__ Wtall,
                                               const float* __restrict__ mask,
                                               unsigned short* __restrict__ Chs1,
                                               unsigned short* __restrict__ Chs2,
                                               unsigned short* __restrict__ Chd1){
  __shared__ short Al[128][56];
  __shared__ short Bl[128][56];
  int tid = threadIdx.x;
  int lane = tid & 63;
  int w = tid >> 6;
  int wm = w >> 1, wn = w & 1;
  int by = blockIdx.y;
  const float* A = (by >= 4) ? Adst : Apkg;
  const unsigned short* Wt = Wtall + (size_t)(by >> 1)*256*DIN;
  unsigned short* Co = (by < 2) ? Chs1 : (by < 4) ? Chs2 : Chd1;
  int row0 = blockIdx.x * 128, col0 = (by & 1) * 128;
  int fr = lane & 15;
  int kb = lane >> 4;
  f32x4 acc[4][4];
  #pragma unroll
  for (int i = 0; i < 4; i++)
    #pragma unroll
    for (int j = 0; j < 4; j++)
      acc[i][j] = (f32x4){0.f, 0.f, 0.f, 0.f};

  for (int k0 = 0; k0 < DIN; k0 += 32){
    u16x8 ra[2]; bf16x8 rb[2];
    #pragma unroll
    for (int p = 0; p < 2; p++){
      int idx = tid + p*256;          // 0..511
      int r = idx >> 2, ch = idx & 3;
      int gr = row0 + r;
      u16x8 o = (u16x8){0,0,0,0,0,0,0,0};
      if (gr < NN){
        float mv = mask[gr];
        const float* ap = A + (size_t)gr*DIN + k0 + ch*8;
        float4 a0 = *(const float4*)(ap);
        float4 a1 = *(const float4*)(ap + 4);
        o[0]=f2b(a0.x*mv); o[1]=f2b(a0.y*mv); o[2]=f2b(a0.z*mv); o[3]=f2b(a0.w*mv);
        o[4]=f2b(a1.x*mv); o[5]=f2b(a1.y*mv); o[6]=f2b(a1.z*mv); o[7]=f2b(a1.w*mv);
      }
      ra[p] = o;
      rb[p] = *(const bf16x8*)(Wt + (size_t)(col0 + r)*DIN + k0 + ch*8);
    }
    __syncthreads();
    #pragma unroll
    for (int p = 0; p < 2; p++){
      int idx = tid + p*256;
      int r = idx >> 2, ch = idx & 3;
      *(u16x8*)(&Al[r][ch*8]) = ra[p];
      *(bf16x8*)(&Bl[r][ch*8]) = rb[p];
    }
    __syncthreads();
    bf16x8 af[4], bfr[4];
    #pragma unroll
    for (int i = 0; i < 4; i++) af[i]  = *(const bf16x8*)(&Al[wm*64 + i*16 + fr][kb*8]);
    #pragma unroll
    for (int j = 0; j < 4; j++) bfr[j] = *(const bf16x8*)(&Bl[wn*64 + j*16 + fr][kb*8]);
    #pragma unroll
    for (int i = 0; i < 4; i++)
      #pragma unroll
      for (int j = 0; j < 4; j++)
        acc[i][j] = __builtin_amdgcn_mfma_f32_16x16x32_bf16(af[i], bfr[j], acc[i][j], 0, 0, 0);
  }
  // C/D layout: col = lane&15, row = (lane>>4)*4 + q  (m89-verified)
  #pragma unroll
  for (int i = 0; i < 4; i++){
    #pragma unroll
    for (int q = 0; q < 4; q++){
      int grow = row0 + wm*64 + i*16 + kb*4 + q;
      if (grow < NN){
        #pragma unroll
        for (int j = 0; j < 4; j++)
          Co[(size_t)grow*256 + col0 + wn*64 + j*16 + fr] = f2b(acc[i][j][q]);
      }
    }
  }
}

// ---------------- MFMA GEMM, bf16 A (h1 @ W2_dst), K=256 ----------------
__global__ __launch_bounds__(256) void gemm_bf16(const short* __restrict__ A, const short* __restrict__ Wt,
                                                 unsigned short* __restrict__ Cb, int M, int K){
  __shared__ short Al[128][56];
  __shared__ short Bl[128][56];
  int tid = threadIdx.x;
  int lane = tid & 63;
  int w = tid >> 6;
  int wm = w >> 1, wn = w & 1;
  int row0 = blockIdx.x * 128, col0 = blockIdx.y * 128;
  int fr = lane & 15;
  int kb = lane >> 4;
  f32x4 acc[4][4];
  #pragma unroll
  for (int i = 0; i < 4; i++)
    #pragma unroll
    for (int j = 0; j < 4; j++)
      acc[i][j] = (f32x4){0.f, 0.f, 0.f, 0.f};

  for (int k0 = 0; k0 < K; k0 += 32){
    bf16x8 ra[2], rb[2];
    #pragma unroll
    for (int p = 0; p < 2; p++){
      int idx = tid + p*256;
      int r = idx >> 2, ch = idx & 3;
      int gr = row0 + r;
      if (gr < M) ra[p] = *(const bf16x8*)(A + (size_t)gr*K + k0 + ch*8);
      else        ra[p] = (bf16x8){0,0,0,0,0,0,0,0};
      rb[p] = *(const bf16x8*)(Wt + (size_t)(col0 + r)*K + k0 + ch*8);
    }
    __syncthreads();
    #pragma unroll
    for (int p = 0; p < 2; p++){
      int idx = tid + p*256;
      int r = idx >> 2, ch = idx & 3;
      *(bf16x8*)(&Al[r][ch*8]) = ra[p];
      *(bf16x8*)(&Bl[r][ch*8]) = rb[p];
    }
    __syncthreads();
    bf16x8 af[4], bfr[4];
    #pragma unroll
    for (int i = 0; i < 4; i++) af[i]  = *(const bf16x8*)(&Al[wm*64 + i*16 + fr][kb*8]);
    #pragma unroll
    for (int j = 0; j < 4; j++) bfr[j] = *(const bf16x8*)(&Bl[wn*64 + j*16 + fr][kb*8]);
    #pragma unroll
    for (int i = 0; i < 4; i++)
      #pragma unroll
      for (int j = 0; j < 4; j++)
        acc[i][j] = __builtin_amdgcn_mfma_f32_16x16x32_bf16(af[i], bfr[j], acc[i][j], 0, 0, 0);
  }
  #pragma unroll
  for (int i = 0; i < 4; i++){
    #pragma unroll
    for (int q = 0; q < 4; q++){
      int grow = row0 + wm*64 + i*16 + kb*4 + q;
      if (grow < M){
        #pragma unroll
        for (int j = 0; j < 4; j++)
          Cb[(size_t)grow*256 + col0 + wn*64 + j*16 + fr] = f2b(acc[i][j][q]);
      }
    }
  }
}

// ---------------- FUSED GAT edge phase: logits + exp + weighted aggregation ----------------
// Wave per dst node; srt[] holds pre-gathered src node ids (CSR order).
__global__ __launch_bounds__(256) void gat_fused(const int* __restrict__ rp, const int* __restrict__ srt,
                                                 const unsigned short* __restrict__ hs,
                                                 const unsigned short* __restrict__ hd,
                                                 const float* __restrict__ att, const float* __restrict__ bias,
                                                 unsigned short* __restrict__ outb, int do_relu){
  int n = blockIdx.x*4 + (threadIdx.x >> 6);
  int lane = threadIdx.x & 63;
  if (n >= NN) return;
  const float4 av = *(const float4*)(att + lane*4);
  ushort4 ud = *(const ushort4*)(hd + (size_t)n*256 + lane*4);
  float d0 = b2f(ud.x), d1 = b2f(ud.y), d2 = b2f(ud.z), d3 = b2f(ud.w);
  int beg = rp[n], end = rp[n+1];
  float4 acc = {0.f,0.f,0.f,0.f};
  float sw = 0.f;
  for (int i = beg; i < end; i++){
    int s = srt[i];
    ushort4 uh = *(const ushort4*)(hs + (size_t)s*256 + lane*4);
    float h0 = b2f(uh.x), h1 = b2f(uh.y), h2 = b2f(uh.z), h3 = b2f(uh.w);
    float m0 = h0 + d0, m1 = h1 + d1, m2 = h2 + d2, m3 = h3 + d3;
    m0 = (m0 > 0.f) ? m0 : 0.2f*m0;
    m1 = (m1 > 0.f) ? m1 : 0.2f*m1;
    m2 = (m2 > 0.f) ? m2 : 0.2f*m2;
    m3 = (m3 > 0.f) ? m3 : 0.2f*m3;
    float p = m0*av.x + m1*av.y + m2*av.z + m3*av.w;
    #pragma unroll
    for (int msk = 8; msk > 0; msk >>= 1) p += __shfl_xor(p, msk);  // 16-lane head-group reduce
    float w = expf(fminf(p, 80.f));     // no segment max: ratio cancels after normalization
    acc.x = fmaf(w, h0, acc.x);
    acc.y = fmaf(w, h1, acc.y);
    acc.z = fmaf(w, h2, acc.z);
    acc.w = fmaf(w, h3, acc.w);
    sw += w;
  }
  float inv = 1.f / (sw + 1e-16f);
  const float4 b4 = *(const float4*)(bias + lane*4);
  float4 r;
  r.x = acc.x*inv + b4.x;
  r.y = acc.y*inv + b4.y;
  r.z = acc.z*inv + b4.z;
  r.w = acc.w*inv + b4.w;
  if (do_relu){
    r.x = fmaxf(r.x, 0.f); r.y = fmaxf(r.y, 0.f);
    r.z = fmaxf(r.z, 0.f); r.w = fmaxf(r.w, 0.f);
  }
  ushort4 o;
  o.x = f2b(r.x); o.y = f2b(r.y); o.z = f2b(r.z); o.w = f2b(r.w);
  *(ushort4*)(outb + (size_t)n*256 + lane*4) = o;
}

// ---------------- FUSED pool: logits GEMM + row softmax (LDS) + partial s^T@h2 ----------------
// One block per 128 rows. Phase A: 128x48 logits. Phase B: softmax -> sld LDS.
// Phase C: partial[k][t] = sum_n sld[n][k]*h2[n][t]. Block 0 also zeroes xpool (consumed
// by pooled_reduce, which launches after this kernel on the same stream).
#define PCH 128
#define NPART ((NN + PCH - 1)/PCH)   // 391
__global__ __launch_bounds__(256) void pool_fused(const unsigned short* __restrict__ h2b,
                                                  const float* __restrict__ Wp,
                                                  const float* __restrict__ bp,
                                                  float* __restrict__ part,
                                                  float* __restrict__ xp){
  __shared__ float As[16][132];  // [kk][row], 128 rows + pad
  __shared__ float Ws[16][KC];   // [kk][col]
  __shared__ float sld[PCH][KC];
  int tid = threadIdx.x;
  int row0 = blockIdx.x * PCH;
  int tx = tid & 15;
  int ty = tid >> 4;
  if (blockIdx.x == 0){
    for (int i = tid; i < KC*FDIM; i += 256) xp[i] = 0.f;
  }
  float acc[8][3] = {};
  for (int k0 = 0; k0 < 256; k0 += 16){
    #pragma unroll
    for (int p = 0; p < 8; p++){
      int idx = tid + p*256;
      int r  = idx >> 4;
      int kk = idx & 15;
      int gr = row0 + r;
      As[kk][r] = (gr < NN) ? b2f(h2b[(size_t)gr*256 + k0 + kk]) : 0.f;
    }
    {
      int idx = tid;
      if (idx < 768) Ws[idx/KC][idx%KC] = Wp[(size_t)(k0 + idx/KC)*KC + idx%KC];
      idx = tid + 256;
      Ws[idx/KC][idx%KC] = Wp[(size_t)(k0 + idx/KC)*KC + idx%KC];
      idx = tid + 512;
      Ws[idx/KC][idx%KC] = Wp[(size_t)(k0 + idx/KC)*KC + idx%KC];
    }
    __syncthreads();
    #pragma unroll
    for (int kk = 0; kk < 16; kk++){
      float a[8], b[3];
      #pragma unroll
      for (int i = 0; i < 8; i++) a[i] = As[kk][ty*8 + i];
      #pragma unroll
      for (int j = 0; j < 3; j++) b[j] = Ws[kk][tx*3 + j];
      #pragma unroll
      for (int i = 0; i < 8; i++)
        #pragma unroll
        for (int j = 0; j < 3; j++)
          acc[i][j] = fmaf(a[i], b[j], acc[i][j]);
    }
    __syncthreads();
  }
  // bias + row softmax -> sld (rows >= NN benign; excluded in phase C)
  float bb[3];
  #pragma unroll
  for (int j = 0; j < 3; j++) bb[j] = bp[tx*3 + j];
  #pragma unroll
  for (int i = 0; i < 8; i++){
    float m = -INFINITY;
    #pragma unroll
    for (int j = 0; j < 3; j++){ acc[i][j] += bb[j]; m = fmaxf(m, acc[i][j]); }
    #pragma unroll
    for (int mask = 8; mask > 0; mask >>= 1) m = fmaxf(m, __shfl_xor(m, mask));
    float e[3], s = 0.f;
    #pragma unroll
    for (int j = 0; j < 3; j++){ e[j] = expf(acc[i][j] - m); s += e[j]; }
    #pragma unroll
    for (int mask = 8; mask > 0; mask >>= 1) s += __shfl_xor(s, mask);
    float inv = 1.f / s;
    #pragma unroll
    for (int j = 0; j < 3; j++) sld[ty*8 + i][tx*3 + j] = e[j] * inv;
  }
  __syncthreads();
  // phase C: per-column partial over this block's rows
  int cnt = min(PCH, NN - row0);
  float pacc[KC];
  #pragma unroll
  for (int k = 0; k < KC; k++) pacc[k] = 0.f;
  for (int n = 0; n < cnt; n++){
    float v = b2f(h2b[(size_t)(row0 + n)*256 + tid]);
    #pragma unroll
    for (int k = 0; k < KC; k++) pacc[k] = fmaf(sld[n][k], v, pacc[k]);
  }
  float* po = part + (size_t)blockIdx.x*KC*256;
  #pragma unroll
  for (int k = 0; k < KC; k++) po[k*256 + tid] = pacc[k];
}

#define PSPL 8
__global__ __launch_bounds__(256) void pooled_reduce(const float* __restrict__ part, float* __restrict__ xp){
  int idx = blockIdx.x*256 + threadIdx.x;     // 0..12287
  const int per = (NPART + PSPL - 1)/PSPL;    // 49
  int p0 = blockIdx.y * per;
  int p1 = min(p0 + per, NPART);
  float s0 = 0.f, s1 = 0.f;
  int p = p0;
  for (; p + 1 < p1; p += 2){
    s0 += part[(size_t)p*KC*256 + idx];
    s1 += part[(size_t)(p+1)*KC*256 + idx];
  }
  if (p < p1) s0 += part[(size_t)p*KC*256 + idx];
  atomicAdd(&xp[idx], s0 + s1);
}

// ---------------- edge_attr mean over E -> [48], parallel grid-stride ----------------
#define BPT 128
__global__ __launch_bounds__(256) void edge_attr_mean(const float* __restrict__ ea, float* __restrict__ out){
  int t   = blockIdx.x / BPT;
  int blk = blockIdx.x % BPT;
  const int NF4 = EE * 2;
  const int per_blk = (NF4 + BPT - 1) / BPT;
  int i0 = blk * per_blk;
  int i1 = min(i0 + per_blk, NF4);
  const float4* base = (const float4*)(ea + (size_t)t*EE*DE);
  float s[8] = {0,0,0,0,0,0,0,0};
  for (int i = i0 + (int)threadIdx.x; i < i1; i += 256){
    float4 v = base[i];
    int db = (i & 1) * 4;
    s[db+0] += v.x; s[db+1] += v.y; s[db+2] += v.z; s[db+3] += v.w;
  }
  __shared__ float red[256];
  for (int d = 0; d < 8; d++){
    red[threadIdx.x] = s[d];
    __syncthreads();
    for (int off = 128; off > 0; off >>= 1){
      if (threadIdx.x < (unsigned)off) red[threadIdx.x] += red[threadIdx.x + off];
      __syncthreads();
    }
    if (threadIdx.x == 0) atomicAdd(&out[t*DE + d], red[0] / (float)EE);
    __syncthreads();
  }
}

// ---------------- final classifier ----------------
__global__ void final_cls(const float* __restrict__ xp, const float* __restrict__ agg,
                          const float* __restrict__ Wc, const float* __restrict__ bc,
                          float* __restrict__ out){
  int k = threadIdx.x;
  if (k < KC){
    float s = bc[0];
    for (int f = 0; f < 256; f++) s = fmaf(xp[k*256 + f], Wc[f], s);
    s = fmaf(agg[k], Wc[256], s);
    out[k] = 1.f/(1.f + expf(-s));
  }
}

extern "C" void kernel_launch(void* const* d_in, const int* in_sizes, int n_in,
                              void* d_out, int out_size, void* d_ws, size_t ws_size,
                              hipStream_t stream) {
  const float* x_pkg     = (const float*)d_in[0];
  const float* x_dst     = (const float*)d_in[1];
  const float* edge_attr = (const float*)d_in[2];
  const float* node_mask = (const float*)d_in[3];
  const float* W1_src    = (const float*)d_in[4];
  const float* W1_dst    = (const float*)d_in[5];
  const float* att1      = (const float*)d_in[6];
  const float* b1        = (const float*)d_in[7];
  const float* W2_src    = (const float*)d_in[8];
  const float* W2_dst    = (const float*)d_in[9];
  const float* att2      = (const float*)d_in[10];
  const float* b2        = (const float*)d_in[11];
  const float* W_pool    = (const float*)d_in[12];
  const float* b_pool    = (const float*)d_in[13];
  const float* W_cls     = (const float*)d_in[14];
  const float* b_cls     = (const float*)d_in[15];
  const int*   edge_index= (const int*)d_in[16];
  float* out = (float*)d_out;

  const int T5 = TT - 1;
  const float* W1s5 = W1_src + (size_t)T5*DIN*FDIM;
  const float* W1d5 = W1_dst + (size_t)T5*DIN*FDIM;
  const float* a1_5 = att1   + (size_t)T5*FDIM;
  const float* b1_5 = b1     + (size_t)T5*FDIM;
  const float* W2s5 = W2_src + (size_t)T5*DIN*FDIM;
  const float* W2d5 = W2_dst + (size_t)T5*FDIM*FDIM;
  const float* a2_5 = att2   + (size_t)T5*FDIM;
  const float* b2_5 = b2     + (size_t)T5*FDIM;
  const float* xd5  = x_dst  + (size_t)T5*NN*DIN;
  const int* src5   = edge_index + (size_t)T5*2*EE;
  const int* dst5   = src5 + EE;

  // ---- workspace layout (bf16 overlays inside three f32-sized slots) ----
  float* buf0 = (float*)d_ws;            // hs1b|hs2b (bf16) -> pooled partials (f32)
  float* buf1 = buf0 + (size_t)NN*FDIM;  // hd1b|h1b (bf16)  -> h2b (bf16)
  float* buf2 = buf1 + (size_t)NN*FDIM;  // hd2b (bf16)
  float* xpool= buf2 + (size_t)NN*FDIM;  // [KC*256]
  float* aggE = xpool + KC*FDIM;         // [64]
  int* deg    = (int*)(aggE + 64);
  int* rp     = deg + NN;
  int* cursor = rp + NN + 1;
  int* srt    = cursor + NN;             // [EE] pre-gathered src ids
  unsigned short* Wtall = (unsigned short*)(srt + EE);   // stacked [768][128]: W1s,W2s,W1d
  unsigned short* Wt2d  = Wtall + (size_t)3*256*DIN;     // [256][256]
  int* bsum = (int*)(Wt2d + (size_t)256*FDIM);   // [NB]
  int* boff = bsum + NB;                 // [NB]
  // bf16 overlays:
  unsigned short* hs1b = (unsigned short*)buf0;                   // dead after L1 fused
  unsigned short* hs2b = hs1b + (size_t)NN*FDIM;                  // dead after L2 fused
  unsigned short* hd1b = (unsigned short*)buf1;                   // dead after L1 fused
  unsigned short* h1b  = hd1b + (size_t)NN*FDIM;                  // dead after hd2 gemm
  unsigned short* h2b  = (unsigned short*)buf1;                   // L2 fused output (hd1b region dead)
  unsigned short* hd2b = (unsigned short*)buf2;                   // dead after L2 fused

  // CSR over dst (shared by both GAT layers) — hierarchical scan
  zero_deg_agg<<<(NN+255)/256, 256, 0, stream>>>(deg, (int*)aggE);
  count_deg<<<(EE+255)/256, 256, 0, stream>>>(dst5, deg);
  scan_blk<<<NB, 256, 0, stream>>>(deg, rp, bsum);
  scan_sums<<<1, 256, 0, stream>>>(bsum, boff);
  scan_add<<<NB, 256, 0, stream>>>(rp, boff, cursor);
  scatter_edges<<<(EE+255)/256, 256, 0, stream>>>(src5, dst5, cursor, srt);

  // edge_attr mean (independent path; aggE zeroed by zero_deg_agg above)
  edge_attr_mean<<<TT*BPT, 256, 0, stream>>>(edge_attr, aggE);

  // transposed bf16 weights (one launch)
  cvt_wt_all<<<dim3(256, 4), 256, 0, stream>>>(W1s5, W2s5, W1d5, W2d5, Wtall, Wt2d);

  // layer 1: hs1 | hs2 | hd1 in one 6-slice launch
  gemm_l1<<<dim3((NN + 127)/128, 6), 256, 0, stream>>>(x_pkg, xd5, Wtall, node_mask,
                                                        hs1b, hs2b, hd1b);
  gat_fused<<<NN/4, 256, 0, stream>>>(rp, srt, hs1b, hd1b, a1_5, b1_5, h1b, 1);   // h1 -> bf16

  // layer 2
  gemm_bf16<<<dim3((NN + 127)/128, 2), 256, 0, stream>>>((const short*)h1b, (const short*)Wt2d,
                                                          hd2b, NN, FDIM);          // hd2
  gat_fused<<<NN/4, 256, 0, stream>>>(rp, srt, hs2b, hd2b, a2_5, b2_5, h2b, 0);   // h2 -> bf16

  // pooling + classifier (buf0 free -> partials; pool_fused block 0 zeroes xpool)
  pool_fused<<<NPART, 256, 0, stream>>>(h2b, W_pool, b_pool, buf0, xpool);
  pooled_reduce<<<dim3(KC, PSPL), 256, 0, stream>>>(buf0, xpool);
  final_cls<<<1, 64, 0, stream>>>(xpool, aggE, W_cls, b_cls, out);
}

// Round 12
// 315.707 us; speedup vs baseline: 4.3038x; 1.0730x over previous
//
#include <hip/hip_runtime.h>
#include <math.h>

#define NN 50000      // nodes (both src and dst)
#define DIN 128
#define FDIM 256      // H*C
#define EE 200000
#define TT 6
#define DE 8
#define KC 48         // clusters
#define NB ((NN + 255)/256)   // 196 scan blocks

typedef __attribute__((ext_vector_type(8))) short bf16x8;
typedef __attribute__((ext_vector_type(8))) unsigned short u16x8;
typedef __attribute__((ext_vector_type(4))) float f32x4;

// f32 -> bf16 round-to-nearest-even
__device__ inline unsigned short f2b(float f){
  unsigned u = __float_as_uint(f);
  unsigned r = u + 0x7FFFu + ((u >> 16) & 1u);
  return (unsigned short)(r >> 16);
}
// bf16 -> f32
__device__ inline float b2f(unsigned short u){ return __uint_as_float(((unsigned)u) << 16); }

// ---------------- utility kernels ----------------
// zero deg[NN] and aggE[64] in one pass
__global__ void zero_deg_agg(int* __restrict__ deg, int* __restrict__ aggE){
  int i = blockIdx.x*256 + threadIdx.x;
  if (i < NN) deg[i] = 0;
  if (i < 64) aggE[i] = 0;
}

__global__ void count_deg(const int* __restrict__ dst, int* __restrict__ deg){
  int i = blockIdx.x*256 + threadIdx.x;
  if (i < EE) atomicAdd(&deg[dst[i]], 1);
}

// ---------------- hierarchical exclusive scan ----------------
__global__ __launch_bounds__(256) void scan_blk(const int* __restrict__ deg, int* __restrict__ rp,
                                                int* __restrict__ bsum){
  __shared__ int sm[256];
  int i = blockIdx.x*256 + threadIdx.x;
  int v = (i < NN) ? deg[i] : 0;
  sm[threadIdx.x] = v;
  __syncthreads();
  #pragma unroll
  for (int off = 1; off < 256; off <<= 1){
    int t = (threadIdx.x >= (unsigned)off) ? sm[threadIdx.x - off] : 0;
    __syncthreads();
    sm[threadIdx.x] += t;
    __syncthreads();
  }
  if (i < NN) rp[i] = sm[threadIdx.x] - v;   // block-local exclusive
  if (threadIdx.x == 255) bsum[blockIdx.x] = sm[255];
}

__global__ __launch_bounds__(256) void scan_sums(const int* __restrict__ bsum, int* __restrict__ boff){
  __shared__ int sm[256];
  int v = (threadIdx.x < NB) ? bsum[threadIdx.x] : 0;
  sm[threadIdx.x] = v;
  __syncthreads();
  #pragma unroll
  for (int off = 1; off < 256; off <<= 1){
    int t = (threadIdx.x >= (unsigned)off) ? sm[threadIdx.x - off] : 0;
    __syncthreads();
    sm[threadIdx.x] += t;
    __syncthreads();
  }
  if (threadIdx.x < NB) boff[threadIdx.x] = sm[threadIdx.x] - v;
}

__global__ __launch_bounds__(256) void scan_add(int* __restrict__ rp, const int* __restrict__ boff,
                                                int* __restrict__ cursor){
  int i = blockIdx.x*256 + threadIdx.x;
  if (i < NN){
    int r = rp[i] + boff[blockIdx.x];
    rp[i] = r;
    cursor[i] = r;
  }
  if (i == 0) rp[NN] = EE;
}

// scatter SRC VALUES (not edge ids): removes one indirection in the fused edge loop
__global__ void scatter_edges(const int* __restrict__ src, const int* __restrict__ dst,
                              int* __restrict__ cursor, int* __restrict__ srt){
  int i = blockIdx.x*256 + threadIdx.x;
  if (i < EE){ int pos = atomicAdd(&cursor[dst[i]], 1); srt[pos] = src[i]; }
}

// ---------------- weight transpose conversion, all four in one launch ----------------
__global__ void cvt_wt_all(const float* __restrict__ W1s, const float* __restrict__ W2s,
                           const float* __restrict__ W1d, const float* __restrict__ W2d,
                           unsigned short* __restrict__ Wtall, unsigned short* __restrict__ Wt2d){
  int n = blockIdx.x;
  int which = blockIdx.y;
  if (which == 3){
    for (int k = threadIdx.x; k < FDIM; k += 256)
      Wt2d[(size_t)n*FDIM + k] = f2b(W2d[(size_t)k*256 + n]);
  } else {
    const float* W = (which == 0) ? W1s : (which == 1) ? W2s : W1d;
    unsigned short* o = Wtall + (size_t)which*256*DIN + (size_t)n*DIN;
    for (int k = threadIdx.x; k < DIN; k += 256)
      o[k] = f2b(W[(size_t)k*256 + n]);
  }
}

// ---------------- layer-1 triple GEMM (hs1 | hs2 | hd1), fused mask+convert ----------------
__global__ __launch_bounds__(256) void gemm_l1(const float* __restrict__ Apkg, const float* __restrict__ Adst,
                                               const unsigned short* __restrict__ Wtall,
                                               const float* __restrict__ mask,
                                               unsigned short* __restrict__ Chs1,
                                               unsigned short* __restrict__ Chs2,
                                               unsigned short* __restrict__ Chd1){
  __shared__ short Al[128][56];
  __shared__ short Bl[128][56];
  int tid = threadIdx.x;
  int lane = tid & 63;
  int w = tid >> 6;
  int wm = w >> 1, wn = w & 1;
  int by = blockIdx.y;
  const float* A = (by >= 4) ? Adst : Apkg;
  const unsigned short* Wt = Wtall + (size_t)(by >> 1)*256*DIN;
  unsigned short* Co = (by < 2) ? Chs1 : (by < 4) ? Chs2 : Chd1;
  int row0 = blockIdx.x * 128, col0 = (by & 1) * 128;
  int fr = lane & 15;
  int kb = lane >> 4;
  f32x4 acc[4][4];
  #pragma unroll
  for (int i = 0; i < 4; i++)
    #pragma unroll
    for (int j = 0; j < 4; j++)
      acc[i][j] = (f32x4){0.f, 0.f, 0.f, 0.f};

  for (int k0 = 0; k0 < DIN; k0 += 32){
    u16x8 ra[2]; bf16x8 rb[2];
    #pragma unroll
    for (int p = 0; p < 2; p++){
      int idx = tid + p*256;          // 0..511
      int r = idx >> 2, ch = idx & 3;
      int gr = row0 + r;
      u16x8 o = (u16x8){0,0,0,0,0,0,0,0};
      if (gr < NN){
        float mv = mask[gr];
        const float* ap = A + (size_t)gr*DIN + k0 + ch*8;
        float4 a0 = *(const float4*)(ap);
        float4 a1 = *(const float4*)(ap + 4);
        o[0]=f2b(a0.x*mv); o[1]=f2b(a0.y*mv); o[2]=f2b(a0.z*mv); o[3]=f2b(a0.w*mv);
        o[4]=f2b(a1.x*mv); o[5]=f2b(a1.y*mv); o[6]=f2b(a1.z*mv); o[7]=f2b(a1.w*mv);
      }
      ra[p] = o;
      rb[p] = *(const bf16x8*)(Wt + (size_t)(col0 + r)*DIN + k0 + ch*8);
    }
    __syncthreads();
    #pragma unroll
    for (int p = 0; p < 2; p++){
      int idx = tid + p*256;
      int r = idx >> 2, ch = idx & 3;
      *(u16x8*)(&Al[r][ch*8]) = ra[p];
      *(bf16x8*)(&Bl[r][ch*8]) = rb[p];
    }
    __syncthreads();
    bf16x8 af[4], bfr[4];
    #pragma unroll
    for (int i = 0; i < 4; i++) af[i]  = *(const bf16x8*)(&Al[wm*64 + i*16 + fr][kb*8]);
    #pragma unroll
    for (int j = 0; j < 4; j++) bfr[j] = *(const bf16x8*)(&Bl[wn*64 + j*16 + fr][kb*8]);
    #pragma unroll
    for (int i = 0; i < 4; i++)
      #pragma unroll
      for (int j = 0; j < 4; j++)
        acc[i][j] = __builtin_amdgcn_mfma_f32_16x16x32_bf16(af[i], bfr[j], acc[i][j], 0, 0, 0);
  }
  // C/D layout: col = lane&15, row = (lane>>4)*4 + q  (m89-verified)
  #pragma unroll
  for (int i = 0; i < 4; i++){
    #pragma unroll
    for (int q = 0; q < 4; q++){
      int grow = row0 + wm*64 + i*16 + kb*4 + q;
      if (grow < NN){
        #pragma unroll
        for (int j = 0; j < 4; j++)
          Co[(size_t)grow*256 + col0 + wn*64 + j*16 + fr] = f2b(acc[i][j][q]);
      }
    }
  }
}

// ---------------- MFMA GEMM, bf16 A (h1 @ W2_dst), K=256 ----------------
__global__ __launch_bounds__(256) void gemm_bf16(const short* __restrict__ A, const short* __restrict__ Wt,
                                                 unsigned short* __restrict__ Cb, int M, int K){
  __shared__ short Al[128][56];
  __shared__ short Bl[128][56];
  int tid = threadIdx.x;
  int lane = tid & 63;
  int w = tid >> 6;
  int wm = w >> 1, wn = w & 1;
  int row0 = blockIdx.x * 128, col0 = blockIdx.y * 128;
  int fr = lane & 15;
  int kb = lane >> 4;
  f32x4 acc[4][4];
  #pragma unroll
  for (int i = 0; i < 4; i++)
    #pragma unroll
    for (int j = 0; j < 4; j++)
      acc[i][j] = (f32x4){0.f, 0.f, 0.f, 0.f};

  for (int k0 = 0; k0 < K; k0 += 32){
    bf16x8 ra[2], rb[2];
    #pragma unroll
    for (int p = 0; p < 2; p++){
      int idx = tid + p*256;
      int r = idx >> 2, ch = idx & 3;
      int gr = row0 + r;
      if (gr < M) ra[p] = *(const bf16x8*)(A + (size_t)gr*K + k0 + ch*8);
      else        ra[p] = (bf16x8){0,0,0,0,0,0,0,0};
      rb[p] = *(const bf16x8*)(Wt + (size_t)(col0 + r)*K + k0 + ch*8);
    }
    __syncthreads();
    #pragma unroll
    for (int p = 0; p < 2; p++){
      int idx = tid + p*256;
      int r = idx >> 2, ch = idx & 3;
      *(bf16x8*)(&Al[r][ch*8]) = ra[p];
      *(bf16x8*)(&Bl[r][ch*8]) = rb[p];
    }
    __syncthreads();
    bf16x8 af[4], bfr[4];
    #pragma unroll
    for (int i = 0; i < 4; i++) af[i]  = *(const bf16x8*)(&Al[wm*64 + i*16 + fr][kb*8]);
    #pragma unroll
    for (int j = 0; j < 4; j++) bfr[j] = *(const bf16x8*)(&Bl[wn*64 + j*16 + fr][kb*8]);
    #pragma unroll
    for (int i = 0; i < 4; i++)
      #pragma unroll
      for (int j = 0; j < 4; j++)
        acc[i][j] = __builtin_amdgcn_mfma_f32_16x16x32_bf16(af[i], bfr[j], acc[i][j], 0, 0, 0);
  }
  #pragma unroll
  for (int i = 0; i < 4; i++){
    #pragma unroll
    for (int q = 0; q < 4; q++){
      int grow = row0 + wm*64 + i*16 + kb*4 + q;
      if (grow < M){
        #pragma unroll
        for (int j = 0; j < 4; j++)
          Cb[(size_t)grow*256 + col0 + wn*64 + j*16 + fr] = f2b(acc[i][j][q]);
      }
    }
  }
}

// ---------------- FUSED GAT edge phase: logits + exp + weighted aggregation ----------------
__global__ __launch_bounds__(256) void gat_fused(const int* __restrict__ rp, const int* __restrict__ srt,
                                                 const unsigned short* __restrict__ hs,
                                                 const unsigned short* __restrict__ hd,
                                                 const float* __restrict__ att, const float* __restrict__ bias,
                                                 unsigned short* __restrict__ outb, int do_relu){
  int n = blockIdx.x*4 + (threadIdx.x >> 6);
  int lane = threadIdx.x & 63;
  if (n >= NN) return;
  const float4 av = *(const float4*)(att + lane*4);
  ushort4 ud = *(const ushort4*)(hd + (size_t)n*256 + lane*4);
  float d0 = b2f(ud.x), d1 = b2f(ud.y), d2 = b2f(ud.z), d3 = b2f(ud.w);
  int beg = rp[n], end = rp[n+1];
  float4 acc = {0.f,0.f,0.f,0.f};
  float sw = 0.f;
  for (int i = beg; i < end; i++){
    int s = srt[i];
    ushort4 uh = *(const ushort4*)(hs + (size_t)s*256 + lane*4);
    float h0 = b2f(uh.x), h1 = b2f(uh.y), h2 = b2f(uh.z), h3 = b2f(uh.w);
    float m0 = h0 + d0, m1 = h1 + d1, m2 = h2 + d2, m3 = h3 + d3;
    m0 = (m0 > 0.f) ? m0 : 0.2f*m0;
    m1 = (m1 > 0.f) ? m1 : 0.2f*m1;
    m2 = (m2 > 0.f) ? m2 : 0.2f*m2;
    m3 = (m3 > 0.f) ? m3 : 0.2f*m3;
    float p = m0*av.x + m1*av.y + m2*av.z + m3*av.w;
    #pragma unroll
    for (int msk = 8; msk > 0; msk >>= 1) p += __shfl_xor(p, msk);  // 16-lane head-group reduce
    float w = expf(fminf(p, 80.f));     // no segment max: ratio cancels after normalization
    acc.x = fmaf(w, h0, acc.x);
    acc.y = fmaf(w, h1, acc.y);
    acc.z = fmaf(w, h2, acc.z);
    acc.w = fmaf(w, h3, acc.w);
    sw += w;
  }
  float inv = 1.f / (sw + 1e-16f);
  const float4 b4 = *(const float4*)(bias + lane*4);
  float4 r;
  r.x = acc.x*inv + b4.x;
  r.y = acc.y*inv + b4.y;
  r.z = acc.z*inv + b4.z;
  r.w = acc.w*inv + b4.w;
  if (do_relu){
    r.x = fmaxf(r.x, 0.f); r.y = fmaxf(r.y, 0.f);
    r.z = fmaxf(r.z, 0.f); r.w = fmaxf(r.w, 0.f);
  }
  ushort4 o;
  o.x = f2b(r.x); o.y = f2b(r.y); o.z = f2b(r.z); o.w = f2b(r.w);
  *(ushort4*)(outb + (size_t)n*256 + lane*4) = o;
}

// ---------------- pool logits via MFMA + in-register row softmax -> sass bf16 [NN][48] ----------------
// grid (391). 4 waves x 32 rows. B (Wp^T bf16 [48][K=256]) staged to LDS once.
// C fragment: col=lane&15, row=(lane>>4)*4+q -> a row lives in one 16-lane group, so the
// row softmax is 3 regs + shfl_xor masks {1,2,4,8}. Block 0 zeroes xpool for pooled_reduce.
__global__ __launch_bounds__(256) void pool_logits_mfma(const unsigned short* __restrict__ h2b,
                                                        const float* __restrict__ Wp,
                                                        const float* __restrict__ bp,
                                                        unsigned short* __restrict__ sass,
                                                        float* __restrict__ xp){
  __shared__ short Al[128][56];    // h2 tile, BK=32
  __shared__ short Bn[KC][264];    // Wp^T, full K=256 (pad 8)
  int tid = threadIdx.x;
  int lane = tid & 63;
  int w = tid >> 6;
  int row0 = blockIdx.x * 128;
  int fr = lane & 15;
  int kb = lane >> 4;
  if (blockIdx.x == 0){
    for (int i = tid; i < KC*FDIM; i += 256) xp[i] = 0.f;
  }
  // stage Wp^T once: Wp is f32 [256][48]
  for (int idx = tid; idx < 256*KC; idx += 256){
    int k = idx / KC, n = idx % KC;
    Bn[n][k] = f2b(Wp[idx]);
  }
  f32x4 acc[2][3];
  #pragma unroll
  for (int i = 0; i < 2; i++)
    #pragma unroll
    for (int j = 0; j < 3; j++)
      acc[i][j] = (f32x4){0.f, 0.f, 0.f, 0.f};

  for (int k0 = 0; k0 < 256; k0 += 32){
    bf16x8 ra[2];
    #pragma unroll
    for (int p = 0; p < 2; p++){
      int idx = tid + p*256;
      int r = idx >> 2, ch = idx & 3;
      int gr = row0 + r;
      if (gr < NN) ra[p] = *(const bf16x8*)((const short*)h2b + (size_t)gr*256 + k0 + ch*8);
      else         ra[p] = (bf16x8){0,0,0,0,0,0,0,0};
    }
    __syncthreads();
    #pragma unroll
    for (int p = 0; p < 2; p++){
      int idx = tid + p*256;
      int r = idx >> 2, ch = idx & 3;
      *(bf16x8*)(&Al[r][ch*8]) = ra[p];
    }
    __syncthreads();
    bf16x8 af[2], bfr[3];
    #pragma unroll
    for (int i = 0; i < 2; i++) af[i]  = *(const bf16x8*)(&Al[w*32 + i*16 + fr][kb*8]);
    #pragma unroll
    for (int j = 0; j < 3; j++) bfr[j] = *(const bf16x8*)(&Bn[j*16 + fr][k0 + kb*8]);
    #pragma unroll
    for (int i = 0; i < 2; i++)
      #pragma unroll
      for (int j = 0; j < 3; j++)
        acc[i][j] = __builtin_amdgcn_mfma_f32_16x16x32_bf16(af[i], bfr[j], acc[i][j], 0, 0, 0);
  }
  // bias + row softmax per (i, q); row's 48 cols = 3 regs x 16 lanes (lane&15)
  float bb[3];
  #pragma unroll
  for (int j = 0; j < 3; j++) bb[j] = bp[j*16 + fr];
  #pragma unroll
  for (int i = 0; i < 2; i++){
    #pragma unroll
    for (int q = 0; q < 4; q++){
      int grow = row0 + w*32 + i*16 + kb*4 + q;
      float v0 = acc[i][0][q] + bb[0];
      float v1 = acc[i][1][q] + bb[1];
      float v2 = acc[i][2][q] + bb[2];
      float m = fmaxf(v0, fmaxf(v1, v2));
      #pragma unroll
      for (int msk = 8; msk > 0; msk >>= 1) m = fmaxf(m, __shfl_xor(m, msk));
      float e0 = expf(v0 - m), e1 = expf(v1 - m), e2 = expf(v2 - m);
      float s = e0 + e1 + e2;
      #pragma unroll
      for (int msk = 8; msk > 0; msk >>= 1) s += __shfl_xor(s, msk);
      float inv = 1.f / s;
      if (grow < NN){
        unsigned short* so = sass + (size_t)grow*KC;
        so[fr]      = f2b(e0 * inv);
        so[16 + fr] = f2b(e1 * inv);
        so[32 + fr] = f2b(e2 * inv);
      }
    }
  }
}

// ---------------- x_pooled partials: s.T @ h2 over 64-node chunks ----------------
#define PCH 64
#define NPART ((NN + PCH - 1)/PCH)   // 782
__global__ __launch_bounds__(256) void pooled_partial(const unsigned short* __restrict__ sass,
                                                      const unsigned short* __restrict__ h2b,
                                                      float* __restrict__ part){
  __shared__ float sld[PCH][KC];
  int t = threadIdx.x;
  int base = blockIdx.x * PCH;
  int cnt = min(PCH, NN - base);
  for (int idx = t; idx < cnt*KC; idx += 256)
    sld[idx/KC][idx%KC] = b2f(sass[(size_t)(base + idx/KC)*KC + idx%KC]);
  __syncthreads();
  float acc[KC];
  #pragma unroll
  for (int k = 0; k < KC; k++) acc[k] = 0.f;
  for (int n = 0; n < cnt; n++){
    float v = b2f(h2b[(size_t)(base + n)*256 + t]);
    #pragma unroll
    for (int k = 0; k < KC; k++) acc[k] = fmaf(sld[n][k], v, acc[k]);
  }
  float* po = part + (size_t)blockIdx.x*KC*256;
  #pragma unroll
  for (int k = 0; k < KC; k++) po[k*256 + t] = acc[k];
}

#define PSPL 8
__global__ __launch_bounds__(256) void pooled_reduce(const float* __restrict__ part, float* __restrict__ xp){
  int idx = blockIdx.x*256 + threadIdx.x;     // 0..12287
  const int per = (NPART + PSPL - 1)/PSPL;    // 98
  int p0 = blockIdx.y * per;
  int p1 = min(p0 + per, NPART);
  float s0 = 0.f, s1 = 0.f;
  int p = p0;
  for (; p + 1 < p1; p += 2){
    s0 += part[(size_t)p*KC*256 + idx];
    s1 += part[(size_t)(p+1)*KC*256 + idx];
  }
  if (p < p1) s0 += part[(size_t)p*KC*256 + idx];
  atomicAdd(&xp[idx], s0 + s1);
}

// ---------------- edge_attr mean over E -> [48], parallel grid-stride ----------------
#define BPT 128
__global__ __launch_bounds__(256) void edge_attr_mean(const float* __restrict__ ea, float* __restrict__ out){
  int t   = blockIdx.x / BPT;
  int blk = blockIdx.x % BPT;
  const int NF4 = EE * 2;
  const int per_blk = (NF4 + BPT - 1) / BPT;
  int i0 = blk * per_blk;
  int i1 = min(i0 + per_blk, NF4);
  const float4* base = (const float4*)(ea + (size_t)t*EE*DE);
  float s[8] = {0,0,0,0,0,0,0,0};
  for (int i = i0 + (int)threadIdx.x; i < i1; i += 256){
    float4 v = base[i];
    int db = (i & 1) * 4;
    s[db+0] += v.x; s[db+1] += v.y; s[db+2] += v.z; s[db+3] += v.w;
  }
  __shared__ float red[256];
  for (int d = 0; d < 8; d++){
    red[threadIdx.x] = s[d];
    __syncthreads();
    for (int off = 128; off > 0; off >>= 1){
      if (threadIdx.x < (unsigned)off) red[threadIdx.x] += red[threadIdx.x + off];
      __syncthreads();
    }
    if (threadIdx.x == 0) atomicAdd(&out[t*DE + d], red[0] / (float)EE);
    __syncthreads();
  }
}

// ---------------- final classifier ----------------
__global__ void final_cls(const float* __restrict__ xp, const float* __restrict__ agg,
                          const float* __restrict__ Wc, const float* __restrict__ bc,
                          float* __restrict__ out){
  int k = threadIdx.x;
  if (k < KC){
    float s = bc[0];
    for (int f = 0; f < 256; f++) s = fmaf(xp[k*256 + f], Wc[f], s);
    s = fmaf(agg[k], Wc[256], s);
    out[k] = 1.f/(1.f + expf(-s));
  }
}

extern "C" void kernel_launch(void* const* d_in, const int* in_sizes, int n_in,
                              void* d_out, int out_size, void* d_ws, size_t ws_size,
                              hipStream_t stream) {
  const float* x_pkg     = (const float*)d_in[0];
  const float* x_dst     = (const float*)d_in[1];
  const float* edge_attr = (const float*)d_in[2];
  const float* node_mask = (const float*)d_in[3];
  const float* W1_src    = (const float*)d_in[4];
  const float* W1_dst    = (const float*)d_in[5];
  const float* att1      = (const float*)d_in[6];
  const float* b1        = (const float*)d_in[7];
  const float* W2_src    = (const float*)d_in[8];
  const float* W2_dst    = (const float*)d_in[9];
  const float* att2      = (const float*)d_in[10];
  const float* b2        = (const float*)d_in[11];
  const float* W_pool    = (const float*)d_in[12];
  const float* b_pool    = (const float*)d_in[13];
  const float* W_cls     = (const float*)d_in[14];
  const float* b_cls     = (const float*)d_in[15];
  const int*   edge_index= (const int*)d_in[16];
  float* out = (float*)d_out;

  const int T5 = TT - 1;
  const float* W1s5 = W1_src + (size_t)T5*DIN*FDIM;
  const float* W1d5 = W1_dst + (size_t)T5*DIN*FDIM;
  const float* a1_5 = att1   + (size_t)T5*FDIM;
  const float* b1_5 = b1     + (size_t)T5*FDIM;
  const float* W2s5 = W2_src + (size_t)T5*DIN*FDIM;
  const float* W2d5 = W2_dst + (size_t)T5*FDIM*FDIM;
  const float* a2_5 = att2   + (size_t)T5*FDIM;
  const float* b2_5 = b2     + (size_t)T5*FDIM;
  const float* xd5  = x_dst  + (size_t)T5*NN*DIN;
  const int* src5   = edge_index + (size_t)T5*2*EE;
  const int* dst5   = src5 + EE;

  // ---- workspace layout (bf16 overlays inside three f32-sized slots) ----
  float* buf0 = (float*)d_ws;            // hs1b|hs2b (bf16) -> pooled partials (f32, 38.4MB)
  float* buf1 = buf0 + (size_t)NN*FDIM;  // hd1b|h1b (bf16)  -> h2b (bf16)
  float* buf2 = buf1 + (size_t)NN*FDIM;  // hd2b (bf16) -> sass (bf16 [NN][48])
  float* xpool= buf2 + (size_t)NN*FDIM;  // [KC*256]
  float* aggE = xpool + KC*FDIM;         // [64]
  int* deg    = (int*)(aggE + 64);
  int* rp     = deg + NN;
  int* cursor = rp + NN + 1;
  int* srt    = cursor + NN;             // [EE] pre-gathered src ids
  unsigned short* Wtall = (unsigned short*)(srt + EE);   // stacked [768][128]: W1s,W2s,W1d
  unsigned short* Wt2d  = Wtall + (size_t)3*256*DIN;     // [256][256]
  int* bsum = (int*)(Wt2d + (size_t)256*FDIM);   // [NB]
  int* boff = bsum + NB;                 // [NB]
  // bf16 overlays:
  unsigned short* hs1b = (unsigned short*)buf0;                   // dead after L1 fused
  unsigned short* hs2b = hs1b + (size_t)NN*FDIM;                  // dead after L2 fused
  unsigned short* hd1b = (unsigned short*)buf1;                   // dead after L1 fused
  unsigned short* h1b  = hd1b + (size_t)NN*FDIM;                  // dead after hd2 gemm
  unsigned short* h2b  = (unsigned short*)buf1;                   // L2 fused output
  unsigned short* hd2b = (unsigned short*)buf2;                   // dead after L2 fused
  unsigned short* sass = (unsigned short*)buf2;                   // pool softmax out [NN][48]

  // CSR over dst (shared by both GAT layers) — hierarchical scan
  zero_deg_agg<<<(NN+255)/256, 256, 0, stream>>>(deg, (int*)aggE);
  count_deg<<<(EE+255)/256, 256, 0, stream>>>(dst5, deg);
  scan_blk<<<NB, 256, 0, stream>>>(deg, rp, bsum);
  scan_sums<<<1, 256, 0, stream>>>(bsum, boff);
  scan_add<<<NB, 256, 0, stream>>>(rp, boff, cursor);
  scatter_edges<<<(EE+255)/256, 256, 0, stream>>>(src5, dst5, cursor, srt);

  // edge_attr mean (independent path; aggE zeroed above)
  edge_attr_mean<<<TT*BPT, 256, 0, stream>>>(edge_attr, aggE);

  // transposed bf16 weights (one launch)
  cvt_wt_all<<<dim3(256, 4), 256, 0, stream>>>(W1s5, W2s5, W1d5, W2d5, Wtall, Wt2d);

  // layer 1: hs1 | hs2 | hd1 in one 6-slice launch
  gemm_l1<<<dim3((NN + 127)/128, 6), 256, 0, stream>>>(x_pkg, xd5, Wtall, node_mask,
                                                        hs1b, hs2b, hd1b);
  gat_fused<<<NN/4, 256, 0, stream>>>(rp, srt, hs1b, hd1b, a1_5, b1_5, h1b, 1);   // h1 -> bf16

  // layer 2
  gemm_bf16<<<dim3((NN + 127)/128, 2), 256, 0, stream>>>((const short*)h1b, (const short*)Wt2d,
                                                          hd2b, NN, FDIM);          // hd2
  gat_fused<<<NN/4, 256, 0, stream>>>(rp, srt, hs2b, hd2b, a2_5, b2_5, h2b, 0);   // h2 -> bf16

  // pooling + classifier (sass overlays dead hd2b; partials in dead buf0)
  pool_logits_mfma<<<(NN + 127)/128, 256, 0, stream>>>(h2b, W_pool, b_pool, sass, xpool);
  pooled_partial<<<NPART, 256, 0, stream>>>(sass, h2b, buf0);
  pooled_reduce<<<dim3(KC, PSPL), 256, 0, stream>>>(buf0, xpool);
  final_cls<<<1, 64, 0, stream>>>(xpool, aggE, W_cls, b_cls, out);
}

// Round 13
// 282.974 us; speedup vs baseline: 4.8017x; 1.1157x over previous
//
#include <hip/hip_runtime.h>
#include <math.h>

#define NN 50000      // nodes (both src and dst)
#define DIN 128
#define FDIM 256      // H*C
#define EE 200000
#define TT 6
#define DE 8
#define KC 48         // clusters
#define NB ((NN + 255)/256)   // 196 scan blocks

typedef __attribute__((ext_vector_type(8))) short bf16x8;
typedef __attribute__((ext_vector_type(8))) unsigned short u16x8;
typedef __attribute__((ext_vector_type(4))) float f32x4;

// f32 -> bf16 round-to-nearest-even
__device__ inline unsigned short f2b(float f){
  unsigned u = __float_as_uint(f);
  unsigned r = u + 0x7FFFu + ((u >> 16) & 1u);
  return (unsigned short)(r >> 16);
}
// bf16 -> f32
__device__ inline float b2f(unsigned short u){ return __uint_as_float(((unsigned)u) << 16); }

// ---------------- utility kernels ----------------
// zero deg[NN] and aggE[64] in one pass
__global__ void zero_deg_agg(int* __restrict__ deg, int* __restrict__ aggE){
  int i = blockIdx.x*256 + threadIdx.x;
  if (i < NN) deg[i] = 0;
  if (i < 64) aggE[i] = 0;
}

__global__ void count_deg(const int* __restrict__ dst, int* __restrict__ deg){
  int i = blockIdx.x*256 + threadIdx.x;
  if (i < EE) atomicAdd(&deg[dst[i]], 1);
}

// ---------------- hierarchical exclusive scan ----------------
__global__ __launch_bounds__(256) void scan_blk(const int* __restrict__ deg, int* __restrict__ rp,
                                                int* __restrict__ bsum){
  __shared__ int sm[256];
  int i = blockIdx.x*256 + threadIdx.x;
  int v = (i < NN) ? deg[i] : 0;
  sm[threadIdx.x] = v;
  __syncthreads();
  #pragma unroll
  for (int off = 1; off < 256; off <<= 1){
    int t = (threadIdx.x >= (unsigned)off) ? sm[threadIdx.x - off] : 0;
    __syncthreads();
    sm[threadIdx.x] += t;
    __syncthreads();
  }
  if (i < NN) rp[i] = sm[threadIdx.x] - v;   // block-local exclusive
  if (threadIdx.x == 255) bsum[blockIdx.x] = sm[255];
}

__global__ __launch_bounds__(256) void scan_sums(const int* __restrict__ bsum, int* __restrict__ boff){
  __shared__ int sm[256];
  int v = (threadIdx.x < NB) ? bsum[threadIdx.x] : 0;
  sm[threadIdx.x] = v;
  __syncthreads();
  #pragma unroll
  for (int off = 1; off < 256; off <<= 1){
    int t = (threadIdx.x >= (unsigned)off) ? sm[threadIdx.x - off] : 0;
    __syncthreads();
    sm[threadIdx.x] += t;
    __syncthreads();
  }
  if (threadIdx.x < NB) boff[threadIdx.x] = sm[threadIdx.x] - v;
}

__global__ __launch_bounds__(256) void scan_add(int* __restrict__ rp, const int* __restrict__ boff,
                                                int* __restrict__ cursor){
  int i = blockIdx.x*256 + threadIdx.x;
  if (i < NN){
    int r = rp[i] + boff[blockIdx.x];
    rp[i] = r;
    cursor[i] = r;
  }
  if (i == 0) rp[NN] = EE;
}

// scatter SRC VALUES (not edge ids): removes one indirection in the fused edge loop
__global__ void scatter_edges(const int* __restrict__ src, const int* __restrict__ dst,
                              int* __restrict__ cursor, int* __restrict__ srt){
  int i = blockIdx.x*256 + threadIdx.x;
  if (i < EE){ int pos = atomicAdd(&cursor[dst[i]], 1); srt[pos] = src[i]; }
}

// ---------------- weight transpose conversion, all four in one launch ----------------
__global__ void cvt_wt_all(const float* __restrict__ W1s, const float* __restrict__ W2s,
                           const float* __restrict__ W1d, const float* __restrict__ W2d,
                           unsigned short* __restrict__ Wtall, unsigned short* __restrict__ Wt2d){
  int n = blockIdx.x;
  int which = blockIdx.y;
  if (which == 3){
    for (int k = threadIdx.x; k < FDIM; k += 256)
      Wt2d[(size_t)n*FDIM + k] = f2b(W2d[(size_t)k*256 + n]);
  } else {
    const float* W = (which == 0) ? W1s : (which == 1) ? W2s : W1d;
    unsigned short* o = Wtall + (size_t)which*256*DIN + (size_t)n*DIN;
    for (int k = threadIdx.x; k < DIN; k += 256)
      o[k] = f2b(W[(size_t)k*256 + n]);
  }
}

// ---------------- layer-1 GEMMs with shared A strip in LDS ----------------
// grid (392, 2). y=0: A=x_pkg, 4 tiles (hs1 c0, hs1 c1, hs2 c0, hs2 c1).
//                y=1: A=xd5,  2 tiles (hd1 c0, hd1 c1).
// A strip (128 rows x 128 k) staged ONCE to LDS (masked f32->bf16) and reused by all tiles,
// cutting f32 A-traffic from 153.6 MB to 51.2 MB. Fragment layouts per learn_hip m89/m91.
__global__ __launch_bounds__(256) void gemm_l1(const float* __restrict__ Apkg, const float* __restrict__ Adst,
                                               const unsigned short* __restrict__ Wtall,
                                               const float* __restrict__ mask,
                                               unsigned short* __restrict__ Chs1,
                                               unsigned short* __restrict__ Chs2,
                                               unsigned short* __restrict__ Chd1){
  __shared__ short Afull[128][136];   // 272B row stride, 16B-aligned
  __shared__ short Bl[128][56];
  int tid = threadIdx.x;
  int lane = tid & 63;
  int w = tid >> 6;
  int wm = w >> 1, wn = w & 1;
  int row0 = blockIdx.x * 128;
  int fr = lane & 15;
  int kb = lane >> 4;
  const float* A = blockIdx.y ? Adst : Apkg;
  // stage A strip once: masked f32 -> bf16
  #pragma unroll
  for (int p = 0; p < 8; p++){
    int idx = tid + p*256;            // 0..2047 chunks of 8 elems
    int r = idx >> 4, ch = idx & 15;  // 16 chunks per row
    int gr = row0 + r;
    u16x8 o = (u16x8){0,0,0,0,0,0,0,0};
    if (gr < NN){
      float mv = mask[gr];
      const float* ap = A + (size_t)gr*DIN + ch*8;
      float4 a0 = *(const float4*)(ap);
      float4 a1 = *(const float4*)(ap + 4);
      o[0]=f2b(a0.x*mv); o[1]=f2b(a0.y*mv); o[2]=f2b(a0.z*mv); o[3]=f2b(a0.w*mv);
      o[4]=f2b(a1.x*mv); o[5]=f2b(a1.y*mv); o[6]=f2b(a1.z*mv); o[7]=f2b(a1.w*mv);
    }
    *(u16x8*)(&Afull[r][ch*8]) = o;
  }
  // (first __syncthreads inside the k-loop below guards Afull staging)
  int ntile = blockIdx.y ? 2 : 4;
  #pragma unroll 1
  for (int t = 0; t < ntile; t++){
    int wsel = blockIdx.y ? 2 : (t >> 1);
    const unsigned short* Wt = Wtall + (size_t)wsel*256*DIN;
    unsigned short* Co = blockIdx.y ? Chd1 : ((t >> 1) ? Chs2 : Chs1);
    int col0 = (t & 1) * 128;
    f32x4 acc[4][4];
    #pragma unroll
    for (int i = 0; i < 4; i++)
      #pragma unroll
      for (int j = 0; j < 4; j++)
        acc[i][j] = (f32x4){0.f, 0.f, 0.f, 0.f};
    for (int k0 = 0; k0 < DIN; k0 += 32){
      bf16x8 rb[2];
      #pragma unroll
      for (int p = 0; p < 2; p++){
        int idx = tid + p*256;
        int r = idx >> 2, ch = idx & 3;
        rb[p] = *(const bf16x8*)(Wt + (size_t)(col0 + r)*DIN + k0 + ch*8);
      }
      __syncthreads();   // prior tile/chunk Bl reads done (also covers Afull staging on 1st pass)
      #pragma unroll
      for (int p = 0; p < 2; p++){
        int idx = tid + p*256;
        int r = idx >> 2, ch = idx & 3;
        *(bf16x8*)(&Bl[r][ch*8]) = rb[p];
      }
      __syncthreads();
      bf16x8 af[4], bfr[4];
      #pragma unroll
      for (int i = 0; i < 4; i++) af[i]  = *(const bf16x8*)(&Afull[wm*64 + i*16 + fr][k0 + kb*8]);
      #pragma unroll
      for (int j = 0; j < 4; j++) bfr[j] = *(const bf16x8*)(&Bl[wn*64 + j*16 + fr][kb*8]);
      #pragma unroll
      for (int i = 0; i < 4; i++)
        #pragma unroll
        for (int j = 0; j < 4; j++)
          acc[i][j] = __builtin_amdgcn_mfma_f32_16x16x32_bf16(af[i], bfr[j], acc[i][j], 0, 0, 0);
    }
    // C/D layout: col = lane&15, row = (lane>>4)*4 + q  (m89-verified)
    #pragma unroll
    for (int i = 0; i < 4; i++){
      #pragma unroll
      for (int q = 0; q < 4; q++){
        int grow = row0 + wm*64 + i*16 + kb*4 + q;
        if (grow < NN){
          #pragma unroll
          for (int j = 0; j < 4; j++)
            Co[(size_t)grow*256 + col0 + wn*64 + j*16 + fr] = f2b(acc[i][j][q]);
        }
      }
    }
  }
}

// ---------------- MFMA GEMM, bf16 A (h1 @ W2_dst), K=256 ----------------
__global__ __launch_bounds__(256) void gemm_bf16(const short* __restrict__ A, const short* __restrict__ Wt,
                                                 unsigned short* __restrict__ Cb, int M, int K){
  __shared__ short Al[128][56];
  __shared__ short Bl[128][56];
  int tid = threadIdx.x;
  int lane = tid & 63;
  int w = tid >> 6;
  int wm = w >> 1, wn = w & 1;
  int row0 = blockIdx.x * 128, col0 = blockIdx.y * 128;
  int fr = lane & 15;
  int kb = lane >> 4;
  f32x4 acc[4][4];
  #pragma unroll
  for (int i = 0; i < 4; i++)
    #pragma unroll
    for (int j = 0; j < 4; j++)
      acc[i][j] = (f32x4){0.f, 0.f, 0.f, 0.f};

  for (int k0 = 0; k0 < K; k0 += 32){
    bf16x8 ra[2], rb[2];
    #pragma unroll
    for (int p = 0; p < 2; p++){
      int idx = tid + p*256;
      int r = idx >> 2, ch = idx & 3;
      int gr = row0 + r;
      if (gr < M) ra[p] = *(const bf16x8*)(A + (size_t)gr*K + k0 + ch*8);
      else        ra[p] = (bf16x8){0,0,0,0,0,0,0,0};
      rb[p] = *(const bf16x8*)(Wt + (size_t)(col0 + r)*K + k0 + ch*8);
    }
    __syncthreads();
    #pragma unroll
    for (int p = 0; p < 2; p++){
      int idx = tid + p*256;
      int r = idx >> 2, ch = idx & 3;
      *(bf16x8*)(&Al[r][ch*8]) = ra[p];
      *(bf16x8*)(&Bl[r][ch*8]) = rb[p];
    }
    __syncthreads();
    bf16x8 af[4], bfr[4];
    #pragma unroll
    for (int i = 0; i < 4; i++) af[i]  = *(const bf16x8*)(&Al[wm*64 + i*16 + fr][kb*8]);
    #pragma unroll
    for (int j = 0; j < 4; j++) bfr[j] = *(const bf16x8*)(&Bl[wn*64 + j*16 + fr][kb*8]);
    #pragma unroll
    for (int i = 0; i < 4; i++)
      #pragma unroll
      for (int j = 0; j < 4; j++)
        acc[i][j] = __builtin_amdgcn_mfma_f32_16x16x32_bf16(af[i], bfr[j], acc[i][j], 0, 0, 0);
  }
  #pragma unroll
  for (int i = 0; i < 4; i++){
    #pragma unroll
    for (int q = 0; q < 4; q++){
      int grow = row0 + wm*64 + i*16 + kb*4 + q;
      if (grow < M){
        #pragma unroll
        for (int j = 0; j < 4; j++)
          Cb[(size_t)grow*256 + col0 + wn*64 + j*16 + fr] = f2b(acc[i][j][q]);
      }
    }
  }
}

// ---------------- FUSED GAT edge phase: logits + exp + weighted aggregation ----------------
// Wave per dst node; srt[] holds pre-gathered src node ids. Unrolled by 2 edges: two
// independent gathers + shfl chains in flight -> 2x memory-level parallelism.
__global__ __launch_bounds__(256) void gat_fused(const int* __restrict__ rp, const int* __restrict__ srt,
                                                 const unsigned short* __restrict__ hs,
                                                 const unsigned short* __restrict__ hd,
                                                 const float* __restrict__ att, const float* __restrict__ bias,
                                                 unsigned short* __restrict__ outb, int do_relu){
  int n = blockIdx.x*4 + (threadIdx.x >> 6);
  int lane = threadIdx.x & 63;
  if (n >= NN) return;
  const float4 av = *(const float4*)(att + lane*4);
  ushort4 ud = *(const ushort4*)(hd + (size_t)n*256 + lane*4);
  float d0 = b2f(ud.x), d1 = b2f(ud.y), d2 = b2f(ud.z), d3 = b2f(ud.w);
  int beg = rp[n], end = rp[n+1];
  float4 acc = {0.f,0.f,0.f,0.f};
  float sw = 0.f;
  int i = beg;
  for (; i + 1 < end; i += 2){
    int sA = srt[i], sB = srt[i+1];
    ushort4 uA = *(const ushort4*)(hs + (size_t)sA*256 + lane*4);
    ushort4 uB = *(const ushort4*)(hs + (size_t)sB*256 + lane*4);
    float hA0 = b2f(uA.x), hA1 = b2f(uA.y), hA2 = b2f(uA.z), hA3 = b2f(uA.w);
    float hB0 = b2f(uB.x), hB1 = b2f(uB.y), hB2 = b2f(uB.z), hB3 = b2f(uB.w);
    float mA0 = hA0 + d0, mA1 = hA1 + d1, mA2 = hA2 + d2, mA3 = hA3 + d3;
    float mB0 = hB0 + d0, mB1 = hB1 + d1, mB2 = hB2 + d2, mB3 = hB3 + d3;
    mA0 = (mA0 > 0.f) ? mA0 : 0.2f*mA0;  mB0 = (mB0 > 0.f) ? mB0 : 0.2f*mB0;
    mA1 = (mA1 > 0.f) ? mA1 : 0.2f*mA1;  mB1 = (mB1 > 0.f) ? mB1 : 0.2f*mB1;
    mA2 = (mA2 > 0.f) ? mA2 : 0.2f*mA2;  mB2 = (mB2 > 0.f) ? mB2 : 0.2f*mB2;
    mA3 = (mA3 > 0.f) ? mA3 : 0.2f*mA3;  mB3 = (mB3 > 0.f) ? mB3 : 0.2f*mB3;
    float pA = mA0*av.x + mA1*av.y + mA2*av.z + mA3*av.w;
    float pB = mB0*av.x + mB1*av.y + mB2*av.z + mB3*av.w;
    #pragma unroll
    for (int msk = 8; msk > 0; msk >>= 1){
      pA += __shfl_xor(pA, msk);
      pB += __shfl_xor(pB, msk);
    }
    float wA = expf(fminf(pA, 80.f));
    float wB = expf(fminf(pB, 80.f));
    acc.x = fmaf(wA, hA0, fmaf(wB, hB0, acc.x));
    acc.y = fmaf(wA, hA1, fmaf(wB, hB1, acc.y));
    acc.z = fmaf(wA, hA2, fmaf(wB, hB2, acc.z));
    acc.w = fmaf(wA, hA3, fmaf(wB, hB3, acc.w));
    sw += wA + wB;
  }
  if (i < end){
    int s = srt[i];
    ushort4 uh = *(const ushort4*)(hs + (size_t)s*256 + lane*4);
    float h0 = b2f(uh.x), h1 = b2f(uh.y), h2 = b2f(uh.z), h3 = b2f(uh.w);
    float m0 = h0 + d0, m1 = h1 + d1, m2 = h2 + d2, m3 = h3 + d3;
    m0 = (m0 > 0.f) ? m0 : 0.2f*m0;
    m1 = (m1 > 0.f) ? m1 : 0.2f*m1;
    m2 = (m2 > 0.f) ? m2 : 0.2f*m2;
    m3 = (m3 > 0.f) ? m3 : 0.2f*m3;
    float p = m0*av.x + m1*av.y + m2*av.z + m3*av.w;
    #pragma unroll
    for (int msk = 8; msk > 0; msk >>= 1) p += __shfl_xor(p, msk);
    float wv = expf(fminf(p, 80.f));
    acc.x = fmaf(wv, h0, acc.x);
    acc.y = fmaf(wv, h1, acc.y);
    acc.z = fmaf(wv, h2, acc.z);
    acc.w = fmaf(wv, h3, acc.w);
    sw += wv;
  }
  float inv = 1.f / (sw + 1e-16f);
  const float4 b4 = *(const float4*)(bias + lane*4);
  float4 r;
  r.x = acc.x*inv + b4.x;
  r.y = acc.y*inv + b4.y;
  r.z = acc.z*inv + b4.z;
  r.w = acc.w*inv + b4.w;
  if (do_relu){
    r.x = fmaxf(r.x, 0.f); r.y = fmaxf(r.y, 0.f);
    r.z = fmaxf(r.z, 0.f); r.w = fmaxf(r.w, 0.f);
  }
  ushort4 o;
  o.x = f2b(r.x); o.y = f2b(r.y); o.z = f2b(r.z); o.w = f2b(r.w);
  *(ushort4*)(outb + (size_t)n*256 + lane*4) = o;
}

// ---------------- pool logits via MFMA + in-register row softmax -> sass bf16 [NN][48] ----------------
__global__ __launch_bounds__(256) void pool_logits_mfma(const unsigned short* __restrict__ h2b,
                                                        const float* __restrict__ Wp,
                                                        const float* __restrict__ bp,
                                                        unsigned short* __restrict__ sass,
                                                        float* __restrict__ xp){
  __shared__ short Al[128][56];    // h2 tile, BK=32
  __shared__ short Bn[KC][264];    // Wp^T, full K=256 (pad 8)
  int tid = threadIdx.x;
  int lane = tid & 63;
  int w = tid >> 6;
  int row0 = blockIdx.x * 128;
  int fr = lane & 15;
  int kb = lane >> 4;
  if (blockIdx.x == 0){
    for (int i = tid; i < KC*FDIM; i += 256) xp[i] = 0.f;
  }
  // stage Wp^T once: Wp is f32 [256][48]
  for (int idx = tid; idx < 256*KC; idx += 256){
    int k = idx / KC, n = idx % KC;
    Bn[n][k] = f2b(Wp[idx]);
  }
  f32x4 acc[2][3];
  #pragma unroll
  for (int i = 0; i < 2; i++)
    #pragma unroll
    for (int j = 0; j < 3; j++)
      acc[i][j] = (f32x4){0.f, 0.f, 0.f, 0.f};

  for (int k0 = 0; k0 < 256; k0 += 32){
    bf16x8 ra[2];
    #pragma unroll
    for (int p = 0; p < 2; p++){
      int idx = tid + p*256;
      int r = idx >> 2, ch = idx & 3;
      int gr = row0 + r;
      if (gr < NN) ra[p] = *(const bf16x8*)((const short*)h2b + (size_t)gr*256 + k0 + ch*8);
      else         ra[p] = (bf16x8){0,0,0,0,0,0,0,0};
    }
    __syncthreads();
    #pragma unroll
    for (int p = 0; p < 2; p++){
      int idx = tid + p*256;
      int r = idx >> 2, ch = idx & 3;
      *(bf16x8*)(&Al[r][ch*8]) = ra[p];
    }
    __syncthreads();
    bf16x8 af[2], bfr[3];
    #pragma unroll
    for (int i = 0; i < 2; i++) af[i]  = *(const bf16x8*)(&Al[w*32 + i*16 + fr][kb*8]);
    #pragma unroll
    for (int j = 0; j < 3; j++) bfr[j] = *(const bf16x8*)(&Bn[j*16 + fr][k0 + kb*8]);
    #pragma unroll
    for (int i = 0; i < 2; i++)
      #pragma unroll
      for (int j = 0; j < 3; j++)
        acc[i][j] = __builtin_amdgcn_mfma_f32_16x16x32_bf16(af[i], bfr[j], acc[i][j], 0, 0, 0);
  }
  float bb[3];
  #pragma unroll
  for (int j = 0; j < 3; j++) bb[j] = bp[j*16 + fr];
  #pragma unroll
  for (int i = 0; i < 2; i++){
    #pragma unroll
    for (int q = 0; q < 4; q++){
      int grow = row0 + w*32 + i*16 + kb*4 + q;
      float v0 = acc[i][0][q] + bb[0];
      float v1 = acc[i][1][q] + bb[1];
      float v2 = acc[i][2][q] + bb[2];
      float m = fmaxf(v0, fmaxf(v1, v2));
      #pragma unroll
      for (int msk = 8; msk > 0; msk >>= 1) m = fmaxf(m, __shfl_xor(m, msk));
      float e0 = expf(v0 - m), e1 = expf(v1 - m), e2 = expf(v2 - m);
      float s = e0 + e1 + e2;
      #pragma unroll
      for (int msk = 8; msk > 0; msk >>= 1) s += __shfl_xor(s, msk);
      float inv = 1.f / s;
      if (grow < NN){
        unsigned short* so = sass + (size_t)grow*KC;
        so[fr]      = f2b(e0 * inv);
        so[16 + fr] = f2b(e1 * inv);
        so[32 + fr] = f2b(e2 * inv);
      }
    }
  }
}

// ---------------- x_pooled partials: s.T @ h2 over 64-node chunks ----------------
#define PCH 64
#define NPART ((NN + PCH - 1)/PCH)   // 782
__global__ __launch_bounds__(256) void pooled_partial(const unsigned short* __restrict__ sass,
                                                      const unsigned short* __restrict__ h2b,
                                                      float* __restrict__ part){
  __shared__ float sld[PCH][KC];
  int t = threadIdx.x;
  int base = blockIdx.x * PCH;
  int cnt = min(PCH, NN - base);
  for (int idx = t; idx < cnt*KC; idx += 256)
    sld[idx/KC][idx%KC] = b2f(sass[(size_t)(base + idx/KC)*KC + idx%KC]);
  __syncthreads();
  float acc[KC];
  #pragma unroll
  for (int k = 0; k < KC; k++) acc[k] = 0.f;
  for (int n = 0; n < cnt; n++){
    float v = b2f(h2b[(size_t)(base + n)*256 + t]);
    #pragma unroll
    for (int k = 0; k < KC; k++) acc[k] = fmaf(sld[n][k], v, acc[k]);
  }
  float* po = part + (size_t)blockIdx.x*KC*256;
  #pragma unroll
  for (int k = 0; k < KC; k++) po[k*256 + t] = acc[k];
}

#define PSPL 8
__global__ __launch_bounds__(256) void pooled_reduce(const float* __restrict__ part, float* __restrict__ xp){
  int idx = blockIdx.x*256 + threadIdx.x;     // 0..12287
  const int per = (NPART + PSPL - 1)/PSPL;    // 98
  int p0 = blockIdx.y * per;
  int p1 = min(p0 + per, NPART);
  float s0 = 0.f, s1 = 0.f;
  int p = p0;
  for (; p + 1 < p1; p += 2){
    s0 += part[(size_t)p*KC*256 + idx];
    s1 += part[(size_t)(p+1)*KC*256 + idx];
  }
  if (p < p1) s0 += part[(size_t)p*KC*256 + idx];
  atomicAdd(&xp[idx], s0 + s1);
}

// ---------------- edge_attr mean over E -> [48], parallel grid-stride ----------------
#define BPT 128
__global__ __launch_bounds__(256) void edge_attr_mean(const float* __restrict__ ea, float* __restrict__ out){
  int t   = blockIdx.x / BPT;
  int blk = blockIdx.x % BPT;
  const int NF4 = EE * 2;
  const int per_blk = (NF4 + BPT - 1) / BPT;
  int i0 = blk * per_blk;
  int i1 = min(i0 + per_blk, NF4);
  const float4* base = (const float4*)(ea + (size_t)t*EE*DE);
  float s[8] = {0,0,0,0,0,0,0,0};
  for (int i = i0 + (int)threadIdx.x; i < i1; i += 256){
    float4 v = base[i];
    int db = (i & 1) * 4;
    s[db+0] += v.x; s[db+1] += v.y; s[db+2] += v.z; s[db+3] += v.w;
  }
  __shared__ float red[256];
  for (int d = 0; d < 8; d++){
    red[threadIdx.x] = s[d];
    __syncthreads();
    for (int off = 128; off > 0; off >>= 1){
      if (threadIdx.x < (unsigned)off) red[threadIdx.x] += red[threadIdx.x + off];
      __syncthreads();
    }
    if (threadIdx.x == 0) atomicAdd(&out[t*DE + d], red[0] / (float)EE);
    __syncthreads();
  }
}

// ---------------- final classifier ----------------
__global__ void final_cls(const float* __restrict__ xp, const float* __restrict__ agg,
                          const float* __restrict__ Wc, const float* __restrict__ bc,
                          float* __restrict__ out){
  int k = threadIdx.x;
  if (k < KC){
    float s = bc[0];
    for (int f = 0; f < 256; f++) s = fmaf(xp[k*256 + f], Wc[f], s);
    s = fmaf(agg[k], Wc[256], s);
    out[k] = 1.f/(1.f + expf(-s));
  }
}

extern "C" void kernel_launch(void* const* d_in, const int* in_sizes, int n_in,
                              void* d_out, int out_size, void* d_ws, size_t ws_size,
                              hipStream_t stream) {
  const float* x_pkg     = (const float*)d_in[0];
  const float* x_dst     = (const float*)d_in[1];
  const float* edge_attr = (const float*)d_in[2];
  const float* node_mask = (const float*)d_in[3];
  const float* W1_src    = (const float*)d_in[4];
  const float* W1_dst    = (const float*)d_in[5];
  const float* att1      = (const float*)d_in[6];
  const float* b1        = (const float*)d_in[7];
  const float* W2_src    = (const float*)d_in[8];
  const float* W2_dst    = (const float*)d_in[9];
  const float* att2      = (const float*)d_in[10];
  const float* b2        = (const float*)d_in[11];
  const float* W_pool    = (const float*)d_in[12];
  const float* b_pool    = (const float*)d_in[13];
  const float* W_cls     = (const float*)d_in[14];
  const float* b_cls     = (const float*)d_in[15];
  const int*   edge_index= (const int*)d_in[16];
  float* out = (float*)d_out;

  const int T5 = TT - 1;
  const float* W1s5 = W1_src + (size_t)T5*DIN*FDIM;
  const float* W1d5 = W1_dst + (size_t)T5*DIN*FDIM;
  const float* a1_5 = att1   + (size_t)T5*FDIM;
  const float* b1_5 = b1     + (size_t)T5*FDIM;
  const float* W2s5 = W2_src + (size_t)T5*DIN*FDIM;
  const float* W2d5 = W2_dst + (size_t)T5*FDIM*FDIM;
  const float* a2_5 = att2   + (size_t)T5*FDIM;
  const float* b2_5 = b2     + (size_t)T5*FDIM;
  const float* xd5  = x_dst  + (size_t)T5*NN*DIN;
  const int* src5   = edge_index + (size_t)T5*2*EE;
  const int* dst5   = src5 + EE;

  // ---- workspace layout (bf16 overlays inside three f32-sized slots) ----
  float* buf0 = (float*)d_ws;            // hs1b|hs2b (bf16) -> pooled partials (f32)
  float* buf1 = buf0 + (size_t)NN*FDIM;  // hd1b|h1b (bf16)  -> h2b (bf16)
  float* buf2 = buf1 + (size_t)NN*FDIM;  // hd2b (bf16) -> sass (bf16 [NN][48])
  float* xpool= buf2 + (size_t)NN*FDIM;  // [KC*256]
  float* aggE = xpool + KC*FDIM;         // [64]
  int* deg    = (int*)(aggE + 64);
  int* rp     = deg + NN;
  int* cursor = rp + NN + 1;
  int* srt    = cursor + NN;             // [EE] pre-gathered src ids
  unsigned short* Wtall = (unsigned short*)(srt + EE);   // stacked [768][128]: W1s,W2s,W1d
  unsigned short* Wt2d  = Wtall + (size_t)3*256*DIN;     // [256][256]
  int* bsum = (int*)(Wt2d + (size_t)256*FDIM);   // [NB]
  int* boff = bsum + NB;                 // [NB]
  // bf16 overlays:
  unsigned short* hs1b = (unsigned short*)buf0;                   // dead after L1 fused
  unsigned short* hs2b = hs1b + (size_t)NN*FDIM;                  // dead after L2 fused
  unsigned short* hd1b = (unsigned short*)buf1;                   // dead after L1 fused
  unsigned short* h1b  = hd1b + (size_t)NN*FDIM;                  // dead after hd2 gemm
  unsigned short* h2b  = (unsigned short*)buf1;                   // L2 fused output
  unsigned short* hd2b = (unsigned short*)buf2;                   // dead after L2 fused
  unsigned short* sass = (unsigned short*)buf2;                   // pool softmax out [NN][48]

  // CSR over dst (shared by both GAT layers) — hierarchical scan
  zero_deg_agg<<<(NN+255)/256, 256, 0, stream>>>(deg, (int*)aggE);
  count_deg<<<(EE+255)/256, 256, 0, stream>>>(dst5, deg);
  scan_blk<<<NB, 256, 0, stream>>>(deg, rp, bsum);
  scan_sums<<<1, 256, 0, stream>>>(bsum, boff);
  scan_add<<<NB, 256, 0, stream>>>(rp, boff, cursor);
  scatter_edges<<<(EE+255)/256, 256, 0, stream>>>(src5, dst5, cursor, srt);

  // edge_attr mean (independent path; aggE zeroed above)
  edge_attr_mean<<<TT*BPT, 256, 0, stream>>>(edge_attr, aggE);

  // transposed bf16 weights (one launch)
  cvt_wt_all<<<dim3(256, 4), 256, 0, stream>>>(W1s5, W2s5, W1d5, W2d5, Wtall, Wt2d);

  // layer 1: hs1 | hs2 | hd1 with A strips staged once per block
  gemm_l1<<<dim3((NN + 127)/128, 2), 256, 0, stream>>>(x_pkg, xd5, Wtall, node_mask,
                                                        hs1b, hs2b, hd1b);
  gat_fused<<<NN/4, 256, 0, stream>>>(rp, srt, hs1b, hd1b, a1_5, b1_5, h1b, 1);   // h1 -> bf16

  // layer 2
  gemm_bf16<<<dim3((NN + 127)/128, 2), 256, 0, stream>>>((const short*)h1b, (const short*)Wt2d,
                                                          hd2b, NN, FDIM);          // hd2
  gat_fused<<<NN/4, 256, 0, stream>>>(rp, srt, hs2b, hd2b, a2_5, b2_5, h2b, 0);   // h2 -> bf16

  // pooling + classifier (sass overlays dead hd2b; partials in dead buf0)
  pool_logits_mfma<<<(NN + 127)/128, 256, 0, stream>>>(h2b, W_pool, b_pool, sass, xpool);
  pooled_partial<<<NPART, 256, 0, stream>>>(sass, h2b, buf0);
  pooled_reduce<<<dim3(KC, PSPL), 256, 0, stream>>>(buf0, xpool);
  final_cls<<<1, 64, 0, stream>>>(xpool, aggE, W_cls, b_cls, out);
}